// Round 7
// baseline (4615.392 us; speedup 1.0000x reference)
//
#include <hip/hip_runtime.h>

typedef unsigned short ushortb;
typedef __attribute__((ext_vector_type(8))) _Float16 f16x8;
typedef __attribute__((ext_vector_type(4))) float f32x4;

__device__ __forceinline__ float h2f(ushortb u) {
    _Float16 h; __builtin_memcpy(&h, &u, 2); return (float)h;
}
__device__ __forceinline__ ushortb f2h(float f) {
    _Float16 h = (_Float16)f; ushortb u; __builtin_memcpy(&u, &h, 2); return u;
}
// tanh-approx GELU == x * sigmoid(1.5957691x + 0.0713548x^3); |err| < ~3e-4 vs erf GELU.
__device__ __forceinline__ float gelu_f(float x) {
    float z = x * (1.59576912f + 0.0713548128f * x * x);
    return x / (1.f + __expf(-z));
}

__device__ __forceinline__ void ld16(const void* g, void* l) {
    __builtin_amdgcn_global_load_lds(
        (const __attribute__((address_space(1))) unsigned int*)g,
        (__attribute__((address_space(3))) unsigned int*)l, 16, 0, 0);
}

// XCD-aware remap: each XCD gets a contiguous tile range so blocks sharing an
// A row-panel land on one XCD's L2. Bijective when total%8==0.
__device__ __forceinline__ void xcd_remap(int& bx, int& by) {
    int nx = gridDim.x;
    int total = nx * gridDim.y;
    bx = blockIdx.x; by = blockIdx.y;
    if ((total & 7) == 0) {
        int lin = by * nx + bx;
        int lin2 = (lin & 7) * (total >> 3) + (lin >> 3);
        by = lin2 / nx; bx = lin2 % nx;
    }
}

// LDS swizzle (rule #21: linear global_load_lds dest + swizzled SOURCE col +
// matching XOR on fragment reads). Kills the 8-way bank conflict of
// row-stride-64B ds_read_b128 (-> 2-way, free per m136).
//   staging source col-chunk: (ln&3) ^ ((ln>>3)&3)
//   fragment read slot:        fq    ^ ((fr>>1)&3)

// ------------------------------------------------------------------
// 3-term split-fp16 MFMA GEMM (NT), pair in -> pair out (fp32 fidelity)
// QK-producer only: writes BLOCK-PERMUTED transposed output QKT:
//   elem(b,d,t) at b*2^20 + (d>>4)*16384 + (t>>4)*256
//                + ((t>>2)&3)*64 + (d&15)*4 + (t&3)
// so each wave (tm,tn) stores one 256-elem block as 512 contiguous bytes
// (lane ln -> offset ln*4..+3). Values identical to round-6 layout.
// ------------------------------------------------------------------
__launch_bounds__(256)
__global__ void gemm_h3(const ushortb* __restrict__ Ah, const ushortb* __restrict__ Al,
                        int lda,
                        const ushortb* __restrict__ Bh, const ushortb* __restrict__ Bl,
                        int ldb,
                        const float* __restrict__ bias,
                        ushortb* __restrict__ Ch, ushortb* __restrict__ Cl, int K)
{
    __shared__ __align__(16) ushortb LDS[16384];
    int bxs, bys; xcd_remap(bxs, bys);
    const int tid = threadIdx.x;
    const int wv = tid >> 6, ln = tid & 63;
    const int fr = ln & 15, fq = ln >> 4;
    const int m0 = bys << 7, n0 = bxs << 7;
    const int wr = (wv & 1) << 6, wc = (wv >> 1) << 6;

    const ushortb* gb; int ld;
    if (wv == 0)      { gb = Ah; ld = lda; }
    else if (wv == 1) { gb = Al; ld = lda; }
    else if (wv == 2) { gb = Bh; ld = ldb; }
    else              { gb = Bl; ld = ldb; }
    const int rbase = (wv < 2) ? m0 : n0;
    const ushortb* gp = gb + (size_t)(rbase + (ln >> 2)) * ld
                          + (((ln & 3) ^ ((ln >> 3) & 3)) * 8);
    ushortb* lplane = LDS + wv * 4096;
    const size_t rstep = (size_t)ld << 4;
    const int sw = (fr >> 1) & 3;

    f32x4 acc[4][4] = {};
    for (int k0 = 0; k0 < K; k0 += 32) {
        __syncthreads();
        #pragma unroll
        for (int i = 0; i < 8; ++i)
            ld16(gp + (size_t)i * rstep, lplane + i * 512);
        gp += 32;
        __syncthreads();
        f16x8 afh[4], afl[4], bfh[4], bfl[4];
        #pragma unroll
        for (int t = 0; t < 4; ++t) {
            int ra = ((wr + t*16 + fr) << 5) + ((fq ^ sw) << 3);
            int rb = ((wc + t*16 + fr) << 5) + ((fq ^ sw) << 3);
            afh[t] = *(const f16x8*)(const void*)(LDS + ra);
            afl[t] = *(const f16x8*)(const void*)(LDS + 4096 + ra);
            bfh[t] = *(const f16x8*)(const void*)(LDS + 8192 + rb);
            bfl[t] = *(const f16x8*)(const void*)(LDS + 12288 + rb);
        }
        #pragma unroll
        for (int tm = 0; tm < 4; ++tm)
            #pragma unroll
            for (int tn = 0; tn < 4; ++tn) {
                f32x4 c = acc[tm][tn];
                c = __builtin_amdgcn_mfma_f32_16x16x32_f16(afh[tm], bfh[tn], c, 0, 0, 0);
                c = __builtin_amdgcn_mfma_f32_16x16x32_f16(afl[tm], bfh[tn], c, 0, 0, 0);
                c = __builtin_amdgcn_mfma_f32_16x16x32_f16(afh[tm], bfl[tn], c, 0, 0, 0);
                acc[tm][tn] = c;
            }
    }
    const size_t bb = (size_t)(m0 >> 10) * 1048576;   // batch base
    #pragma unroll
    for (int tm = 0; tm < 4; ++tm)
        #pragma unroll
        for (int tn = 0; tn < 4; ++tn) {
            int tqb = ((m0 + wr + tm*16) & 1023) >> 4;
            int dg  = (n0 + wc + tn*16) >> 4;
            int col = n0 + wc + tn*16 + fr;
            float bset = bias ? bias[col] : 0.f;
            size_t off = bb + (size_t)dg * 16384 + tqb * 256 + ln * 4;
            float v0 = acc[tm][tn][0] + bset;
            float v1 = acc[tm][tn][1] + bset;
            float v2 = acc[tm][tn][2] + bset;
            float v3 = acc[tm][tn][3] + bset;
            ushortb h0 = f2h(v0), h1 = f2h(v1), h2v = f2h(v2), h3v = f2h(v3);
            uint2 hp, lp_;
            hp.x  = (unsigned)h0 | ((unsigned)h1 << 16);
            hp.y  = (unsigned)h2v | ((unsigned)h3v << 16);
            lp_.x = (unsigned)f2h(v0 - h2f(h0))  | ((unsigned)f2h(v1 - h2f(h1))  << 16);
            lp_.y = (unsigned)f2h(v2 - h2f(h2v)) | ((unsigned)f2h(v3 - h2f(h3v)) << 16);
            *(uint2*)(void*)(Ch + off) = hp;
            *(uint2*)(void*)(Cl + off) = lp_;
        }
}

// ------------------------------------------------------------------
// Single-term fp16 MFMA GEMM (NT), OPERAND-SWAPPED (row=fr, col=fq*4+r):
// coalesced 8B uint2 stores. Optional pair resid, pair/single out, gelu.
// ------------------------------------------------------------------
__launch_bounds__(256)
__global__ void gemm_h1(const ushortb* __restrict__ Ah, int lda,
                        const ushortb* __restrict__ Bh, int ldb,
                        const float* __restrict__ bias,
                        const ushortb* __restrict__ Rh, const ushortb* __restrict__ Rl,
                        ushortb* __restrict__ Ch, ushortb* __restrict__ Cl,
                        int ldc, int K, int act)
{
    __shared__ __align__(16) ushortb LDS[8192];
    int bxs, bys; xcd_remap(bxs, bys);
    const int tid = threadIdx.x;
    const int wv = tid >> 6, ln = tid & 63;
    const int fr = ln & 15, fq = ln >> 4;
    const int m0 = bys << 7, n0 = bxs << 7;
    const int wr = (wv & 1) << 6, wc = (wv >> 1) << 6;

    const ushortb* gb; int ld; int rb;
    if (wv < 2) { gb = Ah; ld = lda; rb = m0; }
    else        { gb = Bh; ld = ldb; rb = n0; }
    const int half = wv & 1;
    const ushortb* gp = gb + (size_t)(rb + half*64 + (ln >> 2)) * ld
                          + (((ln & 3) ^ ((ln >> 3) & 3)) * 8);
    ushortb* lp = LDS + (wv >> 1) * 4096 + half * 2048;
    const size_t rstep = (size_t)ld << 4;
    const int sw = (fr >> 1) & 3;

    f32x4 acc[4][4] = {};
    for (int k0 = 0; k0 < K; k0 += 32) {
        __syncthreads();
        #pragma unroll
        for (int i = 0; i < 4; ++i)
            ld16(gp + (size_t)i * rstep, lp + i * 512);
        gp += 32;
        __syncthreads();
        f16x8 af[4], bf[4];
        #pragma unroll
        for (int t = 0; t < 4; ++t) {
            int ra = ((wr + t*16 + fr) << 5) + ((fq ^ sw) << 3);
            int rx = ((wc + t*16 + fr) << 5) + ((fq ^ sw) << 3);
            af[t] = *(const f16x8*)(const void*)(LDS + ra);
            bf[t] = *(const f16x8*)(const void*)(LDS + 4096 + rx);
        }
        #pragma unroll
        for (int tm = 0; tm < 4; ++tm)
            #pragma unroll
            for (int tn = 0; tn < 4; ++tn)
                acc[tm][tn] = __builtin_amdgcn_mfma_f32_16x16x32_f16(bf[tn], af[tm], acc[tm][tn], 0, 0, 0);
    }
    #pragma unroll
    for (int tm = 0; tm < 4; ++tm)
        #pragma unroll
        for (int tn = 0; tn < 4; ++tn) {
            int row  = m0 + wr + tm*16 + fr;
            int col0 = n0 + wc + tn*16 + (fq << 2);
            size_t off = (size_t)row * ldc + col0;
            float v0 = acc[tm][tn][0], v1 = acc[tm][tn][1];
            float v2 = acc[tm][tn][2], v3 = acc[tm][tn][3];
            if (bias) {
                float4 bv = *(const float4*)(bias + col0);
                v0 += bv.x; v1 += bv.y; v2 += bv.z; v3 += bv.w;
            }
            if (Rh) {
                uint2 rh = *(const uint2*)(const void*)(Rh + off);
                uint2 rl = *(const uint2*)(const void*)(Rl + off);
                v0 += h2f((ushortb)(rh.x & 0xFFFFu)) + h2f((ushortb)(rl.x & 0xFFFFu));
                v1 += h2f((ushortb)(rh.x >> 16))     + h2f((ushortb)(rl.x >> 16));
                v2 += h2f((ushortb)(rh.y & 0xFFFFu)) + h2f((ushortb)(rl.y & 0xFFFFu));
                v3 += h2f((ushortb)(rh.y >> 16))     + h2f((ushortb)(rl.y >> 16));
            }
            if (act) { v0 = gelu_f(v0); v1 = gelu_f(v1); v2 = gelu_f(v2); v3 = gelu_f(v3); }
            ushortb h0 = f2h(v0), h1 = f2h(v1), h2v = f2h(v2), h3v = f2h(v3);
            uint2 hp;
            hp.x = (unsigned)h0 | ((unsigned)h1 << 16);
            hp.y = (unsigned)h2v | ((unsigned)h3v << 16);
            *(uint2*)(void*)(Ch + off) = hp;
            if (Cl) {
                uint2 lo;
                lo.x = (unsigned)f2h(v0 - h2f(h0))  | ((unsigned)f2h(v1 - h2f(h1))  << 16);
                lo.y = (unsigned)f2h(v2 - h2f(h2v)) | ((unsigned)f2h(v3 - h2f(h3v)) << 16);
                *(uint2*)(void*)(Cl + off) = lo;
            }
        }
}

// ------------------------------------------------------------------
// Fused 6-delay gather + O-projection GEMM (operand-swapped like gemm_h1).
// A-staging computes the gather in regs and ds_writes to the SWIZZLED slot.
// ------------------------------------------------------------------
__launch_bounds__(256)
__global__ void gemm_og(const ushortb* __restrict__ Vh,
                        const int* __restrict__ DELAY, const float* __restrict__ WGT,
                        const ushortb* __restrict__ Bh, int ldb,
                        const float* __restrict__ bias,
                        const ushortb* __restrict__ Rh, const ushortb* __restrict__ Rl,
                        ushortb* __restrict__ Ch, ushortb* __restrict__ Cl,
                        int ldc, int K)
{
    __shared__ __align__(16) ushortb LDS[8192];
    int bxs, bys; xcd_remap(bxs, bys);
    const int tid = threadIdx.x;
    const int wv = tid >> 6, ln = tid & 63;
    const int fr = ln & 15, fq = ln >> 4;
    const int m0 = bys << 7, n0 = bxs << 7;
    const int wr = (wv & 1) << 6, wc = (wv >> 1) << 6;
    const int half = wv & 1;

    const int b = m0 >> 10;
    const ushortb* Vb = Vh + ((size_t)b << 19);
    int del[6]; float w6[6];
    #pragma unroll
    for (int j = 0; j < 6; ++j) { del[j] = DELAY[b*6+j]; w6[j] = WGT[b*6+j]; }

    const ushortb* gp = Bh + (size_t)(n0 + half*64 + (ln >> 2)) * ldb
                           + (((ln & 3) ^ ((ln >> 3) & 3)) * 8);
    ushortb* lp = LDS + (wv >> 1) * 4096 + half * 2048;
    const size_t rstep = (size_t)ldb << 4;
    const int sw = (fr >> 1) & 3;
    const int adst = ((ln >> 2) << 5) + (((ln & 3) ^ ((ln >> 3) & 3)) << 3);

    f32x4 acc[4][4] = {};
    for (int k0 = 0; k0 < K; k0 += 32) {
        __syncthreads();
        if (wv < 2) {
            #pragma unroll
            for (int i = 0; i < 4; ++i) {
                int t = (m0 + half*64 + (ln >> 2) + 16*i) & 1023;
                float a0=0,a1=0,a2=0,a3=0,a4=0,a5=0,a6=0,a7=0;
                #pragma unroll
                for (int j = 0; j < 6; ++j) {
                    int s = (t + del[j]) & 1023;
                    f16x8 hv = *(const f16x8*)(const void*)(Vb + (((size_t)s) << 9) + k0 + ((ln & 3) << 3));
                    float w = w6[j];
                    a0 += w * (float)hv[0]; a1 += w * (float)hv[1];
                    a2 += w * (float)hv[2]; a3 += w * (float)hv[3];
                    a4 += w * (float)hv[4]; a5 += w * (float)hv[5];
                    a6 += w * (float)hv[6]; a7 += w * (float)hv[7];
                }
                f16x8 ov;
                ov[0]=(_Float16)a0; ov[1]=(_Float16)a1; ov[2]=(_Float16)a2; ov[3]=(_Float16)a3;
                ov[4]=(_Float16)a4; ov[5]=(_Float16)a5; ov[6]=(_Float16)a6; ov[7]=(_Float16)a7;
                *(f16x8*)(void*)(lp + i*512 + adst) = ov;
            }
        } else {
            #pragma unroll
            for (int i = 0; i < 4; ++i)
                ld16(gp + (size_t)i * rstep, lp + i * 512);
            gp += 32;
        }
        __syncthreads();
        f16x8 af[4], bf[4];
        #pragma unroll
        for (int t = 0; t < 4; ++t) {
            int ra = ((wr + t*16 + fr) << 5) + ((fq ^ sw) << 3);
            int rx = ((wc + t*16 + fr) << 5) + ((fq ^ sw) << 3);
            af[t] = *(const f16x8*)(const void*)(LDS + ra);
            bf[t] = *(const f16x8*)(const void*)(LDS + 4096 + rx);
        }
        #pragma unroll
        for (int tm = 0; tm < 4; ++tm)
            #pragma unroll
            for (int tn = 0; tn < 4; ++tn)
                acc[tm][tn] = __builtin_amdgcn_mfma_f32_16x16x32_f16(bf[tn], af[tm], acc[tm][tn], 0, 0, 0);
    }
    #pragma unroll
    for (int tm = 0; tm < 4; ++tm)
        #pragma unroll
        for (int tn = 0; tn < 4; ++tn) {
            int row  = m0 + wr + tm*16 + fr;
            int col0 = n0 + wc + tn*16 + (fq << 2);
            size_t off = (size_t)row * ldc + col0;
            float4 bv = *(const float4*)(bias + col0);
            float v0 = acc[tm][tn][0] + bv.x, v1 = acc[tm][tn][1] + bv.y;
            float v2 = acc[tm][tn][2] + bv.z, v3 = acc[tm][tn][3] + bv.w;
            uint2 rh = *(const uint2*)(const void*)(Rh + off);
            uint2 rl = *(const uint2*)(const void*)(Rl + off);
            v0 += h2f((ushortb)(rh.x & 0xFFFFu)) + h2f((ushortb)(rl.x & 0xFFFFu));
            v1 += h2f((ushortb)(rh.x >> 16))     + h2f((ushortb)(rl.x >> 16));
            v2 += h2f((ushortb)(rh.y & 0xFFFFu)) + h2f((ushortb)(rl.y & 0xFFFFu));
            v3 += h2f((ushortb)(rh.y >> 16))     + h2f((ushortb)(rl.y >> 16));
            ushortb h0 = f2h(v0), h1 = f2h(v1), h2v = f2h(v2), h3v = f2h(v3);
            uint2 hp, lo;
            hp.x = (unsigned)h0 | ((unsigned)h1 << 16);
            hp.y = (unsigned)h2v | ((unsigned)h3v << 16);
            lo.x = (unsigned)f2h(v0 - h2f(h0))  | ((unsigned)f2h(v1 - h2f(h1))  << 16);
            lo.y = (unsigned)f2h(v2 - h2f(h2v)) | ((unsigned)f2h(v3 - h2f(h3v)) << 16);
            *(uint2*)(void*)(Ch + off) = hp;
            *(uint2*)(void*)(Cl + off) = lo;
        }
}

// ------------------------------------------------------------------
// FFT-based autocorrelation on BLOCK-PERMUTED QKT (see gemm_h3 header).
// chunk c == d-group dg; j == d&15. Per d, lane tid loads uint2 (4 consecutive
// t), block reads the dg-block (L2-resident across the 16 j passes).
// ------------------------------------------------------------------
__device__ __forceinline__ void fft1024_tw(float* Xr, float* Xi, float* Yr, float* Yi,
                                           int tid, const float* csf, const float* snf)
{
    float *psr = Xr, *psi = Xi, *pdr = Yr, *pdi = Yi;
    #pragma unroll
    for (int st = 0; st < 10; ++st) {
        const int s = 1 << st;
        #pragma unroll
        for (int h = 0; h < 2; ++h) {
            int u = tid + (h << 8);
            int qq = u & (s - 1);
            int ps = u - qq;
            float cs = csf[st*2+h], sn = snf[st*2+h];
            float ar = psr[u],       ai = psi[u];
            float br = psr[u + 512], bi = psi[u + 512];
            int d1 = qq + (ps << 1);
            pdr[d1] = ar + br;  pdi[d1] = ai + bi;
            float tr = ar - br, ti = ai - bi;
            pdr[d1 + s] = tr * cs - ti * sn;
            pdi[d1 + s] = tr * sn + ti * cs;
        }
        __syncthreads();
        float* t0 = psr; psr = pdr; pdr = t0;
        float* t1 = psi; psi = pdi; pdi = t1;
    }
}

// grid (32, G): blockIdx.x = 16-wide d-chunk (dg), blockIdx.y = local batch.
__launch_bounds__(256)
__global__ void corr_fft(const ushortb* __restrict__ QKh, const ushortb* __restrict__ QKl,
                         float* __restrict__ SP)
{
    __shared__ __align__(16) float Xr[1024], Xi[1024], Yr[1024], Yi[1024];
    const int tid = threadIdx.x;
    const int c = blockIdx.x, b = blockIdx.y;
    const size_t bbase = (size_t)b << 20;
    float csf[20], snf[20];
    #pragma unroll
    for (int st = 0; st < 10; ++st) {
        const int s = 1 << st;
        #pragma unroll
        for (int h = 0; h < 2; ++h) {
            int u = tid + (h << 8);
            int ps = u - (u & (s - 1));
            float ang = -(3.14159265358979323846f / 512.f) * (float)ps;
            __sincosf(ang, &snf[st*2+h], &csf[st*2+h]);
        }
    }
    // permuted offset for t0 = 4*tid at fixed d: (t0>>4)*256 + ((t0>>2)&3)*64 + (d&15)*4
    const int toff = ((tid >> 2) << 8) + ((tid & 3) << 6);
    const int t0 = tid << 2;
    float sr[4] = {0.f, 0.f, 0.f, 0.f};
    float si[4] = {0.f, 0.f, 0.f, 0.f};
    for (int j = 0; j < 16; ++j) {
        size_t qoff = bbase + ((size_t)c << 14) + toff + (j << 2);
        const ushortb* qh = QKh + qoff;
        const ushortb* ql = QKl + qoff;
        const ushortb* kh = qh + 524288;
        const ushortb* kl = ql + 524288;
        __syncthreads();                    // protect prior unpack reads
        uint2 qa = *(const uint2*)(const void*)qh;
        uint2 qb = *(const uint2*)(const void*)ql;
        uint2 ka = *(const uint2*)(const void*)kh;
        uint2 kb = *(const uint2*)(const void*)kl;
        float4 xr, xi;
        xr.x = h2f((ushortb)(qa.x & 0xFFFFu)) + h2f((ushortb)(qb.x & 0xFFFFu));
        xr.y = h2f((ushortb)(qa.x >> 16))     + h2f((ushortb)(qb.x >> 16));
        xr.z = h2f((ushortb)(qa.y & 0xFFFFu)) + h2f((ushortb)(qb.y & 0xFFFFu));
        xr.w = h2f((ushortb)(qa.y >> 16))     + h2f((ushortb)(qb.y >> 16));
        xi.x = h2f((ushortb)(ka.x & 0xFFFFu)) + h2f((ushortb)(kb.x & 0xFFFFu));
        xi.y = h2f((ushortb)(ka.x >> 16))     + h2f((ushortb)(kb.x >> 16));
        xi.z = h2f((ushortb)(ka.y & 0xFFFFu)) + h2f((ushortb)(kb.y & 0xFFFFu));
        xi.w = h2f((ushortb)(ka.y >> 16))     + h2f((ushortb)(kb.y >> 16));
        *(float4*)(Xr + t0) = xr;
        *(float4*)(Xi + t0) = xi;
        __syncthreads();
        fft1024_tw(Xr, Xi, Yr, Yi, tid, csf, snf);
        #pragma unroll
        for (int i = 0; i < 4; ++i) {
            int f  = tid + (i << 8);
            int f2 = (1024 - f) & 1023;
            float axr = Xr[f],  axi = Xi[f];
            float cxr = Xr[f2], cxi = -Xi[f2];
            float ur = axr + cxr, ui = axi + cxi;
            float vr = axr - cxr, vi = -(axi - cxi);
            float wr_ = ur * vr - ui * vi;
            float wi_ = ur * vi + ui * vr;
            sr[i] += -0.25f * wi_;
            si[i] +=  0.25f * wr_;
        }
    }
    const size_t base = ((size_t)(b * 32 + c)) << 11;
    #pragma unroll
    for (int i = 0; i < 4; ++i) {
        int f = tid + (i << 8);
        SP[base + f]        = sr[i];
        SP[base + 1024 + f] = si[i];
    }
}

// per-b: reduce 32 chunk partials, inverse FFT, top-6 + softmax
__launch_bounds__(256)
__global__ void topk6f_fft(const float* __restrict__ SP, int* __restrict__ DELAY,
                           float* __restrict__ WGT)
{
    __shared__ float Xr[1024], Xi[1024], Yr[1024], Yi[1024];
    __shared__ float v[1024];
    __shared__ float rv[256];
    __shared__ int   ri[256];
    __shared__ float wv6[6];
    __shared__ int   wi6[6];
    const int b = blockIdx.x, tid = threadIdx.x;
    float csf[20], snf[20];
    #pragma unroll
    for (int st = 0; st < 10; ++st) {
        const int s = 1 << st;
        #pragma unroll
        for (int h = 0; h < 2; ++h) {
            int u = tid + (h << 8);
            int ps = u - (u & (s - 1));
            float ang = (3.14159265358979323846f / 512.f) * (float)ps;
            __sincosf(ang, &snf[st*2+h], &csf[st*2+h]);
        }
    }
    #pragma unroll
    for (int i = 0; i < 4; ++i) {
        int f = tid + (i << 8);
        float ar = 0.f, ai = 0.f;
        for (int c = 0; c < 32; ++c) {
            size_t base = ((size_t)(b * 32 + c)) << 11;
            ar += SP[base + f];
            ai += SP[base + 1024 + f];
        }
        Xr[f] = ar; Xi[f] = ai;
    }
    __syncthreads();
    fft1024_tw(Xr, Xi, Yr, Yi, tid, csf, snf);
    #pragma unroll
    for (int i = 0; i < 4; ++i) {
        int f = tid + (i << 8);
        v[f] = Xr[f] * (1.f / 524288.f);
    }
    __syncthreads();
    for (int it = 0; it < 6; ++it) {
        float best = v[tid]; int bi = tid;
        #pragma unroll
        for (int k = 1; k < 4; ++k) {
            int i = tid + (k << 8);
            float xv = v[i];
            if (xv > best) { best = xv; bi = i; }
        }
        rv[tid] = best; ri[tid] = bi;
        __syncthreads();
        for (int s = 128; s > 0; s >>= 1) {
            if (tid < s) {
                if (rv[tid+s] > rv[tid] || (rv[tid+s] == rv[tid] && ri[tid+s] < ri[tid])) {
                    rv[tid] = rv[tid+s]; ri[tid] = ri[tid+s];
                }
            }
            __syncthreads();
        }
        if (tid == 0) { wv6[it] = rv[0]; wi6[it] = ri[0]; v[ri[0]] = -1e30f; }
        __syncthreads();
    }
    if (tid == 0) {
        float mx = wv6[0], s = 0.f, e[6];
        #pragma unroll
        for (int i = 0; i < 6; ++i) { e[i] = expf(wv6[i] - mx); s += e[i]; }
        #pragma unroll
        for (int i = 0; i < 6; ++i) { WGT[b*6+i] = e[i]/s; DELAY[b*6+i] = wi6[i]; }
    }
}

// series_decomp pair->pair, 4 d/thread; TTs trend rows (slot: t>=511 -> t-511, t==0 -> 513)
__launch_bounds__(256)
__global__ void decomp512v(const ushortb* __restrict__ Xh, const ushortb* __restrict__ Xl,
                           ushortb* __restrict__ Sh, ushortb* __restrict__ Sl,
                           float* __restrict__ TTs, int tmode)
{
    int idx = blockIdx.x * 256 + threadIdx.x;   // TG*128
    int d0 = (idx & 127) << 2, bt = idx >> 7, t = bt & 1023;
    int base = bt - t;
    float s0=0,s1=0,s2=0,s3=0;
    #pragma unroll
    for (int w = -12; w <= 12; ++w) {
        int tt = t + w; tt = tt < 0 ? 0 : (tt > 1023 ? 1023 : tt);
        size_t ro = ((size_t)(base + tt) << 9) + d0;
        uint2 hv = *(const uint2*)(Xh + ro);
        uint2 lv = *(const uint2*)(Xl + ro);
        s0 += h2f((ushortb)(hv.x & 0xFFFFu)) + h2f((ushortb)(lv.x & 0xFFFFu));
        s1 += h2f((ushortb)(hv.x >> 16))     + h2f((ushortb)(lv.x >> 16));
        s2 += h2f((ushortb)(hv.y & 0xFFFFu)) + h2f((ushortb)(lv.y & 0xFFFFu));
        s3 += h2f((ushortb)(hv.y >> 16))     + h2f((ushortb)(lv.y >> 16));
    }
    float m0 = s0*(1.f/25.f), m1 = s1*(1.f/25.f), m2 = s2*(1.f/25.f), m3 = s3*(1.f/25.f);
    size_t co = ((size_t)bt << 9) + d0;
    uint2 chv = *(const uint2*)(Xh + co);
    uint2 clv = *(const uint2*)(Xl + co);
    float v0 = h2f((ushortb)(chv.x & 0xFFFFu)) + h2f((ushortb)(clv.x & 0xFFFFu)) - m0;
    float v1 = h2f((ushortb)(chv.x >> 16))     + h2f((ushortb)(clv.x >> 16))     - m1;
    float v2 = h2f((ushortb)(chv.y & 0xFFFFu)) + h2f((ushortb)(clv.y & 0xFFFFu)) - m2;
    float v3 = h2f((ushortb)(chv.y >> 16))     + h2f((ushortb)(clv.y >> 16))     - m3;
    ushortb h0=f2h(v0), h1=f2h(v1), h2v=f2h(v2), h3=f2h(v3);
    uint2 hp, lp;
    hp.x = (unsigned)h0 | ((unsigned)h1 << 16); hp.y = (unsigned)h2v | ((unsigned)h3 << 16);
    lp.x = (unsigned)f2h(v0-h2f(h0)) | ((unsigned)f2h(v1-h2f(h1)) << 16);
    lp.y = (unsigned)f2h(v2-h2f(h2v)) | ((unsigned)f2h(v3-h2f(h3)) << 16);
    *(uint2*)(Sh + co) = hp; *(uint2*)(Sl + co) = lp;
    if (tmode) {
        int slot = (t >= 511) ? (t - 511) : (t == 0 ? 513 : -1);
        if (slot >= 0) {
            int b = bt >> 10;
            float* tp = TTs + (size_t)b * 263168 + ((size_t)slot << 9) + d0;
            if (tmode == 1) { tp[0]=m0; tp[1]=m1; tp[2]=m2; tp[3]=m3; }
            else            { tp[0]+=m0; tp[1]+=m1; tp[2]+=m2; tp[3]+=m3; }
        }
    }
}

// per-token LN, pair in -> pair out
__launch_bounds__(256)
__global__ void ln_rows(const ushortb* __restrict__ Xh, const ushortb* __restrict__ Xl,
                        const float* __restrict__ w, const float* __restrict__ bias,
                        ushortb* __restrict__ Yh, ushortb* __restrict__ Yl)
{
    __shared__ float r1[256], r2[256];
    const int row = blockIdx.x, tid = threadIdx.x;
    size_t ro = (size_t)row * 512;
    float x0 = h2f(Xh[ro + tid]) + h2f(Xl[ro + tid]);
    float x1 = h2f(Xh[ro + tid + 256]) + h2f(Xl[ro + tid + 256]);
    r1[tid] = x0 + x1; r2[tid] = x0*x0 + x1*x1;
    __syncthreads();
    for (int s = 128; s > 0; s >>= 1) {
        if (tid < s) { r1[tid] += r1[tid+s]; r2[tid] += r2[tid+s]; }
        __syncthreads();
    }
    float mu = r1[0] * (1.f/512.f);
    float var = r2[0] * (1.f/512.f) - mu*mu;
    float rstd = rsqrtf(var + 1e-5f);
    float v0 = (x0 - mu) * rstd * w[tid]     + bias[tid];
    float v1 = (x1 - mu) * rstd * w[tid+256] + bias[tid+256];
    ushortb h0 = f2h(v0), h1 = f2h(v1);
    Yh[ro + tid] = h0;       Yl[ro + tid] = f2h(v0 - h2f(h0));
    Yh[ro + tid + 256] = h1; Yl[ro + tid + 256] = f2h(v1 - h2f(h1));
}

// column-mean partials from pair
__launch_bounds__(256)
__global__ void colmean_p(const ushortb* __restrict__ Yh, const ushortb* __restrict__ Yl,
                          float* __restrict__ PC)
{
    int i = blockIdx.x * 256 + threadIdx.x;   // G*4096
    int b = i >> 12, r = i & 4095, d = r >> 3, c = r & 7;
    size_t o = ((size_t)b << 19) + ((size_t)(c << 7) << 9) + d;
    float s = 0.f;
    for (int t = 0; t < 128; ++t) { size_t oo = o + ((size_t)t << 9); s += h2f(Yh[oo]) + h2f(Yl[oo]); }
    PC[i] = s * (1.f/1024.f);
}

// Z = Y - colmean, pair -> pair
__launch_bounds__(256)
__global__ void submean_s(const ushortb* __restrict__ Yh, const ushortb* __restrict__ Yl,
                          const float* __restrict__ PC,
                          ushortb* __restrict__ Zh, ushortb* __restrict__ Zl)
{
    int idx = blockIdx.x * 256 + threadIdx.x;
    int d = idx & 511, b = idx >> 19;
    const float* pc = PC + ((size_t)b << 12) + (d << 3);
    float m = ((pc[0]+pc[1])+(pc[2]+pc[3]))+((pc[4]+pc[5])+(pc[6]+pc[7]));
    float v = h2f(Yh[idx]) + h2f(Yl[idx]) - m;
    ushortb h = f2h(v);
    Zh[idx] = h; Zl[idx] = f2h(v - h2f(h));
}

// embedding -> pair
__launch_bounds__(256)
__global__ void embed_es(const float* __restrict__ x, const float* __restrict__ mark,
                         const float* __restrict__ Wtok, const float* __restrict__ Wtem,
                         ushortb* __restrict__ Oh, ushortb* __restrict__ Ol)
{
    int idx = blockIdx.x * 256 + threadIdx.x;
    int d = idx & 511, bt = idx >> 9, t = bt & 1023, b = bt >> 10;
    float acc = 0.f;
    #pragma unroll
    for (int j = 0; j < 3; ++j) {
        int tt = (t + 1023 + j) & 1023;
        const float* xr = x + (size_t)(b*1024 + tt)*7;
        #pragma unroll
        for (int c = 0; c < 7; ++c)
            acc += xr[c] * Wtok[(j*7+c)*512 + d];
    }
    const float* mr = mark + (size_t)bt*4;
    #pragma unroll
    for (int m = 0; m < 4; ++m) acc += mr[m] * Wtem[m*512 + d];
    ushortb h = f2h(acc);
    Oh[idx] = h; Ol[idx] = f2h(acc - h2f(h));
}

__launch_bounds__(256)
__global__ void mean7(const float* __restrict__ x, float* __restrict__ M7)
{
    __shared__ float r[256];
    int bc = blockIdx.x, b = bc / 7, c = bc % 7, tid = threadIdx.x;
    float s = 0.f;
    for (int t = tid; t < 1024; t += 256) s += x[(size_t)(b*1024+t)*7 + c];
    r[tid] = s; __syncthreads();
    for (int st = 128; st > 0; st >>= 1) { if (tid < st) r[tid] += r[tid+st]; __syncthreads(); }
    if (tid == 0) M7[bc] = r[0] * (1.f/1024.f);
}

__launch_bounds__(256)
__global__ void decomp7(const float* __restrict__ x, const float* __restrict__ M7,
                        float* __restrict__ SEAS7, float* __restrict__ TREND7)
{
    int idx = blockIdx.x * 256 + threadIdx.x;  // TG*7
    int c = idx % 7, bt = idx / 7, t = bt & 1023, b = bt >> 10;
    if (t < 512) {
        int s0 = t + 512;
        float s = 0.f;
        #pragma unroll
        for (int w = -12; w <= 12; ++w) {
            int tt = s0 + w; tt = tt < 0 ? 0 : (tt > 1023 ? 1023 : tt);
            s += x[(size_t)(b*1024+tt)*7 + c];
        }
        float m = s * (1.f/25.f);
        SEAS7[idx] = x[(size_t)(b*1024+s0)*7 + c] - m;
        TREND7[idx] = m;
    } else {
        SEAS7[idx] = 0.f;
        TREND7[idx] = M7[b*7 + c];
    }
}

// fused: out = projb + TREND7 + X@projW + circ_conv3(TTs)@dec_trend_W  (rows t>=512)
__launch_bounds__(256)
__global__ void final_fused(const ushortb* __restrict__ Xh, const ushortb* __restrict__ Xl,
                            const float* __restrict__ PW, const float* __restrict__ PB,
                            const float* __restrict__ TW, const float* __restrict__ TTs,
                            const float* __restrict__ TREND7, float* __restrict__ out)
{
    __shared__ float WT[10752];   // 3*512*7
    __shared__ float WP[3584];    // 512*7
    for (int i = threadIdx.x; i < 10752; i += 256) WT[i] = TW[i];
    for (int i = threadIdx.x; i < 3584; i += 256) WP[i] = PW[i];
    __syncthreads();
    int idx = blockIdx.x * 256 + threadIdx.x;  // G*512*7
    int c = idx % 7, btt = idx / 7, tt = btt & 511, b = btt >> 9;
    int t = tt + 512;
    float acc = PB[c] + TREND7[(size_t)(b*1024 + t)*7 + c];
    size_t ro = ((size_t)(b*1024 + t) << 9);
    for (int d = 0; d < 512; ++d)
        acc += (h2f(Xh[ro + d]) + h2f(Xl[ro + d])) * WP[d*7 + c];
    for (int j = 0; j < 3; ++j) {
        int t2 = t - 1 + j;
        int slot = (t2 >= 1024) ? 513 : (t2 - 511);
        const float* r = TTs + (size_t)b * 263168 + ((size_t)slot << 9);
        const float* wj = WT + j*3584 + c;
        for (int d = 0; d < 512; ++d) acc += r[d] * wj[d*7];
    }
    out[idx] = acc;
}

// attn weight transpose+split pool (block a: 1572864 elems):
// QKh@0 (1024x512), QKl@524288, Vh@1048576, Oh@1310720
__launch_bounds__(256)
__global__ void wsplit_att(const float* __restrict__ W, ushortb* __restrict__ pool, int which)
{
    __shared__ float t[32][33];
    const int m = blockIdx.z;
    const int kb = blockIdx.y << 5, nb = blockIdx.x << 5;
    const int c = threadIdx.x & 31, rr = threadIdx.x >> 5;
    const float* Wm = W + (size_t)m * 262144;
    #pragma unroll
    for (int i = 0; i < 4; ++i)
        t[rr + i*8][c] = Wm[(size_t)(kb + rr + i*8) * 512 + nb + c];
    __syncthreads();
    const int a = (which == 0) ? (m >> 2) : (which + 1);
    const int j = (which == 0) ? (m & 3) : m;
    size_t hi, lo; bool haslo;
    if (j == 0)      { hi = 0;       lo = 524288; haslo = true; }
    else if (j == 1) { hi = 262144;  lo = 786432; haslo = true; }
    else if (j == 2) { hi = 1048576; lo = 0; haslo = false; }
    else             { hi = 1310720; lo = 0; haslo = false; }
    ushortb* pb = pool + (size_t)a * 1572864;
    #pragma unroll
    for (int i = 0; i < 4; ++i) {
        int n = nb + rr + i*8, k = kb + c;
        float v = t[c][rr + i*8];
        ushortb h = f2h(v);
        pb[hi + (size_t)n * 512 + k] = h;
        if (haslo) pb[lo + (size_t)n * 512 + k] = f2h(v - h2f(h));
    }
}

__launch_bounds__(256)
__global__ void wsplit_ff(const float* __restrict__ W, ushortb* __restrict__ dh,
                          int K, int N)
{
    __shared__ float t[32][33];
    const int m = blockIdx.z;
    const int kb = blockIdx.y << 5, nb = blockIdx.x << 5;
    const int c = threadIdx.x & 31, rr = threadIdx.x >> 5;
    const float* Wm = W + (size_t)m * K * N;
    #pragma unroll
    for (int i = 0; i < 4; ++i)
        t[rr + i*8][c] = Wm[(size_t)(kb + rr + i*8) * N + nb + c];
    __syncthreads();
    ushortb* Dh = dh + (size_t)m * 1048576;
    #pragma unroll
    for (int i = 0; i < 4; ++i) {
        int n = nb + rr + i*8, k = kb + c;
        Dh[(size_t)n * K + k] = f2h(t[c][rr + i*8]);
    }
}

__launch_bounds__(256)
__global__ void sentinel(float* __restrict__ out, int n)
{
    int i = blockIdx.x * 256 + threadIdx.x;
    if (i < n) out[i] = -54321.0f;
}

// ------------------------------------------------------------------
extern "C" void kernel_launch(void* const* d_in, const int* in_sizes, int n_in,
                              void* d_out, int out_size, void* d_ws, size_t ws_size,
                              hipStream_t stream)
{
    const float* x_enc      = (const float*)d_in[0];
    const float* x_mark_enc = (const float*)d_in[1];
    const float* x_mark_dec = (const float*)d_in[3];
    const float* W_enc_tok  = (const float*)d_in[4];
    const float* W_enc_tem  = (const float*)d_in[5];
    const float* W_dec_tok  = (const float*)d_in[6];
    const float* W_dec_tem  = (const float*)d_in[7];
    const float* enc_attn_W = (const float*)d_in[8];
    const float* enc_attn_b = (const float*)d_in[9];
    const float* enc_ff1    = (const float*)d_in[10];
    const float* enc_ff2    = (const float*)d_in[11];
    const float* enc_ln_w   = (const float*)d_in[12];
    const float* enc_ln_b   = (const float*)d_in[13];
    const float* dec_self_W = (const float*)d_in[14];
    const float* dec_self_b = (const float*)d_in[15];
    const float* dec_cross_W= (const float*)d_in[16];
    const float* dec_cross_b= (const float*)d_in[17];
    const float* dec_ff1    = (const float*)d_in[18];
    const float* dec_ff2    = (const float*)d_in[19];
    const float* dec_trend_W= (const float*)d_in[20];
    const float* dec_ln_w   = (const float*)d_in[21];
    const float* dec_ln_b   = (const float*)d_in[22];
    const float* proj_W     = (const float*)d_in[23];
    const float* proj_b     = (const float*)d_in[24];
    float* out = (float*)d_out;

    const size_t ATT_E = (size_t)4 * 1572864;
    const size_t FF_E  = (size_t)3 * 1048576;
    const size_t WBYTES = (ATT_E + 2 * FF_E) * 2 + 4096;

    auto need = [&](long g) -> size_t {
        size_t TGl = (size_t)g * 1024;
        size_t pairs = 3 * TGl * 2048;            // SA, TMP, SE pairs
        size_t qk    = TGl * 4096;                // QK pair / MID
        size_t vh    = TGl * 1024;
        size_t tts   = (size_t)g * 263168 * 4;
        size_t pbin  = (size_t)g * 262144;
        size_t misc  = (size_t)g * (16384 + 28 + 28672 + 28672 + 64) + 65536;
        return WBYTES + pairs + qk + vh + tts + pbin + misc + 16384;
    };
    int G = 0;
    for (int g = 32; g >= 1; g >>= 1) if (need(g) <= ws_size) { G = g; break; }
    if (G == 0) {
        sentinel<<<(out_size + 255) / 256, 256, 0, stream>>>(out, out_size);
        return;
    }
    const int TG = G * 1024;

    char* p = (char*)d_ws;
    auto carve = [&](size_t bytes) -> char* {
        char* r = p; p += (bytes + 255) & ~(size_t)255; return r;
    };
    ushortb* ATT = (ushortb*)carve(ATT_E * 2);
    ushortb* FF1 = (ushortb*)carve(FF_E * 2);
    ushortb* FF2 = (ushortb*)carve(FF_E * 2);

    const size_t SPLB = (size_t)TG * 512 * 2;
    ushortb* SAh = (ushortb*)carve(SPLB);
    ushortb* SAl = (ushortb*)carve(SPLB);
    ushortb* TMh = (ushortb*)carve(SPLB);
    ushortb* TMl = (ushortb*)carve(SPLB);
    ushortb* SEh = (ushortb*)carve(SPLB);
    ushortb* SEl = (ushortb*)carve(SPLB);
    char* R1 = carve((size_t)TG * 4096);             // QKTh+QKTl pair / MID
    ushortb* Vh = (ushortb*)carve((size_t)TG * 1024);
    float* TTs   = (float*)carve((size_t)G * 263168 * 4);
    float* PBIN  = (float*)carve((size_t)G * 262144);   // S-partials [b][32][2][1024] f32
    float* PC    = (float*)carve((size_t)G * 16384);
    float* M7    = (float*)carve((size_t)G * 28);
    float* SEAS7 = (float*)carve((size_t)G * 28672);
    float* TREND7= (float*)carve((size_t)G * 28672);
    float* WGT   = (float*)carve((size_t)G * 24);
    int*   DELAY = (int*)  carve((size_t)G * 24);

    ushortb* QKh = (ushortb*)R1;                       // block-permuted [b][dg][tqb][...]
    ushortb* QKl = QKh + (size_t)TG * 1024;
    ushortb* MIDh = (ushortb*)R1;

    // ---- weight transforms ----
    wsplit_att<<<dim3(16,16,8),256,0,stream>>>(enc_attn_W, ATT, 0);
    wsplit_att<<<dim3(16,16,4),256,0,stream>>>(dec_self_W, ATT, 1);
    wsplit_att<<<dim3(16,16,4),256,0,stream>>>(dec_cross_W, ATT, 2);
    wsplit_ff<<<dim3(64,16,2),256,0,stream>>>(enc_ff1, FF1, 512, 2048);
    wsplit_ff<<<dim3(64,16,1),256,0,stream>>>(dec_ff1, FF1 + (size_t)2*1048576, 512, 2048);
    wsplit_ff<<<dim3(16,64,2),256,0,stream>>>(enc_ff2, FF2, 2048, 512);
    wsplit_ff<<<dim3(16,64,1),256,0,stream>>>(dec_ff2, FF2 + (size_t)2*1048576, 2048, 512);

    for (int g0 = 0; g0 < 32; g0 += G) {
        const float* xe  = x_enc      + (size_t)g0 * 1024 * 7;
        const float* me  = x_mark_enc + (size_t)g0 * 1024 * 4;
        const float* md  = x_mark_dec + (size_t)g0 * 1024 * 4;
        float*       outg= out        + (size_t)g0 * 512 * 7;
        const int GB = G * 8;   // TG/128

        auto corr_gather_oproj = [&](const ushortb* base, const float* bv,
                                     const ushortb* rh, const ushortb* rl) {
            corr_fft<<<dim3(32,G),256,0,stream>>>(QKh, QKl, PBIN);
            topk6f_fft<<<G,256,0,stream>>>(PBIN, DELAY, WGT);
            gemm_og<<<dim3(4,GB),256,0,stream>>>(Vh, DELAY, WGT,
                                                 base+1310720,512, bv+1536,
                                                 rh,rl, TMh,TMl, 512, 512);
        };
        auto attn_self = [&](const ushortb* xh, const ushortb* xl, int a, const float* bv) {
            const ushortb* base = ATT + (size_t)a * 1572864;
            gemm_h3<<<dim3(8,GB),256,0,stream>>>(xh,xl,512, base,base+524288,512, bv,
                                                 QKh,QKl, 512);
            gemm_h1<<<dim3(4,GB),256,0,stream>>>(xh,512, base+1048576,512, bv+1024,
                                                 nullptr,nullptr, Vh,nullptr, 512, 512, 0);
            corr_gather_oproj(base, bv, xh, xl);
        };
        auto attn_cross = [&](const ushortb* qh, const ushortb* ql,
                              const ushortb* kvh, const ushortb* kvl,
                              int a, const float* bv) {
            const ushortb* base = ATT + (size_t)a * 1572864;
            gemm_h3<<<dim3(4,GB),256,0,stream>>>(qh,ql,512, base,base+524288,512, bv,
                                                 QKh,QKl, 512);
            gemm_h3<<<dim3(4,GB),256,0,stream>>>(kvh,kvl,512, base+262144,base+786432,512, bv+512,
                                                 QKh+524288,QKl+524288, 512);
            gemm_h1<<<dim3(4,GB),256,0,stream>>>(kvh,512, base+1048576,512, bv+1024,
                                                 nullptr,nullptr, Vh,nullptr, 512, 512, 0);
            corr_gather_oproj(base, bv, qh, ql);
        };
        auto ffn = [&](const ushortb* xh, const ushortb* xl, int fi) {
            gemm_h1<<<dim3(16,GB),256,0,stream>>>(xh,512, FF1 + (size_t)fi*1048576,512, nullptr,
                                                  nullptr,nullptr, MIDh,nullptr, 2048, 512, 1);
            gemm_h1<<<dim3(4,GB),256,0,stream>>>(MIDh,2048, FF2 + (size_t)fi*1048576,2048, nullptr,
                                                 xh,xl, TMh,TMl, 512, 2048, 0);
        };

        // ---------------- encoder ----------------
        embed_es<<<TG*2,256,0,stream>>>(xe, me, W_enc_tok, W_enc_tem, SAh, SAl);
        for (int l = 0; l < 2; ++l) {
            attn_self(SAh, SAl, l, enc_attn_b + (size_t)l*4*512);
            decomp512v<<<TG/2,256,0,stream>>>(TMh, TMl, SAh, SAl, nullptr, 0);
            ffn(SAh, SAl, l);
            decomp512v<<<TG/2,256,0,stream>>>(TMh, TMl, SAh, SAl, nullptr, 0);
        }
        ln_rows<<<TG,256,0,stream>>>(SAh, SAl, enc_ln_w, enc_ln_b, TMh, TMl);
        colmean_p<<<G*16,256,0,stream>>>(TMh, TMl, PC);
        submean_s<<<TG*2,256,0,stream>>>(TMh, TMl, PC, SEh, SEl);

        // ---------------- decoder prep ----------------
        mean7<<<G*7,256,0,stream>>>(xe, M7);
        decomp7<<<G*28,256,0,stream>>>(xe, M7, SEAS7, TREND7);
        embed_es<<<TG*2,256,0,stream>>>(SEAS7, md, W_dec_tok, W_dec_tem, SAh, SAl);

        // ---------------- decoder layer ----------------
        attn_self(SAh, SAl, 2, dec_self_b);
        decomp512v<<<TG/2,256,0,stream>>>(TMh, TMl, SAh, SAl, TTs, 1);

        attn_cross(SAh, SAl, SEh, SEl, 3, dec_cross_b);
        decomp512v<<<TG/2,256,0,stream>>>(TMh, TMl, SAh, SAl, TTs, 2);

        ffn(SAh, SAl, 2);
        decomp512v<<<TG/2,256,0,stream>>>(TMh, TMl, SAh, SAl, TTs, 2);

        ln_rows<<<TG,256,0,stream>>>(SAh, SAl, dec_ln_w, dec_ln_b, TMh, TMl);
        colmean_p<<<G*16,256,0,stream>>>(TMh, TMl, PC);
        submean_s<<<TG*2,256,0,stream>>>(TMh, TMl, PC, SAh, SAl);

        final_fused<<<G*14,256,0,stream>>>(SAh, SAl, proj_W, proj_b, dec_trend_W,
                                           TTs, TREND7, outg);
    }
}

// Round 8
// 3933.125 us; speedup vs baseline: 1.1735x; 1.1735x over previous
//
#include <hip/hip_runtime.h>

typedef unsigned short ushortb;
typedef __attribute__((ext_vector_type(8))) _Float16 f16x8;
typedef __attribute__((ext_vector_type(4))) float f32x4;

__device__ __forceinline__ float h2f(ushortb u) {
    _Float16 h; __builtin_memcpy(&h, &u, 2); return (float)h;
}
__device__ __forceinline__ ushortb f2h(float f) {
    _Float16 h = (_Float16)f; ushortb u; __builtin_memcpy(&u, &h, 2); return u;
}
// tanh-approx GELU == x * sigmoid(1.5957691x + 0.0713548x^3); |err| < ~3e-4 vs erf GELU.
__device__ __forceinline__ float gelu_f(float x) {
    float z = x * (1.59576912f + 0.0713548128f * x * x);
    return x / (1.f + __expf(-z));
}

__device__ __forceinline__ void ld16(const void* g, void* l) {
    __builtin_amdgcn_global_load_lds(
        (const __attribute__((address_space(1))) unsigned int*)g,
        (__attribute__((address_space(3))) unsigned int*)l, 16, 0, 0);
}

// XCD-aware remap: each XCD gets a contiguous tile range so blocks sharing an
// A row-panel land on one XCD's L2. Bijective when total%8==0.
__device__ __forceinline__ void xcd_remap(int& bx, int& by) {
    int nx = gridDim.x;
    int total = nx * gridDim.y;
    bx = blockIdx.x; by = blockIdx.y;
    if ((total & 7) == 0) {
        int lin = by * nx + bx;
        int lin2 = (lin & 7) * (total >> 3) + (lin >> 3);
        by = lin2 / nx; bx = lin2 % nx;
    }
}

// LDS staging swizzle (rule #21): linear global_load_lds dest + swizzled SOURCE
// col + matching XOR on fragment reads. 8-way bank conflict -> 2-way (free).
//   staging source col-chunk: (ln&3) ^ ((ln>>3)&3)
//   fragment read slot:        fq    ^ ((fr>>1)&3)

// ------------------------------------------------------------------
// 3-term split-fp16 MFMA GEMM (NT), pair in -> pair out (fp32 fidelity)
// QK-producer only: TRANSPOSED output QKT[b][d][t] (round-6 linear layout,
// per-batch stride 2^20). Store amplification fixed via LDS-transposed
// epilogue: per tn-pass, stage 32col x 128trow in LDS, re-read col-major,
// store 32B-contiguous runs (8 threads = 256B = 2 full lines per d-row).
// ------------------------------------------------------------------
__launch_bounds__(256)
__global__ void gemm_h3(const ushortb* __restrict__ Ah, const ushortb* __restrict__ Al,
                        int lda,
                        const ushortb* __restrict__ Bh, const ushortb* __restrict__ Bl,
                        int ldb,
                        const float* __restrict__ bias,
                        ushortb* __restrict__ Ch, ushortb* __restrict__ Cl, int K)
{
    __shared__ __align__(16) ushortb LDS[16384];    // 32 KB
    int bxs, bys; xcd_remap(bxs, bys);
    const int tid = threadIdx.x;
    const int wv = tid >> 6, ln = tid & 63;
    const int fr = ln & 15, fq = ln >> 4;
    const int m0 = bys << 7, n0 = bxs << 7;
    const int wr = (wv & 1) << 6, wc = (wv >> 1) << 6;

    const ushortb* gb; int ld;
    if (wv == 0)      { gb = Ah; ld = lda; }
    else if (wv == 1) { gb = Al; ld = lda; }
    else if (wv == 2) { gb = Bh; ld = ldb; }
    else              { gb = Bl; ld = ldb; }
    const int rbase = (wv < 2) ? m0 : n0;
    const ushortb* gp = gb + (size_t)(rbase + (ln >> 2)) * ld
                          + (((ln & 3) ^ ((ln >> 3) & 3)) * 8);
    ushortb* lplane = LDS + wv * 4096;
    const size_t rstep = (size_t)ld << 4;
    const int sw = (fr >> 1) & 3;

    f32x4 acc[4][4] = {};
    for (int k0 = 0; k0 < K; k0 += 32) {
        __syncthreads();
        #pragma unroll
        for (int i = 0; i < 8; ++i)
            ld16(gp + (size_t)i * rstep, lplane + i * 512);
        gp += 32;
        __syncthreads();
        f16x8 afh[4], afl[4], bfh[4], bfl[4];
        #pragma unroll
        for (int t = 0; t < 4; ++t) {
            int ra = ((wr + t*16 + fr) << 5) + ((fq ^ sw) << 3);
            int rb = ((wc + t*16 + fr) << 5) + ((fq ^ sw) << 3);
            afh[t] = *(const f16x8*)(const void*)(LDS + ra);
            afl[t] = *(const f16x8*)(const void*)(LDS + 4096 + ra);
            bfh[t] = *(const f16x8*)(const void*)(LDS + 8192 + rb);
            bfl[t] = *(const f16x8*)(const void*)(LDS + 12288 + rb);
        }
        #pragma unroll
        for (int tm = 0; tm < 4; ++tm)
            #pragma unroll
            for (int tn = 0; tn < 4; ++tn) {
                f32x4 c = acc[tm][tn];
                c = __builtin_amdgcn_mfma_f32_16x16x32_f16(afh[tm], bfh[tn], c, 0, 0, 0);
                c = __builtin_amdgcn_mfma_f32_16x16x32_f16(afl[tm], bfh[tn], c, 0, 0, 0);
                c = __builtin_amdgcn_mfma_f32_16x16x32_f16(afh[tm], bfl[tn], c, 0, 0, 0);
                acc[tm][tn] = c;
            }
    }
    // ---- LDS-transposed epilogue ----
    const size_t bb = (size_t)(m0 >> 10) * 1048576;   // batch base
    const int trow0 = m0 & 1023;                      // block's t-range base
    const int PS = 4224;                              // 32*132 (pad 4)
    ushortb* EH = LDS;
    ushortb* EL = LDS + PS;
    const int cl  = ((wv >> 1) << 4) + fr;            // local col 0..31
    const int rcl = tid >> 3, seg = tid & 7;          // reader mapping
    #pragma unroll
    for (int tn = 0; tn < 4; ++tn) {
        __syncthreads();                              // LDS free / prev pass done
        int col = n0 + ((wv >> 1) << 6) + tn*16 + fr;
        float bset = bias ? bias[col] : 0.f;
        #pragma unroll
        for (int tm = 0; tm < 4; ++tm) {
            int tl = ((wv & 1) << 6) + tm*16 + (fq << 2);
            float v0 = acc[tm][tn][0] + bset;
            float v1 = acc[tm][tn][1] + bset;
            float v2 = acc[tm][tn][2] + bset;
            float v3 = acc[tm][tn][3] + bset;
            ushortb h0 = f2h(v0), h1 = f2h(v1), h2v = f2h(v2), h3v = f2h(v3);
            uint2 hp, lp_;
            hp.x  = (unsigned)h0 | ((unsigned)h1 << 16);
            hp.y  = (unsigned)h2v | ((unsigned)h3v << 16);
            lp_.x = (unsigned)f2h(v0 - h2f(h0))  | ((unsigned)f2h(v1 - h2f(h1))  << 16);
            lp_.y = (unsigned)f2h(v2 - h2f(h2v)) | ((unsigned)f2h(v3 - h2f(h3v)) << 16);
            *(uint2*)(void*)(EH + cl*132 + tl) = hp;
            *(uint2*)(void*)(EL + cl*132 + tl) = lp_;
        }
        __syncthreads();
        int gcol = n0 + ((rcl >> 4) << 6) + tn*16 + (rcl & 15);
        size_t goff = bb + (size_t)gcol * 1024 + trow0 + (seg << 4);
        const ushortb* sh = EH + rcl*132 + (seg << 4);
        const ushortb* sl = EL + rcl*132 + (seg << 4);
        #pragma unroll
        for (int i = 0; i < 4; ++i) {
            *(uint2*)(void*)(Ch + goff + i*4) = *(const uint2*)(const void*)(sh + i*4);
            *(uint2*)(void*)(Cl + goff + i*4) = *(const uint2*)(const void*)(sl + i*4);
        }
    }
}

// ------------------------------------------------------------------
// Single-term fp16 MFMA GEMM (NT), OPERAND-SWAPPED (row=fr, col=fq*4+r):
// coalesced 8B uint2 stores. Optional pair resid, pair/single out, gelu.
// ------------------------------------------------------------------
__launch_bounds__(256)
__global__ void gemm_h1(const ushortb* __restrict__ Ah, int lda,
                        const ushortb* __restrict__ Bh, int ldb,
                        const float* __restrict__ bias,
                        const ushortb* __restrict__ Rh, const ushortb* __restrict__ Rl,
                        ushortb* __restrict__ Ch, ushortb* __restrict__ Cl,
                        int ldc, int K, int act)
{
    __shared__ __align__(16) ushortb LDS[8192];
    int bxs, bys; xcd_remap(bxs, bys);
    const int tid = threadIdx.x;
    const int wv = tid >> 6, ln = tid & 63;
    const int fr = ln & 15, fq = ln >> 4;
    const int m0 = bys << 7, n0 = bxs << 7;
    const int wr = (wv & 1) << 6, wc = (wv >> 1) << 6;

    const ushortb* gb; int ld; int rb;
    if (wv < 2) { gb = Ah; ld = lda; rb = m0; }
    else        { gb = Bh; ld = ldb; rb = n0; }
    const int half = wv & 1;
    const ushortb* gp = gb + (size_t)(rb + half*64 + (ln >> 2)) * ld
                          + (((ln & 3) ^ ((ln >> 3) & 3)) * 8);
    ushortb* lp = LDS + (wv >> 1) * 4096 + half * 2048;
    const size_t rstep = (size_t)ld << 4;
    const int sw = (fr >> 1) & 3;

    f32x4 acc[4][4] = {};
    for (int k0 = 0; k0 < K; k0 += 32) {
        __syncthreads();
        #pragma unroll
        for (int i = 0; i < 4; ++i)
            ld16(gp + (size_t)i * rstep, lp + i * 512);
        gp += 32;
        __syncthreads();
        f16x8 af[4], bf[4];
        #pragma unroll
        for (int t = 0; t < 4; ++t) {
            int ra = ((wr + t*16 + fr) << 5) + ((fq ^ sw) << 3);
            int rx = ((wc + t*16 + fr) << 5) + ((fq ^ sw) << 3);
            af[t] = *(const f16x8*)(const void*)(LDS + ra);
            bf[t] = *(const f16x8*)(const void*)(LDS + 4096 + rx);
        }
        #pragma unroll
        for (int tm = 0; tm < 4; ++tm)
            #pragma unroll
            for (int tn = 0; tn < 4; ++tn)
                acc[tm][tn] = __builtin_amdgcn_mfma_f32_16x16x32_f16(bf[tn], af[tm], acc[tm][tn], 0, 0, 0);
    }
    #pragma unroll
    for (int tm = 0; tm < 4; ++tm)
        #pragma unroll
        for (int tn = 0; tn < 4; ++tn) {
            int row  = m0 + wr + tm*16 + fr;
            int col0 = n0 + wc + tn*16 + (fq << 2);
            size_t off = (size_t)row * ldc + col0;
            float v0 = acc[tm][tn][0], v1 = acc[tm][tn][1];
            float v2 = acc[tm][tn][2], v3 = acc[tm][tn][3];
            if (bias) {
                float4 bv = *(const float4*)(bias + col0);
                v0 += bv.x; v1 += bv.y; v2 += bv.z; v3 += bv.w;
            }
            if (Rh) {
                uint2 rh = *(const uint2*)(const void*)(Rh + off);
                uint2 rl = *(const uint2*)(const void*)(Rl + off);
                v0 += h2f((ushortb)(rh.x & 0xFFFFu)) + h2f((ushortb)(rl.x & 0xFFFFu));
                v1 += h2f((ushortb)(rh.x >> 16))     + h2f((ushortb)(rl.x >> 16));
                v2 += h2f((ushortb)(rh.y & 0xFFFFu)) + h2f((ushortb)(rl.y & 0xFFFFu));
                v3 += h2f((ushortb)(rh.y >> 16))     + h2f((ushortb)(rl.y >> 16));
            }
            if (act) { v0 = gelu_f(v0); v1 = gelu_f(v1); v2 = gelu_f(v2); v3 = gelu_f(v3); }
            ushortb h0 = f2h(v0), h1 = f2h(v1), h2v = f2h(v2), h3v = f2h(v3);
            uint2 hp;
            hp.x = (unsigned)h0 | ((unsigned)h1 << 16);
            hp.y = (unsigned)h2v | ((unsigned)h3v << 16);
            *(uint2*)(void*)(Ch + off) = hp;
            if (Cl) {
                uint2 lo;
                lo.x = (unsigned)f2h(v0 - h2f(h0))  | ((unsigned)f2h(v1 - h2f(h1))  << 16);
                lo.y = (unsigned)f2h(v2 - h2f(h2v)) | ((unsigned)f2h(v3 - h2f(h3v)) << 16);
                *(uint2*)(void*)(Cl + off) = lo;
            }
        }
}

// ------------------------------------------------------------------
// Fused 6-delay gather + O-projection GEMM (operand-swapped like gemm_h1).
// A-staging computes the gather in regs and ds_writes to the SWIZZLED slot.
// ------------------------------------------------------------------
__launch_bounds__(256)
__global__ void gemm_og(const ushortb* __restrict__ Vh,
                        const int* __restrict__ DELAY, const float* __restrict__ WGT,
                        const ushortb* __restrict__ Bh, int ldb,
                        const float* __restrict__ bias,
                        const ushortb* __restrict__ Rh, const ushortb* __restrict__ Rl,
                        ushortb* __restrict__ Ch, ushortb* __restrict__ Cl,
                        int ldc, int K)
{
    __shared__ __align__(16) ushortb LDS[8192];
    int bxs, bys; xcd_remap(bxs, bys);
    const int tid = threadIdx.x;
    const int wv = tid >> 6, ln = tid & 63;
    const int fr = ln & 15, fq = ln >> 4;
    const int m0 = bys << 7, n0 = bxs << 7;
    const int wr = (wv & 1) << 6, wc = (wv >> 1) << 6;
    const int half = wv & 1;

    const int b = m0 >> 10;
    const ushortb* Vb = Vh + ((size_t)b << 19);
    int del[6]; float w6[6];
    #pragma unroll
    for (int j = 0; j < 6; ++j) { del[j] = DELAY[b*6+j]; w6[j] = WGT[b*6+j]; }

    const ushortb* gp = Bh + (size_t)(n0 + half*64 + (ln >> 2)) * ldb
                           + (((ln & 3) ^ ((ln >> 3) & 3)) * 8);
    ushortb* lp = LDS + (wv >> 1) * 4096 + half * 2048;
    const size_t rstep = (size_t)ldb << 4;
    const int sw = (fr >> 1) & 3;
    const int adst = ((ln >> 2) << 5) + (((ln & 3) ^ ((ln >> 3) & 3)) << 3);

    f32x4 acc[4][4] = {};
    for (int k0 = 0; k0 < K; k0 += 32) {
        __syncthreads();
        if (wv < 2) {
            #pragma unroll
            for (int i = 0; i < 4; ++i) {
                int t = (m0 + half*64 + (ln >> 2) + 16*i) & 1023;
                float a0=0,a1=0,a2=0,a3=0,a4=0,a5=0,a6=0,a7=0;
                #pragma unroll
                for (int j = 0; j < 6; ++j) {
                    int s = (t + del[j]) & 1023;
                    f16x8 hv = *(const f16x8*)(const void*)(Vb + (((size_t)s) << 9) + k0 + ((ln & 3) << 3));
                    float w = w6[j];
                    a0 += w * (float)hv[0]; a1 += w * (float)hv[1];
                    a2 += w * (float)hv[2]; a3 += w * (float)hv[3];
                    a4 += w * (float)hv[4]; a5 += w * (float)hv[5];
                    a6 += w * (float)hv[6]; a7 += w * (float)hv[7];
                }
                f16x8 ov;
                ov[0]=(_Float16)a0; ov[1]=(_Float16)a1; ov[2]=(_Float16)a2; ov[3]=(_Float16)a3;
                ov[4]=(_Float16)a4; ov[5]=(_Float16)a5; ov[6]=(_Float16)a6; ov[7]=(_Float16)a7;
                *(f16x8*)(void*)(lp + i*512 + adst) = ov;
            }
        } else {
            #pragma unroll
            for (int i = 0; i < 4; ++i)
                ld16(gp + (size_t)i * rstep, lp + i * 512);
            gp += 32;
        }
        __syncthreads();
        f16x8 af[4], bf[4];
        #pragma unroll
        for (int t = 0; t < 4; ++t) {
            int ra = ((wr + t*16 + fr) << 5) + ((fq ^ sw) << 3);
            int rx = ((wc + t*16 + fr) << 5) + ((fq ^ sw) << 3);
            af[t] = *(const f16x8*)(const void*)(LDS + ra);
            bf[t] = *(const f16x8*)(const void*)(LDS + 4096 + rx);
        }
        #pragma unroll
        for (int tm = 0; tm < 4; ++tm)
            #pragma unroll
            for (int tn = 0; tn < 4; ++tn)
                acc[tm][tn] = __builtin_amdgcn_mfma_f32_16x16x32_f16(bf[tn], af[tm], acc[tm][tn], 0, 0, 0);
    }
    #pragma unroll
    for (int tm = 0; tm < 4; ++tm)
        #pragma unroll
        for (int tn = 0; tn < 4; ++tn) {
            int row  = m0 + wr + tm*16 + fr;
            int col0 = n0 + wc + tn*16 + (fq << 2);
            size_t off = (size_t)row * ldc + col0;
            float4 bv = *(const float4*)(bias + col0);
            float v0 = acc[tm][tn][0] + bv.x, v1 = acc[tm][tn][1] + bv.y;
            float v2 = acc[tm][tn][2] + bv.z, v3 = acc[tm][tn][3] + bv.w;
            uint2 rh = *(const uint2*)(const void*)(Rh + off);
            uint2 rl = *(const uint2*)(const void*)(Rl + off);
            v0 += h2f((ushortb)(rh.x & 0xFFFFu)) + h2f((ushortb)(rl.x & 0xFFFFu));
            v1 += h2f((ushortb)(rh.x >> 16))     + h2f((ushortb)(rl.x >> 16));
            v2 += h2f((ushortb)(rh.y & 0xFFFFu)) + h2f((ushortb)(rl.y & 0xFFFFu));
            v3 += h2f((ushortb)(rh.y >> 16))     + h2f((ushortb)(rl.y >> 16));
            ushortb h0 = f2h(v0), h1 = f2h(v1), h2v = f2h(v2), h3v = f2h(v3);
            uint2 hp, lo;
            hp.x = (unsigned)h0 | ((unsigned)h1 << 16);
            hp.y = (unsigned)h2v | ((unsigned)h3v << 16);
            lo.x = (unsigned)f2h(v0 - h2f(h0))  | ((unsigned)f2h(v1 - h2f(h1))  << 16);
            lo.y = (unsigned)f2h(v2 - h2f(h2v)) | ((unsigned)f2h(v3 - h2f(h3v)) << 16);
            *(uint2*)(void*)(Ch + off) = hp;
            *(uint2*)(void*)(Cl + off) = lo;
        }
}

// ------------------------------------------------------------------
// FFT-based autocorrelation on TRANSPOSED pair QK: QKT[b][d][t], stride 2^20/b
// (round-6 linear layout: per-d row reads, 128B/wave coalesced, 1 read/line).
// ------------------------------------------------------------------
__device__ __forceinline__ void fft1024_tw(float* Xr, float* Xi, float* Yr, float* Yi,
                                           int tid, const float* csf, const float* snf)
{
    float *psr = Xr, *psi = Xi, *pdr = Yr, *pdi = Yi;
    #pragma unroll
    for (int st = 0; st < 10; ++st) {
        const int s = 1 << st;
        #pragma unroll
        for (int h = 0; h < 2; ++h) {
            int u = tid + (h << 8);
            int qq = u & (s - 1);
            int ps = u - qq;
            float cs = csf[st*2+h], sn = snf[st*2+h];
            float ar = psr[u],       ai = psi[u];
            float br = psr[u + 512], bi = psi[u + 512];
            int d1 = qq + (ps << 1);
            pdr[d1] = ar + br;  pdi[d1] = ai + bi;
            float tr = ar - br, ti = ai - bi;
            pdr[d1 + s] = tr * cs - ti * sn;
            pdi[d1 + s] = tr * sn + ti * cs;
        }
        __syncthreads();
        float* t0 = psr; psr = pdr; pdr = t0;
        float* t1 = psi; psi = pdi; pdi = t1;
    }
}

// grid (32, G): blockIdx.x = 16-wide d-chunk, blockIdx.y = local batch.
__launch_bounds__(256)
__global__ void corr_fft(const ushortb* __restrict__ QKh, const ushortb* __restrict__ QKl,
                         float* __restrict__ SP)
{
    __shared__ float Xr[1024], Xi[1024], Yr[1024], Yi[1024];
    const int tid = threadIdx.x;
    const int c = blockIdx.x, b = blockIdx.y;
    const size_t bbase = (size_t)b << 20;
    float csf[20], snf[20];
    #pragma unroll
    for (int st = 0; st < 10; ++st) {
        const int s = 1 << st;
        #pragma unroll
        for (int h = 0; h < 2; ++h) {
            int u = tid + (h << 8);
            int ps = u - (u & (s - 1));
            float ang = -(3.14159265358979323846f / 512.f) * (float)ps;
            __sincosf(ang, &snf[st*2+h], &csf[st*2+h]);
        }
    }
    float sr[4] = {0.f, 0.f, 0.f, 0.f};
    float si[4] = {0.f, 0.f, 0.f, 0.f};
    for (int j = 0; j < 16; ++j) {
        int d = (c << 4) + j;
        const ushortb* qh = QKh + bbase + ((size_t)d << 10);
        const ushortb* ql = QKl + bbase + ((size_t)d << 10);
        const ushortb* kh = qh + (512u << 10);
        const ushortb* kl = ql + (512u << 10);
        __syncthreads();                    // protect prior unpack reads
        #pragma unroll
        for (int i = 0; i < 4; ++i) {
            int t = tid + (i << 8);
            Xr[t] = h2f(qh[t]) + h2f(ql[t]);
            Xi[t] = h2f(kh[t]) + h2f(kl[t]);
        }
        __syncthreads();
        fft1024_tw(Xr, Xi, Yr, Yi, tid, csf, snf);
        #pragma unroll
        for (int i = 0; i < 4; ++i) {
            int f  = tid + (i << 8);
            int f2 = (1024 - f) & 1023;
            float axr = Xr[f],  axi = Xi[f];
            float cxr = Xr[f2], cxi = -Xi[f2];
            float ur = axr + cxr, ui = axi + cxi;
            float vr = axr - cxr, vi = -(axi - cxi);
            float wr_ = ur * vr - ui * vi;
            float wi_ = ur * vi + ui * vr;
            sr[i] += -0.25f * wi_;
            si[i] +=  0.25f * wr_;
        }
    }
    const size_t base = ((size_t)(b * 32 + c)) << 11;
    #pragma unroll
    for (int i = 0; i < 4; ++i) {
        int f = tid + (i << 8);
        SP[base + f]        = sr[i];
        SP[base + 1024 + f] = si[i];
    }
}

// per-b: reduce 32 chunk partials, inverse FFT, top-6 + softmax
__launch_bounds__(256)
__global__ void topk6f_fft(const float* __restrict__ SP, int* __restrict__ DELAY,
                           float* __restrict__ WGT)
{
    __shared__ float Xr[1024], Xi[1024], Yr[1024], Yi[1024];
    __shared__ float v[1024];
    __shared__ float rv[256];
    __shared__ int   ri[256];
    __shared__ float wv6[6];
    __shared__ int   wi6[6];
    const int b = blockIdx.x, tid = threadIdx.x;
    float csf[20], snf[20];
    #pragma unroll
    for (int st = 0; st < 10; ++st) {
        const int s = 1 << st;
        #pragma unroll
        for (int h = 0; h < 2; ++h) {
            int u = tid + (h << 8);
            int ps = u - (u & (s - 1));
            float ang = (3.14159265358979323846f / 512.f) * (float)ps;
            __sincosf(ang, &snf[st*2+h], &csf[st*2+h]);
        }
    }
    #pragma unroll
    for (int i = 0; i < 4; ++i) {
        int f = tid + (i << 8);
        float ar = 0.f, ai = 0.f;
        for (int c = 0; c < 32; ++c) {
            size_t base = ((size_t)(b * 32 + c)) << 11;
            ar += SP[base + f];
            ai += SP[base + 1024 + f];
        }
        Xr[f] = ar; Xi[f] = ai;
    }
    __syncthreads();
    fft1024_tw(Xr, Xi, Yr, Yi, tid, csf, snf);
    #pragma unroll
    for (int i = 0; i < 4; ++i) {
        int f = tid + (i << 8);
        v[f] = Xr[f] * (1.f / 524288.f);
    }
    __syncthreads();
    for (int it = 0; it < 6; ++it) {
        float best = v[tid]; int bi = tid;
        #pragma unroll
        for (int k = 1; k < 4; ++k) {
            int i = tid + (k << 8);
            float xv = v[i];
            if (xv > best) { best = xv; bi = i; }
        }
        rv[tid] = best; ri[tid] = bi;
        __syncthreads();
        for (int s = 128; s > 0; s >>= 1) {
            if (tid < s) {
                if (rv[tid+s] > rv[tid] || (rv[tid+s] == rv[tid] && ri[tid+s] < ri[tid])) {
                    rv[tid] = rv[tid+s]; ri[tid] = ri[tid+s];
                }
            }
            __syncthreads();
        }
        if (tid == 0) { wv6[it] = rv[0]; wi6[it] = ri[0]; v[ri[0]] = -1e30f; }
        __syncthreads();
    }
    if (tid == 0) {
        float mx = wv6[0], s = 0.f, e[6];
        #pragma unroll
        for (int i = 0; i < 6; ++i) { e[i] = expf(wv6[i] - mx); s += e[i]; }
        #pragma unroll
        for (int i = 0; i < 6; ++i) { WGT[b*6+i] = e[i]/s; DELAY[b*6+i] = wi6[i]; }
    }
}

// series_decomp pair->pair, 4 d/thread; TTs trend rows (slot: t>=511 -> t-511, t==0 -> 513)
__launch_bounds__(256)
__global__ void decomp512v(const ushortb* __restrict__ Xh, const ushortb* __restrict__ Xl,
                           ushortb* __restrict__ Sh, ushortb* __restrict__ Sl,
                           float* __restrict__ TTs, int tmode)
{
    int idx = blockIdx.x * 256 + threadIdx.x;   // TG*128
    int d0 = (idx & 127) << 2, bt = idx >> 7, t = bt & 1023;
    int base = bt - t;
    float s0=0,s1=0,s2=0,s3=0;
    #pragma unroll
    for (int w = -12; w <= 12; ++w) {
        int tt = t + w; tt = tt < 0 ? 0 : (tt > 1023 ? 1023 : tt);
        size_t ro = ((size_t)(base + tt) << 9) + d0;
        uint2 hv = *(const uint2*)(Xh + ro);
        uint2 lv = *(const uint2*)(Xl + ro);
        s0 += h2f((ushortb)(hv.x & 0xFFFFu)) + h2f((ushortb)(lv.x & 0xFFFFu));
        s1 += h2f((ushortb)(hv.x >> 16))     + h2f((ushortb)(lv.x >> 16));
        s2 += h2f((ushortb)(hv.y & 0xFFFFu)) + h2f((ushortb)(lv.y & 0xFFFFu));
        s3 += h2f((ushortb)(hv.y >> 16))     + h2f((ushortb)(lv.y >> 16));
    }
    float m0 = s0*(1.f/25.f), m1 = s1*(1.f/25.f), m2 = s2*(1.f/25.f), m3 = s3*(1.f/25.f);
    size_t co = ((size_t)bt << 9) + d0;
    uint2 chv = *(const uint2*)(Xh + co);
    uint2 clv = *(const uint2*)(Xl + co);
    float v0 = h2f((ushortb)(chv.x & 0xFFFFu)) + h2f((ushortb)(clv.x & 0xFFFFu)) - m0;
    float v1 = h2f((ushortb)(chv.x >> 16))     + h2f((ushortb)(clv.x >> 16))     - m1;
    float v2 = h2f((ushortb)(chv.y & 0xFFFFu)) + h2f((ushortb)(clv.y & 0xFFFFu)) - m2;
    float v3 = h2f((ushortb)(chv.y >> 16))     + h2f((ushortb)(clv.y >> 16))     - m3;
    ushortb h0=f2h(v0), h1=f2h(v1), h2v=f2h(v2), h3=f2h(v3);
    uint2 hp, lp;
    hp.x = (unsigned)h0 | ((unsigned)h1 << 16); hp.y = (unsigned)h2v | ((unsigned)h3 << 16);
    lp.x = (unsigned)f2h(v0-h2f(h0)) | ((unsigned)f2h(v1-h2f(h1)) << 16);
    lp.y = (unsigned)f2h(v2-h2f(h2v)) | ((unsigned)f2h(v3-h2f(h3)) << 16);
    *(uint2*)(Sh + co) = hp; *(uint2*)(Sl + co) = lp;
    if (tmode) {
        int slot = (t >= 511) ? (t - 511) : (t == 0 ? 513 : -1);
        if (slot >= 0) {
            int b = bt >> 10;
            float* tp = TTs + (size_t)b * 263168 + ((size_t)slot << 9) + d0;
            if (tmode == 1) { tp[0]=m0; tp[1]=m1; tp[2]=m2; tp[3]=m3; }
            else            { tp[0]+=m0; tp[1]+=m1; tp[2]+=m2; tp[3]+=m3; }
        }
    }
}

// per-token LN, pair in -> pair out
__launch_bounds__(256)
__global__ void ln_rows(const ushortb* __restrict__ Xh, const ushortb* __restrict__ Xl,
                        const float* __restrict__ w, const float* __restrict__ bias,
                        ushortb* __restrict__ Yh, ushortb* __restrict__ Yl)
{
    __shared__ float r1[256], r2[256];
    const int row = blockIdx.x, tid = threadIdx.x;
    size_t ro = (size_t)row * 512;
    float x0 = h2f(Xh[ro + tid]) + h2f(Xl[ro + tid]);
    float x1 = h2f(Xh[ro + tid + 256]) + h2f(Xl[ro + tid + 256]);
    r1[tid] = x0 + x1; r2[tid] = x0*x0 + x1*x1;
    __syncthreads();
    for (int s = 128; s > 0; s >>= 1) {
        if (tid < s) { r1[tid] += r1[tid+s]; r2[tid] += r2[tid+s]; }
        __syncthreads();
    }
    float mu = r1[0] * (1.f/512.f);
    float var = r2[0] * (1.f/512.f) - mu*mu;
    float rstd = rsqrtf(var + 1e-5f);
    float v0 = (x0 - mu) * rstd * w[tid]     + bias[tid];
    float v1 = (x1 - mu) * rstd * w[tid+256] + bias[tid+256];
    ushortb h0 = f2h(v0), h1 = f2h(v1);
    Yh[ro + tid] = h0;       Yl[ro + tid] = f2h(v0 - h2f(h0));
    Yh[ro + tid + 256] = h1; Yl[ro + tid + 256] = f2h(v1 - h2f(h1));
}

// column-mean partials from pair
__launch_bounds__(256)
__global__ void colmean_p(const ushortb* __restrict__ Yh, const ushortb* __restrict__ Yl,
                          float* __restrict__ PC)
{
    int i = blockIdx.x * 256 + threadIdx.x;   // G*4096
    int b = i >> 12, r = i & 4095, d = r >> 3, c = r & 7;
    size_t o = ((size_t)b << 19) + ((size_t)(c << 7) << 9) + d;
    float s = 0.f;
    for (int t = 0; t < 128; ++t) { size_t oo = o + ((size_t)t << 9); s += h2f(Yh[oo]) + h2f(Yl[oo]); }
    PC[i] = s * (1.f/1024.f);
}

// Z = Y - colmean, pair -> pair
__launch_bounds__(256)
__global__ void submean_s(const ushortb* __restrict__ Yh, const ushortb* __restrict__ Yl,
                          const float* __restrict__ PC,
                          ushortb* __restrict__ Zh, ushortb* __restrict__ Zl)
{
    int idx = blockIdx.x * 256 + threadIdx.x;
    int d = idx & 511, b = idx >> 19;
    const float* pc = PC + ((size_t)b << 12) + (d << 3);
    float m = ((pc[0]+pc[1])+(pc[2]+pc[3]))+((pc[4]+pc[5])+(pc[6]+pc[7]));
    float v = h2f(Yh[idx]) + h2f(Yl[idx]) - m;
    ushortb h = f2h(v);
    Zh[idx] = h; Zl[idx] = f2h(v - h2f(h));
}

// embedding -> pair
__launch_bounds__(256)
__global__ void embed_es(const float* __restrict__ x, const float* __restrict__ mark,
                         const float* __restrict__ Wtok, const float* __restrict__ Wtem,
                         ushortb* __restrict__ Oh, ushortb* __restrict__ Ol)
{
    int idx = blockIdx.x * 256 + threadIdx.x;
    int d = idx & 511, bt = idx >> 9, t = bt & 1023, b = bt >> 10;
    float acc = 0.f;
    #pragma unroll
    for (int j = 0; j < 3; ++j) {
        int tt = (t + 1023 + j) & 1023;
        const float* xr = x + (size_t)(b*1024 + tt)*7;
        #pragma unroll
        for (int c = 0; c < 7; ++c)
            acc += xr[c] * Wtok[(j*7+c)*512 + d];
    }
    const float* mr = mark + (size_t)bt*4;
    #pragma unroll
    for (int m = 0; m < 4; ++m) acc += mr[m] * Wtem[m*512 + d];
    ushortb h = f2h(acc);
    Oh[idx] = h; Ol[idx] = f2h(acc - h2f(h));
}

__launch_bounds__(256)
__global__ void mean7(const float* __restrict__ x, float* __restrict__ M7)
{
    __shared__ float r[256];
    int bc = blockIdx.x, b = bc / 7, c = bc % 7, tid = threadIdx.x;
    float s = 0.f;
    for (int t = tid; t < 1024; t += 256) s += x[(size_t)(b*1024+t)*7 + c];
    r[tid] = s; __syncthreads();
    for (int st = 128; st > 0; st >>= 1) { if (tid < st) r[tid] += r[tid+st]; __syncthreads(); }
    if (tid == 0) M7[bc] = r[0] * (1.f/1024.f);
}

__launch_bounds__(256)
__global__ void decomp7(const float* __restrict__ x, const float* __restrict__ M7,
                        float* __restrict__ SEAS7, float* __restrict__ TREND7)
{
    int idx = blockIdx.x * 256 + threadIdx.x;  // TG*7
    int c = idx % 7, bt = idx / 7, t = bt & 1023, b = bt >> 10;
    if (t < 512) {
        int s0 = t + 512;
        float s = 0.f;
        #pragma unroll
        for (int w = -12; w <= 12; ++w) {
            int tt = s0 + w; tt = tt < 0 ? 0 : (tt > 1023 ? 1023 : tt);
            s += x[(size_t)(b*1024+tt)*7 + c];
        }
        float m = s * (1.f/25.f);
        SEAS7[idx] = x[(size_t)(b*1024+s0)*7 + c] - m;
        TREND7[idx] = m;
    } else {
        SEAS7[idx] = 0.f;
        TREND7[idx] = M7[b*7 + c];
    }
}

// fused: out = projb + TREND7 + X@projW + circ_conv3(TTs)@dec_trend_W  (rows t>=512)
__launch_bounds__(256)
__global__ void final_fused(const ushortb* __restrict__ Xh, const ushortb* __restrict__ Xl,
                            const float* __restrict__ PW, const float* __restrict__ PB,
                            const float* __restrict__ TW, const float* __restrict__ TTs,
                            const float* __restrict__ TREND7, float* __restrict__ out)
{
    __shared__ float WT[10752];   // 3*512*7
    __shared__ float WP[3584];    // 512*7
    for (int i = threadIdx.x; i < 10752; i += 256) WT[i] = TW[i];
    for (int i = threadIdx.x; i < 3584; i += 256) WP[i] = PW[i];
    __syncthreads();
    int idx = blockIdx.x * 256 + threadIdx.x;  // G*512*7
    int c = idx % 7, btt = idx / 7, tt = btt & 511, b = btt >> 9;
    int t = tt + 512;
    float acc = PB[c] + TREND7[(size_t)(b*1024 + t)*7 + c];
    size_t ro = ((size_t)(b*1024 + t) << 9);
    for (int d = 0; d < 512; ++d)
        acc += (h2f(Xh[ro + d]) + h2f(Xl[ro + d])) * WP[d*7 + c];
    for (int j = 0; j < 3; ++j) {
        int t2 = t - 1 + j;
        int slot = (t2 >= 1024) ? 513 : (t2 - 511);
        const float* r = TTs + (size_t)b * 263168 + ((size_t)slot << 9);
        const float* wj = WT + j*3584 + c;
        for (int d = 0; d < 512; ++d) acc += r[d] * wj[d*7];
    }
    out[idx] = acc;
}

// attn weight transpose+split pool (block a: 1572864 elems):
// QKh@0 (1024x512), QKl@524288, Vh@1048576, Oh@1310720
__launch_bounds__(256)
__global__ void wsplit_att(const float* __restrict__ W, ushortb* __restrict__ pool, int which)
{
    __shared__ float t[32][33];
    const int m = blockIdx.z;
    const int kb = blockIdx.y << 5, nb = blockIdx.x << 5;
    const int c = threadIdx.x & 31, rr = threadIdx.x >> 5;
    const float* Wm = W + (size_t)m * 262144;
    #pragma unroll
    for (int i = 0; i < 4; ++i)
        t[rr + i*8][c] = Wm[(size_t)(kb + rr + i*8) * 512 + nb + c];
    __syncthreads();
    const int a = (which == 0) ? (m >> 2) : (which + 1);
    const int j = (which == 0) ? (m & 3) : m;
    size_t hi, lo; bool haslo;
    if (j == 0)      { hi = 0;       lo = 524288; haslo = true; }
    else if (j == 1) { hi = 262144;  lo = 786432; haslo = true; }
    else if (j == 2) { hi = 1048576; lo = 0; haslo = false; }
    else             { hi = 1310720; lo = 0; haslo = false; }
    ushortb* pb = pool + (size_t)a * 1572864;
    #pragma unroll
    for (int i = 0; i < 4; ++i) {
        int n = nb + rr + i*8, k = kb + c;
        float v = t[c][rr + i*8];
        ushortb h = f2h(v);
        pb[hi + (size_t)n * 512 + k] = h;
        if (haslo) pb[lo + (size_t)n * 512 + k] = f2h(v - h2f(h));
    }
}

__launch_bounds__(256)
__global__ void wsplit_ff(const float* __restrict__ W, ushortb* __restrict__ dh,
                          int K, int N)
{
    __shared__ float t[32][33];
    const int m = blockIdx.z;
    const int kb = blockIdx.y << 5, nb = blockIdx.x << 5;
    const int c = threadIdx.x & 31, rr = threadIdx.x >> 5;
    const float* Wm = W + (size_t)m * K * N;
    #pragma unroll
    for (int i = 0; i < 4; ++i)
        t[rr + i*8][c] = Wm[(size_t)(kb + rr + i*8) * N + nb + c];
    __syncthreads();
    ushortb* Dh = dh + (size_t)m * 1048576;
    #pragma unroll
    for (int i = 0; i < 4; ++i) {
        int n = nb + rr + i*8, k = kb + c;
        Dh[(size_t)n * K + k] = f2h(t[c][rr + i*8]);
    }
}

__launch_bounds__(256)
__global__ void sentinel(float* __restrict__ out, int n)
{
    int i = blockIdx.x * 256 + threadIdx.x;
    if (i < n) out[i] = -54321.0f;
}

// ------------------------------------------------------------------
extern "C" void kernel_launch(void* const* d_in, const int* in_sizes, int n_in,
                              void* d_out, int out_size, void* d_ws, size_t ws_size,
                              hipStream_t stream)
{
    const float* x_enc      = (const float*)d_in[0];
    const float* x_mark_enc = (const float*)d_in[1];
    const float* x_mark_dec = (const float*)d_in[3];
    const float* W_enc_tok  = (const float*)d_in[4];
    const float* W_enc_tem  = (const float*)d_in[5];
    const float* W_dec_tok  = (const float*)d_in[6];
    const float* W_dec_tem  = (const float*)d_in[7];
    const float* enc_attn_W = (const float*)d_in[8];
    const float* enc_attn_b = (const float*)d_in[9];
    const float* enc_ff1    = (const float*)d_in[10];
    const float* enc_ff2    = (const float*)d_in[11];
    const float* enc_ln_w   = (const float*)d_in[12];
    const float* enc_ln_b   = (const float*)d_in[13];
    const float* dec_self_W = (const float*)d_in[14];
    const float* dec_self_b = (const float*)d_in[15];
    const float* dec_cross_W= (const float*)d_in[16];
    const float* dec_cross_b= (const float*)d_in[17];
    const float* dec_ff1    = (const float*)d_in[18];
    const float* dec_ff2    = (const float*)d_in[19];
    const float* dec_trend_W= (const float*)d_in[20];
    const float* dec_ln_w   = (const float*)d_in[21];
    const float* dec_ln_b   = (const float*)d_in[22];
    const float* proj_W     = (const float*)d_in[23];
    const float* proj_b     = (const float*)d_in[24];
    float* out = (float*)d_out;

    const size_t ATT_E = (size_t)4 * 1572864;
    const size_t FF_E  = (size_t)3 * 1048576;
    const size_t WBYTES = (ATT_E + 2 * FF_E) * 2 + 4096;

    auto need = [&](long g) -> size_t {
        size_t TGl = (size_t)g * 1024;
        size_t pairs = 3 * TGl * 2048;            // SA, TMP, SE pairs
        size_t qk    = TGl * 4096;                // QK pair / MID
        size_t vh    = TGl * 1024;
        size_t tts   = (size_t)g * 263168 * 4;
        size_t pbin  = (size_t)g * 262144;
        size_t misc  = (size_t)g * (16384 + 28 + 28672 + 28672 + 64) + 65536;
        return WBYTES + pairs + qk + vh + tts + pbin + misc + 16384;
    };
    int G = 0;
    for (int g = 32; g >= 1; g >>= 1) if (need(g) <= ws_size) { G = g; break; }
    if (G == 0) {
        sentinel<<<(out_size + 255) / 256, 256, 0, stream>>>(out, out_size);
        return;
    }
    const int TG = G * 1024;

    char* p = (char*)d_ws;
    auto carve = [&](size_t bytes) -> char* {
        char* r = p; p += (bytes + 255) & ~(size_t)255; return r;
    };
    ushortb* ATT = (ushortb*)carve(ATT_E * 2);
    ushortb* FF1 = (ushortb*)carve(FF_E * 2);
    ushortb* FF2 = (ushortb*)carve(FF_E * 2);

    const size_t SPLB = (size_t)TG * 512 * 2;
    ushortb* SAh = (ushortb*)carve(SPLB);
    ushortb* SAl = (ushortb*)carve(SPLB);
    ushortb* TMh = (ushortb*)carve(SPLB);
    ushortb* TMl = (ushortb*)carve(SPLB);
    ushortb* SEh = (ushortb*)carve(SPLB);
    ushortb* SEl = (ushortb*)carve(SPLB);
    char* R1 = carve((size_t)TG * 4096);             // QKTh+QKTl pair / MID
    ushortb* Vh = (ushortb*)carve((size_t)TG * 1024);
    float* TTs   = (float*)carve((size_t)G * 263168 * 4);
    float* PBIN  = (float*)carve((size_t)G * 262144);   // S-partials [b][32][2][1024] f32
    float* PC    = (float*)carve((size_t)G * 16384);
    float* M7    = (float*)carve((size_t)G * 28);
    float* SEAS7 = (float*)carve((size_t)G * 28672);
    float* TREND7= (float*)carve((size_t)G * 28672);
    float* WGT   = (float*)carve((size_t)G * 24);
    int*   DELAY = (int*)  carve((size_t)G * 24);

    ushortb* QKh = (ushortb*)R1;                       // transposed [b][d][t]
    ushortb* QKl = QKh + (size_t)TG * 1024;
    ushortb* MIDh = (ushortb*)R1;

    // ---- weight transforms ----
    wsplit_att<<<dim3(16,16,8),256,0,stream>>>(enc_attn_W, ATT, 0);
    wsplit_att<<<dim3(16,16,4),256,0,stream>>>(dec_self_W, ATT, 1);
    wsplit_att<<<dim3(16,16,4),256,0,stream>>>(dec_cross_W, ATT, 2);
    wsplit_ff<<<dim3(64,16,2),256,0,stream>>>(enc_ff1, FF1, 512, 2048);
    wsplit_ff<<<dim3(64,16,1),256,0,stream>>>(dec_ff1, FF1 + (size_t)2*1048576, 512, 2048);
    wsplit_ff<<<dim3(16,64,2),256,0,stream>>>(enc_ff2, FF2, 2048, 512);
    wsplit_ff<<<dim3(16,64,1),256,0,stream>>>(dec_ff2, FF2 + (size_t)2*1048576, 2048, 512);

    for (int g0 = 0; g0 < 32; g0 += G) {
        const float* xe  = x_enc      + (size_t)g0 * 1024 * 7;
        const float* me  = x_mark_enc + (size_t)g0 * 1024 * 4;
        const float* md  = x_mark_dec + (size_t)g0 * 1024 * 4;
        float*       outg= out        + (size_t)g0 * 512 * 7;
        const int GB = G * 8;   // TG/128

        auto corr_gather_oproj = [&](const ushortb* base, const float* bv,
                                     const ushortb* rh, const ushortb* rl) {
            corr_fft<<<dim3(32,G),256,0,stream>>>(QKh, QKl, PBIN);
            topk6f_fft<<<G,256,0,stream>>>(PBIN, DELAY, WGT);
            gemm_og<<<dim3(4,GB),256,0,stream>>>(Vh, DELAY, WGT,
                                                 base+1310720,512, bv+1536,
                                                 rh,rl, TMh,TMl, 512, 512);
        };
        auto attn_self = [&](const ushortb* xh, const ushortb* xl, int a, const float* bv) {
            const ushortb* base = ATT + (size_t)a * 1572864;
            gemm_h3<<<dim3(8,GB),256,0,stream>>>(xh,xl,512, base,base+524288,512, bv,
                                                 QKh,QKl, 512);
            gemm_h1<<<dim3(4,GB),256,0,stream>>>(xh,512, base+1048576,512, bv+1024,
                                                 nullptr,nullptr, Vh,nullptr, 512, 512, 0);
            corr_gather_oproj(base, bv, xh, xl);
        };
        auto attn_cross = [&](const ushortb* qh, const ushortb* ql,
                              const ushortb* kvh, const ushortb* kvl,
                              int a, const float* bv) {
            const ushortb* base = ATT + (size_t)a * 1572864;
            gemm_h3<<<dim3(4,GB),256,0,stream>>>(qh,ql,512, base,base+524288,512, bv,
                                                 QKh,QKl, 512);
            gemm_h3<<<dim3(4,GB),256,0,stream>>>(kvh,kvl,512, base+262144,base+786432,512, bv+512,
                                                 QKh+524288,QKl+524288, 512);
            gemm_h1<<<dim3(4,GB),256,0,stream>>>(kvh,512, base+1048576,512, bv+1024,
                                                 nullptr,nullptr, Vh,nullptr, 512, 512, 0);
            corr_gather_oproj(base, bv, qh, ql);
        };
        auto ffn = [&](const ushortb* xh, const ushortb* xl, int fi) {
            gemm_h1<<<dim3(16,GB),256,0,stream>>>(xh,512, FF1 + (size_t)fi*1048576,512, nullptr,
                                                  nullptr,nullptr, MIDh,nullptr, 2048, 512, 1);
            gemm_h1<<<dim3(4,GB),256,0,stream>>>(MIDh,2048, FF2 + (size_t)fi*1048576,2048, nullptr,
                                                 xh,xl, TMh,TMl, 512, 2048, 0);
        };

        // ---------------- encoder ----------------
        embed_es<<<TG*2,256,0,stream>>>(xe, me, W_enc_tok, W_enc_tem, SAh, SAl);
        for (int l = 0; l < 2; ++l) {
            attn_self(SAh, SAl, l, enc_attn_b + (size_t)l*4*512);
            decomp512v<<<TG/2,256,0,stream>>>(TMh, TMl, SAh, SAl, nullptr, 0);
            ffn(SAh, SAl, l);
            decomp512v<<<TG/2,256,0,stream>>>(TMh, TMl, SAh, SAl, nullptr, 0);
        }
        ln_rows<<<TG,256,0,stream>>>(SAh, SAl, enc_ln_w, enc_ln_b, TMh, TMl);
        colmean_p<<<G*16,256,0,stream>>>(TMh, TMl, PC);
        submean_s<<<TG*2,256,0,stream>>>(TMh, TMl, PC, SEh, SEl);

        // ---------------- decoder prep ----------------
        mean7<<<G*7,256,0,stream>>>(xe, M7);
        decomp7<<<G*28,256,0,stream>>>(xe, M7, SEAS7, TREND7);
        embed_es<<<TG*2,256,0,stream>>>(SEAS7, md, W_dec_tok, W_dec_tem, SAh, SAl);

        // ---------------- decoder layer ----------------
        attn_self(SAh, SAl, 2, dec_self_b);
        decomp512v<<<TG/2,256,0,stream>>>(TMh, TMl, SAh, SAl, TTs, 1);

        attn_cross(SAh, SAl, SEh, SEl, 3, dec_cross_b);
        decomp512v<<<TG/2,256,0,stream>>>(TMh, TMl, SAh, SAl, TTs, 2);

        ffn(SAh, SAl, 2);
        decomp512v<<<TG/2,256,0,stream>>>(TMh, TMl, SAh, SAl, TTs, 2);

        ln_rows<<<TG,256,0,stream>>>(SAh, SAl, dec_ln_w, dec_ln_b, TMh, TMl);
        colmean_p<<<G*16,256,0,stream>>>(TMh, TMl, PC);
        submean_s<<<TG*2,256,0,stream>>>(TMh, TMl, PC, SAh, SAl);

        final_fused<<<G*14,256,0,stream>>>(SAh, SAl, proj_W, proj_b, dec_trend_W,
                                           TTs, TREND7, outg);
    }
}

// Round 9
// 3409.596 us; speedup vs baseline: 1.3536x; 1.1535x over previous
//
#include <hip/hip_runtime.h>

typedef unsigned short ushortb;
typedef __attribute__((ext_vector_type(8))) _Float16 f16x8;
typedef __attribute__((ext_vector_type(4))) float f32x4;

__device__ __forceinline__ float h2f(ushortb u) {
    _Float16 h; __builtin_memcpy(&h, &u, 2); return (float)h;
}
__device__ __forceinline__ ushortb f2h(float f) {
    _Float16 h = (_Float16)f; ushortb u; __builtin_memcpy(&u, &h, 2); return u;
}
// tanh-approx GELU == x * sigmoid(1.5957691x + 0.0713548x^3); |err| < ~3e-4 vs erf GELU.
__device__ __forceinline__ float gelu_f(float x) {
    float z = x * (1.59576912f + 0.0713548128f * x * x);
    return x / (1.f + __expf(-z));
}

__device__ __forceinline__ void ld16(const void* g, void* l) {
    __builtin_amdgcn_global_load_lds(
        (const __attribute__((address_space(1))) unsigned int*)g,
        (__attribute__((address_space(3))) unsigned int*)l, 16, 0, 0);
}

// XCD-aware remap: each XCD gets a contiguous tile range so blocks sharing an
// A row-panel land on one XCD's L2. Bijective when total%8==0.
__device__ __forceinline__ void xcd_remap(int& bx, int& by) {
    int nx = gridDim.x;
    int total = nx * gridDim.y;
    bx = blockIdx.x; by = blockIdx.y;
    if ((total & 7) == 0) {
        int lin = by * nx + bx;
        int lin2 = (lin & 7) * (total >> 3) + (lin >> 3);
        by = lin2 / nx; bx = lin2 % nx;
    }
}

// LDS staging swizzle (rule #21): linear global_load_lds dest + swizzled SOURCE
// col + matching XOR on fragment reads.
//   staging source col-chunk: (ln&3) ^ ((ln>>3)&3)
//   fragment read slot:        fq    ^ ((fr>>1)&3)

// ------------------------------------------------------------------
// 3-term split-fp16 MFMA GEMM (NT), pair in -> pair out (fp32 fidelity)
// QK-producer only: TRANSPOSED output QKT[b][d][t] (linear layout,
// per-batch stride 2^20). LDS-transposed epilogue for coalesced stores.
// ------------------------------------------------------------------
__launch_bounds__(256)
__global__ void gemm_h3(const ushortb* __restrict__ Ah, const ushortb* __restrict__ Al,
                        int lda,
                        const ushortb* __restrict__ Bh, const ushortb* __restrict__ Bl,
                        int ldb,
                        const float* __restrict__ bias,
                        ushortb* __restrict__ Ch, ushortb* __restrict__ Cl, int K)
{
    __shared__ __align__(16) ushortb LDS[16384];    // 32 KB
    int bxs, bys; xcd_remap(bxs, bys);
    const int tid = threadIdx.x;
    const int wv = tid >> 6, ln = tid & 63;
    const int fr = ln & 15, fq = ln >> 4;
    const int m0 = bys << 7, n0 = bxs << 7;
    const int wr = (wv & 1) << 6, wc = (wv >> 1) << 6;

    const ushortb* gb; int ld;
    if (wv == 0)      { gb = Ah; ld = lda; }
    else if (wv == 1) { gb = Al; ld = lda; }
    else if (wv == 2) { gb = Bh; ld = ldb; }
    else              { gb = Bl; ld = ldb; }
    const int rbase = (wv < 2) ? m0 : n0;
    const ushortb* gp = gb + (size_t)(rbase + (ln >> 2)) * ld
                          + (((ln & 3) ^ ((ln >> 3) & 3)) * 8);
    ushortb* lplane = LDS + wv * 4096;
    const size_t rstep = (size_t)ld << 4;
    const int sw = (fr >> 1) & 3;

    f32x4 acc[4][4] = {};
    for (int k0 = 0; k0 < K; k0 += 32) {
        __syncthreads();
        #pragma unroll
        for (int i = 0; i < 8; ++i)
            ld16(gp + (size_t)i * rstep, lplane + i * 512);
        gp += 32;
        __syncthreads();
        f16x8 afh[4], afl[4], bfh[4], bfl[4];
        #pragma unroll
        for (int t = 0; t < 4; ++t) {
            int ra = ((wr + t*16 + fr) << 5) + ((fq ^ sw) << 3);
            int rb = ((wc + t*16 + fr) << 5) + ((fq ^ sw) << 3);
            afh[t] = *(const f16x8*)(const void*)(LDS + ra);
            afl[t] = *(const f16x8*)(const void*)(LDS + 4096 + ra);
            bfh[t] = *(const f16x8*)(const void*)(LDS + 8192 + rb);
            bfl[t] = *(const f16x8*)(const void*)(LDS + 12288 + rb);
        }
        #pragma unroll
        for (int tm = 0; tm < 4; ++tm)
            #pragma unroll
            for (int tn = 0; tn < 4; ++tn) {
                f32x4 c = acc[tm][tn];
                c = __builtin_amdgcn_mfma_f32_16x16x32_f16(afh[tm], bfh[tn], c, 0, 0, 0);
                c = __builtin_amdgcn_mfma_f32_16x16x32_f16(afl[tm], bfh[tn], c, 0, 0, 0);
                c = __builtin_amdgcn_mfma_f32_16x16x32_f16(afh[tm], bfl[tn], c, 0, 0, 0);
                acc[tm][tn] = c;
            }
    }
    // ---- LDS-transposed epilogue ----
    const size_t bb = (size_t)(m0 >> 10) * 1048576;   // batch base
    const int trow0 = m0 & 1023;                      // block's t-range base
    const int PS = 4224;                              // 32*132 (pad 4)
    ushortb* EH = LDS;
    ushortb* EL = LDS + PS;
    const int cl  = ((wv >> 1) << 4) + fr;            // local col 0..31
    const int rcl = tid >> 3, seg = tid & 7;          // reader mapping
    #pragma unroll
    for (int tn = 0; tn < 4; ++tn) {
        __syncthreads();                              // LDS free / prev pass done
        int col = n0 + ((wv >> 1) << 6) + tn*16 + fr;
        float bset = bias ? bias[col] : 0.f;
        #pragma unroll
        for (int tm = 0; tm < 4; ++tm) {
            int tl = ((wv & 1) << 6) + tm*16 + (fq << 2);
            float v0 = acc[tm][tn][0] + bset;
            float v1 = acc[tm][tn][1] + bset;
            float v2 = acc[tm][tn][2] + bset;
            float v3 = acc[tm][tn][3] + bset;
            ushortb h0 = f2h(v0), h1 = f2h(v1), h2v = f2h(v2), h3v = f2h(v3);
            uint2 hp, lp_;
            hp.x  = (unsigned)h0 | ((unsigned)h1 << 16);
            hp.y  = (unsigned)h2v | ((unsigned)h3v << 16);
            lp_.x = (unsigned)f2h(v0 - h2f(h0))  | ((unsigned)f2h(v1 - h2f(h1))  << 16);
            lp_.y = (unsigned)f2h(v2 - h2f(h2v)) | ((unsigned)f2h(v3 - h2f(h3v)) << 16);
            *(uint2*)(void*)(EH + cl*132 + tl) = hp;
            *(uint2*)(void*)(EL + cl*132 + tl) = lp_;
        }
        __syncthreads();
        int gcol = n0 + ((rcl >> 4) << 6) + tn*16 + (rcl & 15);
        size_t goff = bb + (size_t)gcol * 1024 + trow0 + (seg << 4);
        const ushortb* sh = EH + rcl*132 + (seg << 4);
        const ushortb* sl = EL + rcl*132 + (seg << 4);
        #pragma unroll
        for (int i = 0; i < 4; ++i) {
            *(uint2*)(void*)(Ch + goff + i*4) = *(const uint2*)(const void*)(sh + i*4);
            *(uint2*)(void*)(Cl + goff + i*4) = *(const uint2*)(const void*)(sl + i*4);
        }
    }
}

// ------------------------------------------------------------------
// Single-term fp16 MFMA GEMM (NT), OPERAND-SWAPPED (row=fr, col=fq*4+r):
// coalesced 8B uint2 stores. Optional pair resid, pair/single out, gelu.
// ------------------------------------------------------------------
__launch_bounds__(256)
__global__ void gemm_h1(const ushortb* __restrict__ Ah, int lda,
                        const ushortb* __restrict__ Bh, int ldb,
                        const float* __restrict__ bias,
                        const ushortb* __restrict__ Rh, const ushortb* __restrict__ Rl,
                        ushortb* __restrict__ Ch, ushortb* __restrict__ Cl,
                        int ldc, int K, int act)
{
    __shared__ __align__(16) ushortb LDS[8192];
    int bxs, bys; xcd_remap(bxs, bys);
    const int tid = threadIdx.x;
    const int wv = tid >> 6, ln = tid & 63;
    const int fr = ln & 15, fq = ln >> 4;
    const int m0 = bys << 7, n0 = bxs << 7;
    const int wr = (wv & 1) << 6, wc = (wv >> 1) << 6;

    const ushortb* gb; int ld; int rb;
    if (wv < 2) { gb = Ah; ld = lda; rb = m0; }
    else        { gb = Bh; ld = ldb; rb = n0; }
    const int half = wv & 1;
    const ushortb* gp = gb + (size_t)(rb + half*64 + (ln >> 2)) * ld
                          + (((ln & 3) ^ ((ln >> 3) & 3)) * 8);
    ushortb* lp = LDS + (wv >> 1) * 4096 + half * 2048;
    const size_t rstep = (size_t)ld << 4;
    const int sw = (fr >> 1) & 3;

    f32x4 acc[4][4] = {};
    for (int k0 = 0; k0 < K; k0 += 32) {
        __syncthreads();
        #pragma unroll
        for (int i = 0; i < 4; ++i)
            ld16(gp + (size_t)i * rstep, lp + i * 512);
        gp += 32;
        __syncthreads();
        f16x8 af[4], bf[4];
        #pragma unroll
        for (int t = 0; t < 4; ++t) {
            int ra = ((wr + t*16 + fr) << 5) + ((fq ^ sw) << 3);
            int rx = ((wc + t*16 + fr) << 5) + ((fq ^ sw) << 3);
            af[t] = *(const f16x8*)(const void*)(LDS + ra);
            bf[t] = *(const f16x8*)(const void*)(LDS + 4096 + rx);
        }
        #pragma unroll
        for (int tm = 0; tm < 4; ++tm)
            #pragma unroll
            for (int tn = 0; tn < 4; ++tn)
                acc[tm][tn] = __builtin_amdgcn_mfma_f32_16x16x32_f16(bf[tn], af[tm], acc[tm][tn], 0, 0, 0);
    }
    #pragma unroll
    for (int tm = 0; tm < 4; ++tm)
        #pragma unroll
        for (int tn = 0; tn < 4; ++tn) {
            int row  = m0 + wr + tm*16 + fr;
            int col0 = n0 + wc + tn*16 + (fq << 2);
            size_t off = (size_t)row * ldc + col0;
            float v0 = acc[tm][tn][0], v1 = acc[tm][tn][1];
            float v2 = acc[tm][tn][2], v3 = acc[tm][tn][3];
            if (bias) {
                float4 bv = *(const float4*)(bias + col0);
                v0 += bv.x; v1 += bv.y; v2 += bv.z; v3 += bv.w;
            }
            if (Rh) {
                uint2 rh = *(const uint2*)(const void*)(Rh + off);
                uint2 rl = *(const uint2*)(const void*)(Rl + off);
                v0 += h2f((ushortb)(rh.x & 0xFFFFu)) + h2f((ushortb)(rl.x & 0xFFFFu));
                v1 += h2f((ushortb)(rh.x >> 16))     + h2f((ushortb)(rl.x >> 16));
                v2 += h2f((ushortb)(rh.y & 0xFFFFu)) + h2f((ushortb)(rl.y & 0xFFFFu));
                v3 += h2f((ushortb)(rh.y >> 16))     + h2f((ushortb)(rl.y >> 16));
            }
            if (act) { v0 = gelu_f(v0); v1 = gelu_f(v1); v2 = gelu_f(v2); v3 = gelu_f(v3); }
            ushortb h0 = f2h(v0), h1 = f2h(v1), h2v = f2h(v2), h3v = f2h(v3);
            uint2 hp;
            hp.x = (unsigned)h0 | ((unsigned)h1 << 16);
            hp.y = (unsigned)h2v | ((unsigned)h3v << 16);
            *(uint2*)(void*)(Ch + off) = hp;
            if (Cl) {
                uint2 lo;
                lo.x = (unsigned)f2h(v0 - h2f(h0))  | ((unsigned)f2h(v1 - h2f(h1))  << 16);
                lo.y = (unsigned)f2h(v2 - h2f(h2v)) | ((unsigned)f2h(v3 - h2f(h3v)) << 16);
                *(uint2*)(void*)(Cl + off) = lo;
            }
        }
}

// ------------------------------------------------------------------
// Fused 6-delay gather + O-projection GEMM (operand-swapped like gemm_h1).
// A-staging computes the gather in regs and ds_writes to the SWIZZLED slot.
// ------------------------------------------------------------------
__launch_bounds__(256)
__global__ void gemm_og(const ushortb* __restrict__ Vh,
                        const int* __restrict__ DELAY, const float* __restrict__ WGT,
                        const ushortb* __restrict__ Bh, int ldb,
                        const float* __restrict__ bias,
                        const ushortb* __restrict__ Rh, const ushortb* __restrict__ Rl,
                        ushortb* __restrict__ Ch, ushortb* __restrict__ Cl,
                        int ldc, int K)
{
    __shared__ __align__(16) ushortb LDS[8192];
    int bxs, bys; xcd_remap(bxs, bys);
    const int tid = threadIdx.x;
    const int wv = tid >> 6, ln = tid & 63;
    const int fr = ln & 15, fq = ln >> 4;
    const int m0 = bys << 7, n0 = bxs << 7;
    const int wr = (wv & 1) << 6, wc = (wv >> 1) << 6;
    const int half = wv & 1;

    const int b = m0 >> 10;
    const ushortb* Vb = Vh + ((size_t)b << 19);
    int del[6]; float w6[6];
    #pragma unroll
    for (int j = 0; j < 6; ++j) { del[j] = DELAY[b*6+j]; w6[j] = WGT[b*6+j]; }

    const ushortb* gp = Bh + (size_t)(n0 + half*64 + (ln >> 2)) * ldb
                           + (((ln & 3) ^ ((ln >> 3) & 3)) * 8);
    ushortb* lp = LDS + (wv >> 1) * 4096 + half * 2048;
    const size_t rstep = (size_t)ldb << 4;
    const int sw = (fr >> 1) & 3;
    const int adst = ((ln >> 2) << 5) + (((ln & 3) ^ ((ln >> 3) & 3)) << 3);

    f32x4 acc[4][4] = {};
    for (int k0 = 0; k0 < K; k0 += 32) {
        __syncthreads();
        if (wv < 2) {
            #pragma unroll
            for (int i = 0; i < 4; ++i) {
                int t = (m0 + half*64 + (ln >> 2) + 16*i) & 1023;
                float a0=0,a1=0,a2=0,a3=0,a4=0,a5=0,a6=0,a7=0;
                #pragma unroll
                for (int j = 0; j < 6; ++j) {
                    int s = (t + del[j]) & 1023;
                    f16x8 hv = *(const f16x8*)(const void*)(Vb + (((size_t)s) << 9) + k0 + ((ln & 3) << 3));
                    float w = w6[j];
                    a0 += w * (float)hv[0]; a1 += w * (float)hv[1];
                    a2 += w * (float)hv[2]; a3 += w * (float)hv[3];
                    a4 += w * (float)hv[4]; a5 += w * (float)hv[5];
                    a6 += w * (float)hv[6]; a7 += w * (float)hv[7];
                }
                f16x8 ov;
                ov[0]=(_Float16)a0; ov[1]=(_Float16)a1; ov[2]=(_Float16)a2; ov[3]=(_Float16)a3;
                ov[4]=(_Float16)a4; ov[5]=(_Float16)a5; ov[6]=(_Float16)a6; ov[7]=(_Float16)a7;
                *(f16x8*)(void*)(lp + i*512 + adst) = ov;
            }
        } else {
            #pragma unroll
            for (int i = 0; i < 4; ++i)
                ld16(gp + (size_t)i * rstep, lp + i * 512);
            gp += 32;
        }
        __syncthreads();
        f16x8 af[4], bf[4];
        #pragma unroll
        for (int t = 0; t < 4; ++t) {
            int ra = ((wr + t*16 + fr) << 5) + ((fq ^ sw) << 3);
            int rx = ((wc + t*16 + fr) << 5) + ((fq ^ sw) << 3);
            af[t] = *(const f16x8*)(const void*)(LDS + ra);
            bf[t] = *(const f16x8*)(const void*)(LDS + 4096 + rx);
        }
        #pragma unroll
        for (int tm = 0; tm < 4; ++tm)
            #pragma unroll
            for (int tn = 0; tn < 4; ++tn)
                acc[tm][tn] = __builtin_amdgcn_mfma_f32_16x16x32_f16(bf[tn], af[tm], acc[tm][tn], 0, 0, 0);
    }
    #pragma unroll
    for (int tm = 0; tm < 4; ++tm)
        #pragma unroll
        for (int tn = 0; tn < 4; ++tn) {
            int row  = m0 + wr + tm*16 + fr;
            int col0 = n0 + wc + tn*16 + (fq << 2);
            size_t off = (size_t)row * ldc + col0;
            float4 bv = *(const float4*)(bias + col0);
            float v0 = acc[tm][tn][0] + bv.x, v1 = acc[tm][tn][1] + bv.y;
            float v2 = acc[tm][tn][2] + bv.z, v3 = acc[tm][tn][3] + bv.w;
            uint2 rh = *(const uint2*)(const void*)(Rh + off);
            uint2 rl = *(const uint2*)(const void*)(Rl + off);
            v0 += h2f((ushortb)(rh.x & 0xFFFFu)) + h2f((ushortb)(rl.x & 0xFFFFu));
            v1 += h2f((ushortb)(rh.x >> 16))     + h2f((ushortb)(rl.x >> 16));
            v2 += h2f((ushortb)(rh.y & 0xFFFFu)) + h2f((ushortb)(rl.y & 0xFFFFu));
            v3 += h2f((ushortb)(rh.y >> 16))     + h2f((ushortb)(rl.y >> 16));
            ushortb h0 = f2h(v0), h1 = f2h(v1), h2v = f2h(v2), h3v = f2h(v3);
            uint2 hp, lo;
            hp.x = (unsigned)h0 | ((unsigned)h1 << 16);
            hp.y = (unsigned)h2v | ((unsigned)h3v << 16);
            lo.x = (unsigned)f2h(v0 - h2f(h0))  | ((unsigned)f2h(v1 - h2f(h1))  << 16);
            lo.y = (unsigned)f2h(v2 - h2f(h2v)) | ((unsigned)f2h(v3 - h2f(h3v)) << 16);
            *(uint2*)(void*)(Ch + off) = hp;
            *(uint2*)(void*)(Cl + off) = lo;
        }
}

// ------------------------------------------------------------------
// FFT-based autocorrelation on TRANSPOSED pair QK: QKT[b][d][t], stride 2^20/b.
// ------------------------------------------------------------------
__device__ __forceinline__ void fft1024_tw(float* Xr, float* Xi, float* Yr, float* Yi,
                                           int tid, const float* csf, const float* snf)
{
    float *psr = Xr, *psi = Xi, *pdr = Yr, *pdi = Yi;
    #pragma unroll
    for (int st = 0; st < 10; ++st) {
        const int s = 1 << st;
        #pragma unroll
        for (int h = 0; h < 2; ++h) {
            int u = tid + (h << 8);
            int qq = u & (s - 1);
            int ps = u - qq;
            float cs = csf[st*2+h], sn = snf[st*2+h];
            float ar = psr[u],       ai = psi[u];
            float br = psr[u + 512], bi = psi[u + 512];
            int d1 = qq + (ps << 1);
            pdr[d1] = ar + br;  pdi[d1] = ai + bi;
            float tr = ar - br, ti = ai - bi;
            pdr[d1 + s] = tr * cs - ti * sn;
            pdi[d1 + s] = tr * sn + ti * cs;
        }
        __syncthreads();
        float* t0 = psr; psr = pdr; pdr = t0;
        float* t1 = psi; psi = pdi; pdi = t1;
    }
}

// grid (32, G): blockIdx.x = 16-wide d-chunk, blockIdx.y = local batch.
__launch_bounds__(256)
__global__ void corr_fft(const ushortb* __restrict__ QKh, const ushortb* __restrict__ QKl,
                         float* __restrict__ SP)
{
    __shared__ float Xr[1024], Xi[1024], Yr[1024], Yi[1024];
    const int tid = threadIdx.x;
    const int c = blockIdx.x, b = blockIdx.y;
    const size_t bbase = (size_t)b << 20;
    float csf[20], snf[20];
    #pragma unroll
    for (int st = 0; st < 10; ++st) {
        const int s = 1 << st;
        #pragma unroll
        for (int h = 0; h < 2; ++h) {
            int u = tid + (h << 8);
            int ps = u - (u & (s - 1));
            float ang = -(3.14159265358979323846f / 512.f) * (float)ps;
            __sincosf(ang, &snf[st*2+h], &csf[st*2+h]);
        }
    }
    float sr[4] = {0.f, 0.f, 0.f, 0.f};
    float si[4] = {0.f, 0.f, 0.f, 0.f};
    for (int j = 0; j < 16; ++j) {
        int d = (c << 4) + j;
        const ushortb* qh = QKh + bbase + ((size_t)d << 10);
        const ushortb* ql = QKl + bbase + ((size_t)d << 10);
        const ushortb* kh = qh + (512u << 10);
        const ushortb* kl = ql + (512u << 10);
        __syncthreads();                    // protect prior unpack reads
        #pragma unroll
        for (int i = 0; i < 4; ++i) {
            int t = tid + (i << 8);
            Xr[t] = h2f(qh[t]) + h2f(ql[t]);
            Xi[t] = h2f(kh[t]) + h2f(kl[t]);
        }
        __syncthreads();
        fft1024_tw(Xr, Xi, Yr, Yi, tid, csf, snf);
        #pragma unroll
        for (int i = 0; i < 4; ++i) {
            int f  = tid + (i << 8);
            int f2 = (1024 - f) & 1023;
            float axr = Xr[f],  axi = Xi[f];
            float cxr = Xr[f2], cxi = -Xi[f2];
            float ur = axr + cxr, ui = axi + cxi;
            float vr = axr - cxr, vi = -(axi - cxi);
            float wr_ = ur * vr - ui * vi;
            float wi_ = ur * vi + ui * vr;
            sr[i] += -0.25f * wi_;
            si[i] +=  0.25f * wr_;
        }
    }
    const size_t base = ((size_t)(b * 32 + c)) << 11;
    #pragma unroll
    for (int i = 0; i < 4; ++i) {
        int f = tid + (i << 8);
        SP[base + f]        = sr[i];
        SP[base + 1024 + f] = si[i];
    }
}

// per-b: reduce 32 chunk partials, inverse FFT, top-6 + softmax
__launch_bounds__(256)
__global__ void topk6f_fft(const float* __restrict__ SP, int* __restrict__ DELAY,
                           float* __restrict__ WGT)
{
    __shared__ float Xr[1024], Xi[1024], Yr[1024], Yi[1024];
    __shared__ float v[1024];
    __shared__ float rv[256];
    __shared__ int   ri[256];
    __shared__ float wv6[6];
    __shared__ int   wi6[6];
    const int b = blockIdx.x, tid = threadIdx.x;
    float csf[20], snf[20];
    #pragma unroll
    for (int st = 0; st < 10; ++st) {
        const int s = 1 << st;
        #pragma unroll
        for (int h = 0; h < 2; ++h) {
            int u = tid + (h << 8);
            int ps = u - (u & (s - 1));
            float ang = (3.14159265358979323846f / 512.f) * (float)ps;
            __sincosf(ang, &snf[st*2+h], &csf[st*2+h]);
        }
    }
    #pragma unroll
    for (int i = 0; i < 4; ++i) {
        int f = tid + (i << 8);
        float ar = 0.f, ai = 0.f;
        for (int c = 0; c < 32; ++c) {
            size_t base = ((size_t)(b * 32 + c)) << 11;
            ar += SP[base + f];
            ai += SP[base + 1024 + f];
        }
        Xr[f] = ar; Xi[f] = ai;
    }
    __syncthreads();
    fft1024_tw(Xr, Xi, Yr, Yi, tid, csf, snf);
    #pragma unroll
    for (int i = 0; i < 4; ++i) {
        int f = tid + (i << 8);
        v[f] = Xr[f] * (1.f / 524288.f);
    }
    __syncthreads();
    for (int it = 0; it < 6; ++it) {
        float best = v[tid]; int bi = tid;
        #pragma unroll
        for (int k = 1; k < 4; ++k) {
            int i = tid + (k << 8);
            float xv = v[i];
            if (xv > best) { best = xv; bi = i; }
        }
        rv[tid] = best; ri[tid] = bi;
        __syncthreads();
        for (int s = 128; s > 0; s >>= 1) {
            if (tid < s) {
                if (rv[tid+s] > rv[tid] || (rv[tid+s] == rv[tid] && ri[tid+s] < ri[tid])) {
                    rv[tid] = rv[tid+s]; ri[tid] = ri[tid+s];
                }
            }
            __syncthreads();
        }
        if (tid == 0) { wv6[it] = rv[0]; wi6[it] = ri[0]; v[ri[0]] = -1e30f; }
        __syncthreads();
    }
    if (tid == 0) {
        float mx = wv6[0], s = 0.f, e[6];
        #pragma unroll
        for (int i = 0; i < 6; ++i) { e[i] = expf(wv6[i] - mx); s += e[i]; }
        #pragma unroll
        for (int i = 0; i < 6; ++i) { WGT[b*6+i] = e[i]/s; DELAY[b*6+i] = wi6[i]; }
    }
}

// ------------------------------------------------------------------
// series_decomp pair->pair, STRIP-4 running-window version:
// each thread: 4 d x 4 consecutive t with a sliding 25-row sum
// (35 row-loads vs 104). j=0 sum is bit-identical to the old kernel;
// j=1..3 differ only by fp32 reassociation (~1e-6, selector-safe).
// grid: TG/8 blocks x 256 threads.
// ------------------------------------------------------------------
__launch_bounds__(256)
__global__ void decomp512v(const ushortb* __restrict__ Xh, const ushortb* __restrict__ Xl,
                           ushortb* __restrict__ Sh, ushortb* __restrict__ Sl,
                           float* __restrict__ TTs, int tmode)
{
    int idx = blockIdx.x * 256 + threadIdx.x;   // TG*32 threads
    int d0 = (idx & 127) << 2;
    int tg = idx >> 7;                          // global t-group
    int t0 = (tg & 255) << 2;
    int base = (tg >> 8) << 10;                 // batch row base
    int bb = tg >> 8;

    auto ldrow = [&](int tt) -> float4 {
        tt = tt < 0 ? 0 : (tt > 1023 ? 1023 : tt);
        size_t ro = ((size_t)(base + tt) << 9) + d0;
        uint2 hv = *(const uint2*)(Xh + ro);
        uint2 lv = *(const uint2*)(Xl + ro);
        float4 r;
        r.x = h2f((ushortb)(hv.x & 0xFFFFu)) + h2f((ushortb)(lv.x & 0xFFFFu));
        r.y = h2f((ushortb)(hv.x >> 16))     + h2f((ushortb)(lv.x >> 16));
        r.z = h2f((ushortb)(hv.y & 0xFFFFu)) + h2f((ushortb)(lv.y & 0xFFFFu));
        r.w = h2f((ushortb)(hv.y >> 16))     + h2f((ushortb)(lv.y >> 16));
        return r;
    };

    float s0 = 0.f, s1 = 0.f, s2 = 0.f, s3 = 0.f;
    #pragma unroll
    for (int w = -12; w <= 12; ++w) {
        float4 r = ldrow(t0 + w);
        s0 += r.x; s1 += r.y; s2 += r.z; s3 += r.w;
    }
    #pragma unroll
    for (int j = 0; j < 4; ++j) {
        int t = t0 + j;
        if (j > 0) {
            float4 add = ldrow(t + 12);
            float4 sub = ldrow(t - 13);
            s0 += add.x - sub.x; s1 += add.y - sub.y;
            s2 += add.z - sub.z; s3 += add.w - sub.w;
        }
        float m0 = s0*(1.f/25.f), m1 = s1*(1.f/25.f), m2 = s2*(1.f/25.f), m3 = s3*(1.f/25.f);
        size_t co = ((size_t)(base + t) << 9) + d0;
        uint2 chv = *(const uint2*)(Xh + co);
        uint2 clv = *(const uint2*)(Xl + co);
        float v0 = h2f((ushortb)(chv.x & 0xFFFFu)) + h2f((ushortb)(clv.x & 0xFFFFu)) - m0;
        float v1 = h2f((ushortb)(chv.x >> 16))     + h2f((ushortb)(clv.x >> 16))     - m1;
        float v2 = h2f((ushortb)(chv.y & 0xFFFFu)) + h2f((ushortb)(clv.y & 0xFFFFu)) - m2;
        float v3 = h2f((ushortb)(chv.y >> 16))     + h2f((ushortb)(clv.y >> 16))     - m3;
        ushortb h0=f2h(v0), h1=f2h(v1), h2v=f2h(v2), h3=f2h(v3);
        uint2 hp, lp;
        hp.x = (unsigned)h0 | ((unsigned)h1 << 16); hp.y = (unsigned)h2v | ((unsigned)h3 << 16);
        lp.x = (unsigned)f2h(v0-h2f(h0)) | ((unsigned)f2h(v1-h2f(h1)) << 16);
        lp.y = (unsigned)f2h(v2-h2f(h2v)) | ((unsigned)f2h(v3-h2f(h3)) << 16);
        *(uint2*)(Sh + co) = hp; *(uint2*)(Sl + co) = lp;
        if (tmode) {
            int slot = (t >= 511) ? (t - 511) : (t == 0 ? 513 : -1);
            if (slot >= 0) {
                float* tp = TTs + (size_t)bb * 263168 + ((size_t)slot << 9) + d0;
                if (tmode == 1) { tp[0]=m0; tp[1]=m1; tp[2]=m2; tp[3]=m3; }
                else            { tp[0]+=m0; tp[1]+=m1; tp[2]+=m2; tp[3]+=m3; }
            }
        }
    }
}

// per-token LN, pair in -> pair out
__launch_bounds__(256)
__global__ void ln_rows(const ushortb* __restrict__ Xh, const ushortb* __restrict__ Xl,
                        const float* __restrict__ w, const float* __restrict__ bias,
                        ushortb* __restrict__ Yh, ushortb* __restrict__ Yl)
{
    __shared__ float r1[256], r2[256];
    const int row = blockIdx.x, tid = threadIdx.x;
    size_t ro = (size_t)row * 512;
    float x0 = h2f(Xh[ro + tid]) + h2f(Xl[ro + tid]);
    float x1 = h2f(Xh[ro + tid + 256]) + h2f(Xl[ro + tid + 256]);
    r1[tid] = x0 + x1; r2[tid] = x0*x0 + x1*x1;
    __syncthreads();
    for (int s = 128; s > 0; s >>= 1) {
        if (tid < s) { r1[tid] += r1[tid+s]; r2[tid] += r2[tid+s]; }
        __syncthreads();
    }
    float mu = r1[0] * (1.f/512.f);
    float var = r2[0] * (1.f/512.f) - mu*mu;
    float rstd = rsqrtf(var + 1e-5f);
    float v0 = (x0 - mu) * rstd * w[tid]     + bias[tid];
    float v1 = (x1 - mu) * rstd * w[tid+256] + bias[tid+256];
    ushortb h0 = f2h(v0), h1 = f2h(v1);
    Yh[ro + tid] = h0;       Yl[ro + tid] = f2h(v0 - h2f(h0));
    Yh[ro + tid + 256] = h1; Yl[ro + tid + 256] = f2h(v1 - h2f(h1));
}

// column-mean partials from pair — COALESCED: consecutive threads walk
// consecutive d (128B/wave reads). PC layout unchanged: PC[b][d][c].
__launch_bounds__(256)
__global__ void colmean_p(const ushortb* __restrict__ Yh, const ushortb* __restrict__ Yl,
                          float* __restrict__ PC)
{
    int i = blockIdx.x * 256 + threadIdx.x;   // G*4096
    int b = i >> 12, r = i & 4095, d = r & 511, c = r >> 9;
    size_t o = ((size_t)b << 19) + ((size_t)(c << 7) << 9) + d;
    float s = 0.f;
    for (int t = 0; t < 128; ++t) { size_t oo = o + ((size_t)t << 9); s += h2f(Yh[oo]) + h2f(Yl[oo]); }
    PC[((size_t)b << 12) + (d << 3) + c] = s * (1.f/1024.f);
}

// Z = Y - colmean, pair -> pair
__launch_bounds__(256)
__global__ void submean_s(const ushortb* __restrict__ Yh, const ushortb* __restrict__ Yl,
                          const float* __restrict__ PC,
                          ushortb* __restrict__ Zh, ushortb* __restrict__ Zl)
{
    int idx = blockIdx.x * 256 + threadIdx.x;
    int d = idx & 511, b = idx >> 19;
    const float* pc = PC + ((size_t)b << 12) + (d << 3);
    float m = ((pc[0]+pc[1])+(pc[2]+pc[3]))+((pc[4]+pc[5])+(pc[6]+pc[7]));
    float v = h2f(Yh[idx]) + h2f(Yl[idx]) - m;
    ushortb h = f2h(v);
    Zh[idx] = h; Zl[idx] = f2h(v - h2f(h));
}

// embedding -> pair
__launch_bounds__(256)
__global__ void embed_es(const float* __restrict__ x, const float* __restrict__ mark,
                         const float* __restrict__ Wtok, const float* __restrict__ Wtem,
                         ushortb* __restrict__ Oh, ushortb* __restrict__ Ol)
{
    int idx = blockIdx.x * 256 + threadIdx.x;
    int d = idx & 511, bt = idx >> 9, t = bt & 1023, b = bt >> 10;
    float acc = 0.f;
    #pragma unroll
    for (int j = 0; j < 3; ++j) {
        int tt = (t + 1023 + j) & 1023;
        const float* xr = x + (size_t)(b*1024 + tt)*7;
        #pragma unroll
        for (int c = 0; c < 7; ++c)
            acc += xr[c] * Wtok[(j*7+c)*512 + d];
    }
    const float* mr = mark + (size_t)bt*4;
    #pragma unroll
    for (int m = 0; m < 4; ++m) acc += mr[m] * Wtem[m*512 + d];
    ushortb h = f2h(acc);
    Oh[idx] = h; Ol[idx] = f2h(acc - h2f(h));
}

__launch_bounds__(256)
__global__ void mean7(const float* __restrict__ x, float* __restrict__ M7)
{
    __shared__ float r[256];
    int bc = blockIdx.x, b = bc / 7, c = bc % 7, tid = threadIdx.x;
    float s = 0.f;
    for (int t = tid; t < 1024; t += 256) s += x[(size_t)(b*1024+t)*7 + c];
    r[tid] = s; __syncthreads();
    for (int st = 128; st > 0; st >>= 1) { if (tid < st) r[tid] += r[tid+st]; __syncthreads(); }
    if (tid == 0) M7[bc] = r[0] * (1.f/1024.f);
}

__launch_bounds__(256)
__global__ void decomp7(const float* __restrict__ x, const float* __restrict__ M7,
                        float* __restrict__ SEAS7, float* __restrict__ TREND7)
{
    int idx = blockIdx.x * 256 + threadIdx.x;  // TG*7
    int c = idx % 7, bt = idx / 7, t = bt & 1023, b = bt >> 10;
    if (t < 512) {
        int s0 = t + 512;
        float s = 0.f;
        #pragma unroll
        for (int w = -12; w <= 12; ++w) {
            int tt = s0 + w; tt = tt < 0 ? 0 : (tt > 1023 ? 1023 : tt);
            s += x[(size_t)(b*1024+tt)*7 + c];
        }
        float m = s * (1.f/25.f);
        SEAS7[idx] = x[(size_t)(b*1024+s0)*7 + c] - m;
        TREND7[idx] = m;
    } else {
        SEAS7[idx] = 0.f;
        TREND7[idx] = M7[b*7 + c];
    }
}

// fused: out = projb + TREND7 + X@projW + circ_conv3(TTs)@dec_trend_W  (rows t>=512)
__launch_bounds__(256)
__global__ void final_fused(const ushortb* __restrict__ Xh, const ushortb* __restrict__ Xl,
                            const float* __restrict__ PW, const float* __restrict__ PB,
                            const float* __restrict__ TW, const float* __restrict__ TTs,
                            const float* __restrict__ TREND7, float* __restrict__ out)
{
    __shared__ float WT[10752];   // 3*512*7
    __shared__ float WP[3584];    // 512*7
    for (int i = threadIdx.x; i < 10752; i += 256) WT[i] = TW[i];
    for (int i = threadIdx.x; i < 3584; i += 256) WP[i] = PW[i];
    __syncthreads();
    int idx = blockIdx.x * 256 + threadIdx.x;  // G*512*7
    int c = idx % 7, btt = idx / 7, tt = btt & 511, b = btt >> 9;
    int t = tt + 512;
    float acc = PB[c] + TREND7[(size_t)(b*1024 + t)*7 + c];
    size_t ro = ((size_t)(b*1024 + t) << 9);
    for (int d = 0; d < 512; ++d)
        acc += (h2f(Xh[ro + d]) + h2f(Xl[ro + d])) * WP[d*7 + c];
    for (int j = 0; j < 3; ++j) {
        int t2 = t - 1 + j;
        int slot = (t2 >= 1024) ? 513 : (t2 - 511);
        const float* r = TTs + (size_t)b * 263168 + ((size_t)slot << 9);
        const float* wj = WT + j*3584 + c;
        for (int d = 0; d < 512; ++d) acc += r[d] * wj[d*7];
    }
    out[idx] = acc;
}

// attn weight transpose+split pool (block a: 1572864 elems):
// QKh@0 (1024x512), QKl@524288, Vh@1048576, Oh@1310720
__launch_bounds__(256)
__global__ void wsplit_att(const float* __restrict__ W, ushortb* __restrict__ pool, int which)
{
    __shared__ float t[32][33];
    const int m = blockIdx.z;
    const int kb = blockIdx.y << 5, nb = blockIdx.x << 5;
    const int c = threadIdx.x & 31, rr = threadIdx.x >> 5;
    const float* Wm = W + (size_t)m * 262144;
    #pragma unroll
    for (int i = 0; i < 4; ++i)
        t[rr + i*8][c] = Wm[(size_t)(kb + rr + i*8) * 512 + nb + c];
    __syncthreads();
    const int a = (which == 0) ? (m >> 2) : (which + 1);
    const int j = (which == 0) ? (m & 3) : m;
    size_t hi, lo; bool haslo;
    if (j == 0)      { hi = 0;       lo = 524288; haslo = true; }
    else if (j == 1) { hi = 262144;  lo = 786432; haslo = true; }
    else if (j == 2) { hi = 1048576; lo = 0; haslo = false; }
    else             { hi = 1310720; lo = 0; haslo = false; }
    ushortb* pb = pool + (size_t)a * 1572864;
    #pragma unroll
    for (int i = 0; i < 4; ++i) {
        int n = nb + rr + i*8, k = kb + c;
        float v = t[c][rr + i*8];
        ushortb h = f2h(v);
        pb[hi + (size_t)n * 512 + k] = h;
        if (haslo) pb[lo + (size_t)n * 512 + k] = f2h(v - h2f(h));
    }
}

__launch_bounds__(256)
__global__ void wsplit_ff(const float* __restrict__ W, ushortb* __restrict__ dh,
                          int K, int N)
{
    __shared__ float t[32][33];
    const int m = blockIdx.z;
    const int kb = blockIdx.y << 5, nb = blockIdx.x << 5;
    const int c = threadIdx.x & 31, rr = threadIdx.x >> 5;
    const float* Wm = W + (size_t)m * K * N;
    #pragma unroll
    for (int i = 0; i < 4; ++i)
        t[rr + i*8][c] = Wm[(size_t)(kb + rr + i*8) * N + nb + c];
    __syncthreads();
    ushortb* Dh = dh + (size_t)m * 1048576;
    #pragma unroll
    for (int i = 0; i < 4; ++i) {
        int n = nb + rr + i*8, k = kb + c;
        Dh[(size_t)n * K + k] = f2h(t[c][rr + i*8]);
    }
}

__launch_bounds__(256)
__global__ void sentinel(float* __restrict__ out, int n)
{
    int i = blockIdx.x * 256 + threadIdx.x;
    if (i < n) out[i] = -54321.0f;
}

// ------------------------------------------------------------------
extern "C" void kernel_launch(void* const* d_in, const int* in_sizes, int n_in,
                              void* d_out, int out_size, void* d_ws, size_t ws_size,
                              hipStream_t stream)
{
    const float* x_enc      = (const float*)d_in[0];
    const float* x_mark_enc = (const float*)d_in[1];
    const float* x_mark_dec = (const float*)d_in[3];
    const float* W_enc_tok  = (const float*)d_in[4];
    const float* W_enc_tem  = (const float*)d_in[5];
    const float* W_dec_tok  = (const float*)d_in[6];
    const float* W_dec_tem  = (const float*)d_in[7];
    const float* enc_attn_W = (const float*)d_in[8];
    const float* enc_attn_b = (const float*)d_in[9];
    const float* enc_ff1    = (const float*)d_in[10];
    const float* enc_ff2    = (const float*)d_in[11];
    const float* enc_ln_w   = (const float*)d_in[12];
    const float* enc_ln_b   = (const float*)d_in[13];
    const float* dec_self_W = (const float*)d_in[14];
    const float* dec_self_b = (const float*)d_in[15];
    const float* dec_cross_W= (const float*)d_in[16];
    const float* dec_cross_b= (const float*)d_in[17];
    const float* dec_ff1    = (const float*)d_in[18];
    const float* dec_ff2    = (const float*)d_in[19];
    const float* dec_trend_W= (const float*)d_in[20];
    const float* dec_ln_w   = (const float*)d_in[21];
    const float* dec_ln_b   = (const float*)d_in[22];
    const float* proj_W     = (const float*)d_in[23];
    const float* proj_b     = (const float*)d_in[24];
    float* out = (float*)d_out;

    const size_t ATT_E = (size_t)4 * 1572864;
    const size_t FF_E  = (size_t)3 * 1048576;
    const size_t WBYTES = (ATT_E + 2 * FF_E) * 2 + 4096;

    auto need = [&](long g) -> size_t {
        size_t TGl = (size_t)g * 1024;
        size_t pairs = 3 * TGl * 2048;            // SA, TMP, SE pairs
        size_t qk    = TGl * 4096;                // QK pair / MID
        size_t vh    = TGl * 1024;
        size_t tts   = (size_t)g * 263168 * 4;
        size_t pbin  = (size_t)g * 262144;
        size_t misc  = (size_t)g * (16384 + 28 + 28672 + 28672 + 64) + 65536;
        return WBYTES + pairs + qk + vh + tts + pbin + misc + 16384;
    };
    int G = 0;
    for (int g = 32; g >= 1; g >>= 1) if (need(g) <= ws_size) { G = g; break; }
    if (G == 0) {
        sentinel<<<(out_size + 255) / 256, 256, 0, stream>>>(out, out_size);
        return;
    }
    const int TG = G * 1024;

    char* p = (char*)d_ws;
    auto carve = [&](size_t bytes) -> char* {
        char* r = p; p += (bytes + 255) & ~(size_t)255; return r;
    };
    ushortb* ATT = (ushortb*)carve(ATT_E * 2);
    ushortb* FF1 = (ushortb*)carve(FF_E * 2);
    ushortb* FF2 = (ushortb*)carve(FF_E * 2);

    const size_t SPLB = (size_t)TG * 512 * 2;
    ushortb* SAh = (ushortb*)carve(SPLB);
    ushortb* SAl = (ushortb*)carve(SPLB);
    ushortb* TMh = (ushortb*)carve(SPLB);
    ushortb* TMl = (ushortb*)carve(SPLB);
    ushortb* SEh = (ushortb*)carve(SPLB);
    ushortb* SEl = (ushortb*)carve(SPLB);
    char* R1 = carve((size_t)TG * 4096);             // QKTh+QKTl pair / MID
    ushortb* Vh = (ushortb*)carve((size_t)TG * 1024);
    float* TTs   = (float*)carve((size_t)G * 263168 * 4);
    float* PBIN  = (float*)carve((size_t)G * 262144);   // S-partials [b][32][2][1024] f32
    float* PC    = (float*)carve((size_t)G * 16384);
    float* M7    = (float*)carve((size_t)G * 28);
    float* SEAS7 = (float*)carve((size_t)G * 28672);
    float* TREND7= (float*)carve((size_t)G * 28672);
    float* WGT   = (float*)carve((size_t)G * 24);
    int*   DELAY = (int*)  carve((size_t)G * 24);

    ushortb* QKh = (ushortb*)R1;                       // transposed [b][d][t]
    ushortb* QKl = QKh + (size_t)TG * 1024;
    ushortb* MIDh = (ushortb*)R1;

    // ---- weight transforms ----
    wsplit_att<<<dim3(16,16,8),256,0,stream>>>(enc_attn_W, ATT, 0);
    wsplit_att<<<dim3(16,16,4),256,0,stream>>>(dec_self_W, ATT, 1);
    wsplit_att<<<dim3(16,16,4),256,0,stream>>>(dec_cross_W, ATT, 2);
    wsplit_ff<<<dim3(64,16,2),256,0,stream>>>(enc_ff1, FF1, 512, 2048);
    wsplit_ff<<<dim3(64,16,1),256,0,stream>>>(dec_ff1, FF1 + (size_t)2*1048576, 512, 2048);
    wsplit_ff<<<dim3(16,64,2),256,0,stream>>>(enc_ff2, FF2, 2048, 512);
    wsplit_ff<<<dim3(16,64,1),256,0,stream>>>(dec_ff2, FF2 + (size_t)2*1048576, 2048, 512);

    for (int g0 = 0; g0 < 32; g0 += G) {
        const float* xe  = x_enc      + (size_t)g0 * 1024 * 7;
        const float* me  = x_mark_enc + (size_t)g0 * 1024 * 4;
        const float* md  = x_mark_dec + (size_t)g0 * 1024 * 4;
        float*       outg= out        + (size_t)g0 * 512 * 7;
        const int GB = G * 8;   // TG/128

        auto corr_gather_oproj = [&](const ushortb* base, const float* bv,
                                     const ushortb* rh, const ushortb* rl) {
            corr_fft<<<dim3(32,G),256,0,stream>>>(QKh, QKl, PBIN);
            topk6f_fft<<<G,256,0,stream>>>(PBIN, DELAY, WGT);
            gemm_og<<<dim3(4,GB),256,0,stream>>>(Vh, DELAY, WGT,
                                                 base+1310720,512, bv+1536,
                                                 rh,rl, TMh,TMl, 512, 512);
        };
        auto attn_self = [&](const ushortb* xh, const ushortb* xl, int a, const float* bv) {
            const ushortb* base = ATT + (size_t)a * 1572864;
            gemm_h3<<<dim3(8,GB),256,0,stream>>>(xh,xl,512, base,base+524288,512, bv,
                                                 QKh,QKl, 512);
            gemm_h1<<<dim3(4,GB),256,0,stream>>>(xh,512, base+1048576,512, bv+1024,
                                                 nullptr,nullptr, Vh,nullptr, 512, 512, 0);
            corr_gather_oproj(base, bv, xh, xl);
        };
        auto attn_cross = [&](const ushortb* qh, const ushortb* ql,
                              const ushortb* kvh, const ushortb* kvl,
                              int a, const float* bv) {
            const ushortb* base = ATT + (size_t)a * 1572864;
            gemm_h3<<<dim3(4,GB),256,0,stream>>>(qh,ql,512, base,base+524288,512, bv,
                                                 QKh,QKl, 512);
            gemm_h3<<<dim3(4,GB),256,0,stream>>>(kvh,kvl,512, base+262144,base+786432,512, bv+512,
                                                 QKh+524288,QKl+524288, 512);
            gemm_h1<<<dim3(4,GB),256,0,stream>>>(kvh,512, base+1048576,512, bv+1024,
                                                 nullptr,nullptr, Vh,nullptr, 512, 512, 0);
            corr_gather_oproj(base, bv, qh, ql);
        };
        auto ffn = [&](const ushortb* xh, const ushortb* xl, int fi) {
            gemm_h1<<<dim3(16,GB),256,0,stream>>>(xh,512, FF1 + (size_t)fi*1048576,512, nullptr,
                                                  nullptr,nullptr, MIDh,nullptr, 2048, 512, 1);
            gemm_h1<<<dim3(4,GB),256,0,stream>>>(MIDh,2048, FF2 + (size_t)fi*1048576,2048, nullptr,
                                                 xh,xl, TMh,TMl, 512, 2048, 0);
        };

        // ---------------- encoder ----------------
        embed_es<<<TG*2,256,0,stream>>>(xe, me, W_enc_tok, W_enc_tem, SAh, SAl);
        for (int l = 0; l < 2; ++l) {
            attn_self(SAh, SAl, l, enc_attn_b + (size_t)l*4*512);
            decomp512v<<<TG/8,256,0,stream>>>(TMh, TMl, SAh, SAl, nullptr, 0);
            ffn(SAh, SAl, l);
            decomp512v<<<TG/8,256,0,stream>>>(TMh, TMl, SAh, SAl, nullptr, 0);
        }
        ln_rows<<<TG,256,0,stream>>>(SAh, SAl, enc_ln_w, enc_ln_b, TMh, TMl);
        colmean_p<<<G*16,256,0,stream>>>(TMh, TMl, PC);
        submean_s<<<TG*2,256,0,stream>>>(TMh, TMl, PC, SEh, SEl);

        // ---------------- decoder prep ----------------
        mean7<<<G*7,256,0,stream>>>(xe, M7);
        decomp7<<<G*28,256,0,stream>>>(xe, M7, SEAS7, TREND7);
        embed_es<<<TG*2,256,0,stream>>>(SEAS7, md, W_dec_tok, W_dec_tem, SAh, SAl);

        // ---------------- decoder layer ----------------
        attn_self(SAh, SAl, 2, dec_self_b);
        decomp512v<<<TG/8,256,0,stream>>>(TMh, TMl, SAh, SAl, TTs, 1);

        attn_cross(SAh, SAl, SEh, SEl, 3, dec_cross_b);
        decomp512v<<<TG/8,256,0,stream>>>(TMh, TMl, SAh, SAl, TTs, 2);

        ffn(SAh, SAl, 2);
        decomp512v<<<TG/8,256,0,stream>>>(TMh, TMl, SAh, SAl, TTs, 2);

        ln_rows<<<TG,256,0,stream>>>(SAh, SAl, dec_ln_w, dec_ln_b, TMh, TMl);
        colmean_p<<<G*16,256,0,stream>>>(TMh, TMl, PC);
        submean_s<<<TG*2,256,0,stream>>>(TMh, TMl, PC, SAh, SAl);

        final_fused<<<G*14,256,0,stream>>>(SAh, SAl, proj_W, proj_b, dec_trend_W,
                                           TTs, TREND7, outg);
    }
}

// Round 10
// 3309.886 us; speedup vs baseline: 1.3944x; 1.0301x over previous
//
#include <hip/hip_runtime.h>

typedef unsigned short ushortb;
typedef __attribute__((ext_vector_type(8))) _Float16 f16x8;
typedef __attribute__((ext_vector_type(4))) float f32x4;

__device__ __forceinline__ float h2f(ushortb u) {
    _Float16 h; __builtin_memcpy(&h, &u, 2); return (float)h;
}
__device__ __forceinline__ ushortb f2h(float f) {
    _Float16 h = (_Float16)f; ushortb u; __builtin_memcpy(&u, &h, 2); return u;
}
// tanh-approx GELU == x * sigmoid(1.5957691x + 0.0713548x^3); |err| < ~3e-4 vs erf GELU.
__device__ __forceinline__ float gelu_f(float x) {
    float z = x * (1.59576912f + 0.0713548128f * x * x);
    return x / (1.f + __expf(-z));
}

__device__ __forceinline__ void ld16(const void* g, void* l) {
    __builtin_amdgcn_global_load_lds(
        (const __attribute__((address_space(1))) unsigned int*)g,
        (__attribute__((address_space(3))) unsigned int*)l, 16, 0, 0);
}

// XCD-aware remap: each XCD gets a contiguous tile range so blocks sharing an
// A row-panel land on one XCD's L2. Bijective when total%8==0.
__device__ __forceinline__ void xcd_remap(int& bx, int& by) {
    int nx = gridDim.x;
    int total = nx * gridDim.y;
    bx = blockIdx.x; by = blockIdx.y;
    if ((total & 7) == 0) {
        int lin = by * nx + bx;
        int lin2 = (lin & 7) * (total >> 3) + (lin >> 3);
        by = lin2 / nx; bx = lin2 % nx;
    }
}

// LDS staging swizzle (rule #21): linear global_load_lds dest + swizzled SOURCE
// col + matching XOR on fragment reads.
//   staging source col-chunk: (ln&3) ^ ((ln>>3)&3)
//   fragment read slot:        fq    ^ ((fr>>1)&3)
// Invariant: LDS[r][j] holds global chunk j ^ ((r>>1)&3).

// ------------------------------------------------------------------
// 3-term split-fp16 MFMA GEMM (NT), pair in -> pair out (fp32 fidelity)
// QK-producer only: TRANSPOSED output QKT[b][d][t] (linear layout,
// per-batch stride 2^20). LDS-transposed epilogue for coalesced stores.
// ------------------------------------------------------------------
__launch_bounds__(256)
__global__ void gemm_h3(const ushortb* __restrict__ Ah, const ushortb* __restrict__ Al,
                        int lda,
                        const ushortb* __restrict__ Bh, const ushortb* __restrict__ Bl,
                        int ldb,
                        const float* __restrict__ bias,
                        ushortb* __restrict__ Ch, ushortb* __restrict__ Cl, int K)
{
    __shared__ __align__(16) ushortb LDS[16384];    // 32 KB
    int bxs, bys; xcd_remap(bxs, bys);
    const int tid = threadIdx.x;
    const int wv = tid >> 6, ln = tid & 63;
    const int fr = ln & 15, fq = ln >> 4;
    const int m0 = bys << 7, n0 = bxs << 7;
    const int wr = (wv & 1) << 6, wc = (wv >> 1) << 6;

    const ushortb* gb; int ld;
    if (wv == 0)      { gb = Ah; ld = lda; }
    else if (wv == 1) { gb = Al; ld = lda; }
    else if (wv == 2) { gb = Bh; ld = ldb; }
    else              { gb = Bl; ld = ldb; }
    const int rbase = (wv < 2) ? m0 : n0;
    const ushortb* gp = gb + (size_t)(rbase + (ln >> 2)) * ld
                          + (((ln & 3) ^ ((ln >> 3) & 3)) * 8);
    ushortb* lplane = LDS + wv * 4096;
    const size_t rstep = (size_t)ld << 4;
    const int sw = (fr >> 1) & 3;

    f32x4 acc[4][4] = {};
    for (int k0 = 0; k0 < K; k0 += 32) {
        __syncthreads();
        #pragma unroll
        for (int i = 0; i < 8; ++i)
            ld16(gp + (size_t)i * rstep, lplane + i * 512);
        gp += 32;
        __syncthreads();
        f16x8 afh[4], afl[4], bfh[4], bfl[4];
        #pragma unroll
        for (int t = 0; t < 4; ++t) {
            int ra = ((wr + t*16 + fr) << 5) + ((fq ^ sw) << 3);
            int rb = ((wc + t*16 + fr) << 5) + ((fq ^ sw) << 3);
            afh[t] = *(const f16x8*)(const void*)(LDS + ra);
            afl[t] = *(const f16x8*)(const void*)(LDS + 4096 + ra);
            bfh[t] = *(const f16x8*)(const void*)(LDS + 8192 + rb);
            bfl[t] = *(const f16x8*)(const void*)(LDS + 12288 + rb);
        }
        #pragma unroll
        for (int tm = 0; tm < 4; ++tm)
            #pragma unroll
            for (int tn = 0; tn < 4; ++tn) {
                f32x4 c = acc[tm][tn];
                c = __builtin_amdgcn_mfma_f32_16x16x32_f16(afh[tm], bfh[tn], c, 0, 0, 0);
                c = __builtin_amdgcn_mfma_f32_16x16x32_f16(afl[tm], bfh[tn], c, 0, 0, 0);
                c = __builtin_amdgcn_mfma_f32_16x16x32_f16(afh[tm], bfl[tn], c, 0, 0, 0);
                acc[tm][tn] = c;
            }
    }
    // ---- LDS-transposed epilogue ----
    const size_t bb = (size_t)(m0 >> 10) * 1048576;   // batch base
    const int trow0 = m0 & 1023;                      // block's t-range base
    const int PS = 4224;                              // 32*132 (pad 4)
    ushortb* EH = LDS;
    ushortb* EL = LDS + PS;
    const int cl  = ((wv >> 1) << 4) + fr;            // local col 0..31
    const int rcl = tid >> 3, seg = tid & 7;          // reader mapping
    #pragma unroll
    for (int tn = 0; tn < 4; ++tn) {
        __syncthreads();                              // LDS free / prev pass done
        int col = n0 + ((wv >> 1) << 6) + tn*16 + fr;
        float bset = bias ? bias[col] : 0.f;
        #pragma unroll
        for (int tm = 0; tm < 4; ++tm) {
            int tl = ((wv & 1) << 6) + tm*16 + (fq << 2);
            float v0 = acc[tm][tn][0] + bset;
            float v1 = acc[tm][tn][1] + bset;
            float v2 = acc[tm][tn][2] + bset;
            float v3 = acc[tm][tn][3] + bset;
            ushortb h0 = f2h(v0), h1 = f2h(v1), h2v = f2h(v2), h3v = f2h(v3);
            uint2 hp, lp_;
            hp.x  = (unsigned)h0 | ((unsigned)h1 << 16);
            hp.y  = (unsigned)h2v | ((unsigned)h3v << 16);
            lp_.x = (unsigned)f2h(v0 - h2f(h0))  | ((unsigned)f2h(v1 - h2f(h1))  << 16);
            lp_.y = (unsigned)f2h(v2 - h2f(h2v)) | ((unsigned)f2h(v3 - h2f(h3v)) << 16);
            *(uint2*)(void*)(EH + cl*132 + tl) = hp;
            *(uint2*)(void*)(EL + cl*132 + tl) = lp_;
        }
        __syncthreads();
        int gcol = n0 + ((rcl >> 4) << 6) + tn*16 + (rcl & 15);
        size_t goff = bb + (size_t)gcol * 1024 + trow0 + (seg << 4);
        const ushortb* sh = EH + rcl*132 + (seg << 4);
        const ushortb* sl = EL + rcl*132 + (seg << 4);
        #pragma unroll
        for (int i = 0; i < 4; ++i) {
            *(uint2*)(void*)(Ch + goff + i*4) = *(const uint2*)(const void*)(sh + i*4);
            *(uint2*)(void*)(Cl + goff + i*4) = *(const uint2*)(const void*)(sl + i*4);
        }
    }
}

// ------------------------------------------------------------------
// Single-term fp16 MFMA GEMM (NT), OPERAND-SWAPPED, M-TILE 64:
// grid y covers M in 64-row tiles (2x grid => 4+ blocks/CU, was grid-limited
// at 2). acc[2][4]; A 64x32 @LDS 0, B 128x32 @LDS+2048. Same per-output math
// as the 128-tile version (bit-identical).
// ------------------------------------------------------------------
__launch_bounds__(256)
__global__ void gemm_h1(const ushortb* __restrict__ Ah, int lda,
                        const ushortb* __restrict__ Bh, int ldb,
                        const float* __restrict__ bias,
                        const ushortb* __restrict__ Rh, const ushortb* __restrict__ Rl,
                        ushortb* __restrict__ Ch, ushortb* __restrict__ Cl,
                        int ldc, int K, int act)
{
    __shared__ __align__(16) ushortb LDS[6144];     // 12 KB
    int bxs, bys; xcd_remap(bxs, bys);
    const int tid = threadIdx.x;
    const int wv = tid >> 6, ln = tid & 63;
    const int fr = ln & 15, fq = ln >> 4;
    const int m0 = bys << 6, n0 = bxs << 7;
    const int wr = (wv & 1) << 5, wc = (wv >> 1) << 6;
    const int half = wv & 1;

    const ushortb* gp; ushortb* lp; size_t rstep;
    if (wv < 2) {
        gp = Ah + (size_t)(m0 + half*32 + (ln >> 2)) * lda
                + (((ln & 3) ^ ((ln >> 3) & 3)) * 8);
        lp = LDS + half * 1024;
        rstep = (size_t)lda << 4;
    } else {
        gp = Bh + (size_t)(n0 + half*64 + (ln >> 2)) * ldb
                + (((ln & 3) ^ ((ln >> 3) & 3)) * 8);
        lp = LDS + 2048 + half * 2048;
        rstep = (size_t)ldb << 4;
    }
    const int sw = (fr >> 1) & 3;

    f32x4 acc[2][4] = {};
    for (int k0 = 0; k0 < K; k0 += 32) {
        __syncthreads();
        if (wv < 2) {
            #pragma unroll
            for (int i = 0; i < 2; ++i)
                ld16(gp + (size_t)i * rstep, lp + i * 512);
        } else {
            #pragma unroll
            for (int i = 0; i < 4; ++i)
                ld16(gp + (size_t)i * rstep, lp + i * 512);
        }
        gp += 32;
        __syncthreads();
        f16x8 af[2], bf[4];
        #pragma unroll
        for (int t = 0; t < 2; ++t) {
            int ra = ((wr + t*16 + fr) << 5) + ((fq ^ sw) << 3);
            af[t] = *(const f16x8*)(const void*)(LDS + ra);
        }
        #pragma unroll
        for (int t = 0; t < 4; ++t) {
            int rx = ((wc + t*16 + fr) << 5) + ((fq ^ sw) << 3);
            bf[t] = *(const f16x8*)(const void*)(LDS + 2048 + rx);
        }
        #pragma unroll
        for (int tm = 0; tm < 2; ++tm)
            #pragma unroll
            for (int tn = 0; tn < 4; ++tn)
                acc[tm][tn] = __builtin_amdgcn_mfma_f32_16x16x32_f16(bf[tn], af[tm], acc[tm][tn], 0, 0, 0);
    }
    #pragma unroll
    for (int tm = 0; tm < 2; ++tm)
        #pragma unroll
        for (int tn = 0; tn < 4; ++tn) {
            int row  = m0 + wr + tm*16 + fr;
            int col0 = n0 + wc + tn*16 + (fq << 2);
            size_t off = (size_t)row * ldc + col0;
            float v0 = acc[tm][tn][0], v1 = acc[tm][tn][1];
            float v2 = acc[tm][tn][2], v3 = acc[tm][tn][3];
            if (bias) {
                float4 bv = *(const float4*)(bias + col0);
                v0 += bv.x; v1 += bv.y; v2 += bv.z; v3 += bv.w;
            }
            if (Rh) {
                uint2 rh = *(const uint2*)(const void*)(Rh + off);
                uint2 rl = *(const uint2*)(const void*)(Rl + off);
                v0 += h2f((ushortb)(rh.x & 0xFFFFu)) + h2f((ushortb)(rl.x & 0xFFFFu));
                v1 += h2f((ushortb)(rh.x >> 16))     + h2f((ushortb)(rl.x >> 16));
                v2 += h2f((ushortb)(rh.y & 0xFFFFu)) + h2f((ushortb)(rl.y & 0xFFFFu));
                v3 += h2f((ushortb)(rh.y >> 16))     + h2f((ushortb)(rl.y >> 16));
            }
            if (act) { v0 = gelu_f(v0); v1 = gelu_f(v1); v2 = gelu_f(v2); v3 = gelu_f(v3); }
            ushortb h0 = f2h(v0), h1 = f2h(v1), h2v = f2h(v2), h3v = f2h(v3);
            uint2 hp;
            hp.x = (unsigned)h0 | ((unsigned)h1 << 16);
            hp.y = (unsigned)h2v | ((unsigned)h3v << 16);
            *(uint2*)(void*)(Ch + off) = hp;
            if (Cl) {
                uint2 lo;
                lo.x = (unsigned)f2h(v0 - h2f(h0))  | ((unsigned)f2h(v1 - h2f(h1))  << 16);
                lo.y = (unsigned)f2h(v2 - h2f(h2v)) | ((unsigned)f2h(v3 - h2f(h3v)) << 16);
                *(uint2*)(void*)(Cl + off) = lo;
            }
        }
}

// ------------------------------------------------------------------
// Fused 6-delay gather + O-projection GEMM, M-TILE 64 (matches gemm_h1).
// A-staging computes the gather in regs and ds_writes to the SWIZZLED slot.
// ------------------------------------------------------------------
__launch_bounds__(256)
__global__ void gemm_og(const ushortb* __restrict__ Vh,
                        const int* __restrict__ DELAY, const float* __restrict__ WGT,
                        const ushortb* __restrict__ Bh, int ldb,
                        const float* __restrict__ bias,
                        const ushortb* __restrict__ Rh, const ushortb* __restrict__ Rl,
                        ushortb* __restrict__ Ch, ushortb* __restrict__ Cl,
                        int ldc, int K)
{
    __shared__ __align__(16) ushortb LDS[6144];
    int bxs, bys; xcd_remap(bxs, bys);
    const int tid = threadIdx.x;
    const int wv = tid >> 6, ln = tid & 63;
    const int fr = ln & 15, fq = ln >> 4;
    const int m0 = bys << 6, n0 = bxs << 7;
    const int wr = (wv & 1) << 5, wc = (wv >> 1) << 6;
    const int half = wv & 1;

    const int b = m0 >> 10;
    const ushortb* Vb = Vh + ((size_t)b << 19);
    int del[6]; float w6[6];
    #pragma unroll
    for (int j = 0; j < 6; ++j) { del[j] = DELAY[b*6+j]; w6[j] = WGT[b*6+j]; }

    const ushortb* gp = Bh + (size_t)(n0 + half*64 + (ln >> 2)) * ldb
                           + (((ln & 3) ^ ((ln >> 3) & 3)) * 8);
    ushortb* lpA = LDS + half * 1024;
    ushortb* lpB = LDS + 2048 + half * 2048;
    const size_t rstep = (size_t)ldb << 4;
    const int sw = (fr >> 1) & 3;
    const int adst = ((ln >> 2) << 5) + (((ln & 3) ^ ((ln >> 3) & 3)) << 3);

    f32x4 acc[2][4] = {};
    for (int k0 = 0; k0 < K; k0 += 32) {
        __syncthreads();
        if (wv < 2) {
            #pragma unroll
            for (int i = 0; i < 2; ++i) {
                int t = (m0 + half*32 + (ln >> 2) + 16*i) & 1023;
                float a0=0,a1=0,a2=0,a3=0,a4=0,a5=0,a6=0,a7=0;
                #pragma unroll
                for (int j = 0; j < 6; ++j) {
                    int s = (t + del[j]) & 1023;
                    f16x8 hv = *(const f16x8*)(const void*)(Vb + (((size_t)s) << 9) + k0 + ((ln & 3) << 3));
                    float w = w6[j];
                    a0 += w * (float)hv[0]; a1 += w * (float)hv[1];
                    a2 += w * (float)hv[2]; a3 += w * (float)hv[3];
                    a4 += w * (float)hv[4]; a5 += w * (float)hv[5];
                    a6 += w * (float)hv[6]; a7 += w * (float)hv[7];
                }
                f16x8 ov;
                ov[0]=(_Float16)a0; ov[1]=(_Float16)a1; ov[2]=(_Float16)a2; ov[3]=(_Float16)a3;
                ov[4]=(_Float16)a4; ov[5]=(_Float16)a5; ov[6]=(_Float16)a6; ov[7]=(_Float16)a7;
                *(f16x8*)(void*)(lpA + i*512 + adst) = ov;
            }
        } else {
            #pragma unroll
            for (int i = 0; i < 4; ++i)
                ld16(gp + (size_t)i * rstep, lpB + i * 512);
            gp += 32;
        }
        __syncthreads();
        f16x8 af[2], bf[4];
        #pragma unroll
        for (int t = 0; t < 2; ++t) {
            int ra = ((wr + t*16 + fr) << 5) + ((fq ^ sw) << 3);
            af[t] = *(const f16x8*)(const void*)(LDS + ra);
        }
        #pragma unroll
        for (int t = 0; t < 4; ++t) {
            int rx = ((wc + t*16 + fr) << 5) + ((fq ^ sw) << 3);
            bf[t] = *(const f16x8*)(const void*)(LDS + 2048 + rx);
        }
        #pragma unroll
        for (int tm = 0; tm < 2; ++tm)
            #pragma unroll
            for (int tn = 0; tn < 4; ++tn)
                acc[tm][tn] = __builtin_amdgcn_mfma_f32_16x16x32_f16(bf[tn], af[tm], acc[tm][tn], 0, 0, 0);
    }
    #pragma unroll
    for (int tm = 0; tm < 2; ++tm)
        #pragma unroll
        for (int tn = 0; tn < 4; ++tn) {
            int row  = m0 + wr + tm*16 + fr;
            int col0 = n0 + wc + tn*16 + (fq << 2);
            size_t off = (size_t)row * ldc + col0;
            float4 bv = *(const float4*)(bias + col0);
            float v0 = acc[tm][tn][0] + bv.x, v1 = acc[tm][tn][1] + bv.y;
            float v2 = acc[tm][tn][2] + bv.z, v3 = acc[tm][tn][3] + bv.w;
            uint2 rh = *(const uint2*)(const void*)(Rh + off);
            uint2 rl = *(const uint2*)(const void*)(Rl + off);
            v0 += h2f((ushortb)(rh.x & 0xFFFFu)) + h2f((ushortb)(rl.x & 0xFFFFu));
            v1 += h2f((ushortb)(rh.x >> 16))     + h2f((ushortb)(rl.x >> 16));
            v2 += h2f((ushortb)(rh.y & 0xFFFFu)) + h2f((ushortb)(rl.y & 0xFFFFu));
            v3 += h2f((ushortb)(rh.y >> 16))     + h2f((ushortb)(rl.y >> 16));
            ushortb h0 = f2h(v0), h1 = f2h(v1), h2v = f2h(v2), h3v = f2h(v3);
            uint2 hp, lo;
            hp.x = (unsigned)h0 | ((unsigned)h1 << 16);
            hp.y = (unsigned)h2v | ((unsigned)h3v << 16);
            lo.x = (unsigned)f2h(v0 - h2f(h0))  | ((unsigned)f2h(v1 - h2f(h1))  << 16);
            lo.y = (unsigned)f2h(v2 - h2f(h2v)) | ((unsigned)f2h(v3 - h2f(h3v)) << 16);
            *(uint2*)(void*)(Ch + off) = hp;
            *(uint2*)(void*)(Cl + off) = lo;
        }
}

// ------------------------------------------------------------------
// FFT-based autocorrelation on TRANSPOSED pair QK: QKT[b][d][t], stride 2^20/b.
// ------------------------------------------------------------------
__device__ __forceinline__ void fft1024_tw(float* Xr, float* Xi, float* Yr, float* Yi,
                                           int tid, const float* csf, const float* snf)
{
    float *psr = Xr, *psi = Xi, *pdr = Yr, *pdi = Yi;
    #pragma unroll
    for (int st = 0; st < 10; ++st) {
        const int s = 1 << st;
        #pragma unroll
        for (int h = 0; h < 2; ++h) {
            int u = tid + (h << 8);
            int qq = u & (s - 1);
            int ps = u - qq;
            float cs = csf[st*2+h], sn = snf[st*2+h];
            float ar = psr[u],       ai = psi[u];
            float br = psr[u + 512], bi = psi[u + 512];
            int d1 = qq + (ps << 1);
            pdr[d1] = ar + br;  pdi[d1] = ai + bi;
            float tr = ar - br, ti = ai - bi;
            pdr[d1 + s] = tr * cs - ti * sn;
            pdi[d1 + s] = tr * sn + ti * cs;
        }
        __syncthreads();
        float* t0 = psr; psr = pdr; pdr = t0;
        float* t1 = psi; psi = pdi; pdi = t1;
    }
}

// grid (32, G): blockIdx.x = 16-wide d-chunk, blockIdx.y = local batch.
__launch_bounds__(256)
__global__ void corr_fft(const ushortb* __restrict__ QKh, const ushortb* __restrict__ QKl,
                         float* __restrict__ SP)
{
    __shared__ float Xr[1024], Xi[1024], Yr[1024], Yi[1024];
    const int tid = threadIdx.x;
    const int c = blockIdx.x, b = blockIdx.y;
    const size_t bbase = (size_t)b << 20;
    float csf[20], snf[20];
    #pragma unroll
    for (int st = 0; st < 10; ++st) {
        const int s = 1 << st;
        #pragma unroll
        for (int h = 0; h < 2; ++h) {
            int u = tid + (h << 8);
            int ps = u - (u & (s - 1));
            float ang = -(3.14159265358979323846f / 512.f) * (float)ps;
            __sincosf(ang, &snf[st*2+h], &csf[st*2+h]);
        }
    }
    float sr[4] = {0.f, 0.f, 0.f, 0.f};
    float si[4] = {0.f, 0.f, 0.f, 0.f};
    for (int j = 0; j < 16; ++j) {
        int d = (c << 4) + j;
        const ushortb* qh = QKh + bbase + ((size_t)d << 10);
        const ushortb* ql = QKl + bbase + ((size_t)d << 10);
        const ushortb* kh = qh + (512u << 10);
        const ushortb* kl = ql + (512u << 10);
        __syncthreads();                    // protect prior unpack reads
        #pragma unroll
        for (int i = 0; i < 4; ++i) {
            int t = tid + (i << 8);
            Xr[t] = h2f(qh[t]) + h2f(ql[t]);
            Xi[t] = h2f(kh[t]) + h2f(kl[t]);
        }
        __syncthreads();
        fft1024_tw(Xr, Xi, Yr, Yi, tid, csf, snf);
        #pragma unroll
        for (int i = 0; i < 4; ++i) {
            int f  = tid + (i << 8);
            int f2 = (1024 - f) & 1023;
            float axr = Xr[f],  axi = Xi[f];
            float cxr = Xr[f2], cxi = -Xi[f2];
            float ur = axr + cxr, ui = axi + cxi;
            float vr = axr - cxr, vi = -(axi - cxi);
            float wr_ = ur * vr - ui * vi;
            float wi_ = ur * vi + ui * vr;
            sr[i] += -0.25f * wi_;
            si[i] +=  0.25f * wr_;
        }
    }
    const size_t base = ((size_t)(b * 32 + c)) << 11;
    #pragma unroll
    for (int i = 0; i < 4; ++i) {
        int f = tid + (i << 8);
        SP[base + f]        = sr[i];
        SP[base + 1024 + f] = si[i];
    }
}

// per-b: reduce 32 chunk partials, inverse FFT, top-6 + softmax
__launch_bounds__(256)
__global__ void topk6f_fft(const float* __restrict__ SP, int* __restrict__ DELAY,
                           float* __restrict__ WGT)
{
    __shared__ float Xr[1024], Xi[1024], Yr[1024], Yi[1024];
    __shared__ float v[1024];
    __shared__ float rv[256];
    __shared__ int   ri[256];
    __shared__ float wv6[6];
    __shared__ int   wi6[6];
    const int b = blockIdx.x, tid = threadIdx.x;
    float csf[20], snf[20];
    #pragma unroll
    for (int st = 0; st < 10; ++st) {
        const int s = 1 << st;
        #pragma unroll
        for (int h = 0; h < 2; ++h) {
            int u = tid + (h << 8);
            int ps = u - (u & (s - 1));
            float ang = (3.14159265358979323846f / 512.f) * (float)ps;
            __sincosf(ang, &snf[st*2+h], &csf[st*2+h]);
        }
    }
    #pragma unroll
    for (int i = 0; i < 4; ++i) {
        int f = tid + (i << 8);
        float ar = 0.f, ai = 0.f;
        for (int c = 0; c < 32; ++c) {
            size_t base = ((size_t)(b * 32 + c)) << 11;
            ar += SP[base + f];
            ai += SP[base + 1024 + f];
        }
        Xr[f] = ar; Xi[f] = ai;
    }
    __syncthreads();
    fft1024_tw(Xr, Xi, Yr, Yi, tid, csf, snf);
    #pragma unroll
    for (int i = 0; i < 4; ++i) {
        int f = tid + (i << 8);
        v[f] = Xr[f] * (1.f / 524288.f);
    }
    __syncthreads();
    for (int it = 0; it < 6; ++it) {
        float best = v[tid]; int bi = tid;
        #pragma unroll
        for (int k = 1; k < 4; ++k) {
            int i = tid + (k << 8);
            float xv = v[i];
            if (xv > best) { best = xv; bi = i; }
        }
        rv[tid] = best; ri[tid] = bi;
        __syncthreads();
        for (int s = 128; s > 0; s >>= 1) {
            if (tid < s) {
                if (rv[tid+s] > rv[tid] || (rv[tid+s] == rv[tid] && ri[tid+s] < ri[tid])) {
                    rv[tid] = rv[tid+s]; ri[tid] = ri[tid+s];
                }
            }
            __syncthreads();
        }
        if (tid == 0) { wv6[it] = rv[0]; wi6[it] = ri[0]; v[ri[0]] = -1e30f; }
        __syncthreads();
    }
    if (tid == 0) {
        float mx = wv6[0], s = 0.f, e[6];
        #pragma unroll
        for (int i = 0; i < 6; ++i) { e[i] = expf(wv6[i] - mx); s += e[i]; }
        #pragma unroll
        for (int i = 0; i < 6; ++i) { WGT[b*6+i] = e[i]/s; DELAY[b*6+i] = wi6[i]; }
    }
}

// ------------------------------------------------------------------
// series_decomp pair->pair, STRIP-4 running-window version.
// grid: TG/8 blocks x 256 threads.
// ------------------------------------------------------------------
__launch_bounds__(256)
__global__ void decomp512v(const ushortb* __restrict__ Xh, const ushortb* __restrict__ Xl,
                           ushortb* __restrict__ Sh, ushortb* __restrict__ Sl,
                           float* __restrict__ TTs, int tmode)
{
    int idx = blockIdx.x * 256 + threadIdx.x;   // TG*32 threads
    int d0 = (idx & 127) << 2;
    int tg = idx >> 7;                          // global t-group
    int t0 = (tg & 255) << 2;
    int base = (tg >> 8) << 10;                 // batch row base
    int bb = tg >> 8;

    auto ldrow = [&](int tt) -> float4 {
        tt = tt < 0 ? 0 : (tt > 1023 ? 1023 : tt);
        size_t ro = ((size_t)(base + tt) << 9) + d0;
        uint2 hv = *(const uint2*)(Xh + ro);
        uint2 lv = *(const uint2*)(Xl + ro);
        float4 r;
        r.x = h2f((ushortb)(hv.x & 0xFFFFu)) + h2f((ushortb)(lv.x & 0xFFFFu));
        r.y = h2f((ushortb)(hv.x >> 16))     + h2f((ushortb)(lv.x >> 16));
        r.z = h2f((ushortb)(hv.y & 0xFFFFu)) + h2f((ushortb)(lv.y & 0xFFFFu));
        r.w = h2f((ushortb)(hv.y >> 16))     + h2f((ushortb)(lv.y >> 16));
        return r;
    };

    float s0 = 0.f, s1 = 0.f, s2 = 0.f, s3 = 0.f;
    #pragma unroll
    for (int w = -12; w <= 12; ++w) {
        float4 r = ldrow(t0 + w);
        s0 += r.x; s1 += r.y; s2 += r.z; s3 += r.w;
    }
    #pragma unroll
    for (int j = 0; j < 4; ++j) {
        int t = t0 + j;
        if (j > 0) {
            float4 add = ldrow(t + 12);
            float4 sub = ldrow(t - 13);
            s0 += add.x - sub.x; s1 += add.y - sub.y;
            s2 += add.z - sub.z; s3 += add.w - sub.w;
        }
        float m0 = s0*(1.f/25.f), m1 = s1*(1.f/25.f), m2 = s2*(1.f/25.f), m3 = s3*(1.f/25.f);
        size_t co = ((size_t)(base + t) << 9) + d0;
        uint2 chv = *(const uint2*)(Xh + co);
        uint2 clv = *(const uint2*)(Xl + co);
        float v0 = h2f((ushortb)(chv.x & 0xFFFFu)) + h2f((ushortb)(clv.x & 0xFFFFu)) - m0;
        float v1 = h2f((ushortb)(chv.x >> 16))     + h2f((ushortb)(clv.x >> 16))     - m1;
        float v2 = h2f((ushortb)(chv.y & 0xFFFFu)) + h2f((ushortb)(clv.y & 0xFFFFu)) - m2;
        float v3 = h2f((ushortb)(chv.y >> 16))     + h2f((ushortb)(clv.y >> 16))     - m3;
        ushortb h0=f2h(v0), h1=f2h(v1), h2v=f2h(v2), h3=f2h(v3);
        uint2 hp, lp;
        hp.x = (unsigned)h0 | ((unsigned)h1 << 16); hp.y = (unsigned)h2v | ((unsigned)h3 << 16);
        lp.x = (unsigned)f2h(v0-h2f(h0)) | ((unsigned)f2h(v1-h2f(h1)) << 16);
        lp.y = (unsigned)f2h(v2-h2f(h2v)) | ((unsigned)f2h(v3-h2f(h3)) << 16);
        *(uint2*)(Sh + co) = hp; *(uint2*)(Sl + co) = lp;
        if (tmode) {
            int slot = (t >= 511) ? (t - 511) : (t == 0 ? 513 : -1);
            if (slot >= 0) {
                float* tp = TTs + (size_t)bb * 263168 + ((size_t)slot << 9) + d0;
                if (tmode == 1) { tp[0]=m0; tp[1]=m1; tp[2]=m2; tp[3]=m3; }
                else            { tp[0]+=m0; tp[1]+=m1; tp[2]+=m2; tp[3]+=m3; }
            }
        }
    }
}

// per-token LN, pair in -> pair out
__launch_bounds__(256)
__global__ void ln_rows(const ushortb* __restrict__ Xh, const ushortb* __restrict__ Xl,
                        const float* __restrict__ w, const float* __restrict__ bias,
                        ushortb* __restrict__ Yh, ushortb* __restrict__ Yl)
{
    __shared__ float r1[256], r2[256];
    const int row = blockIdx.x, tid = threadIdx.x;
    size_t ro = (size_t)row * 512;
    float x0 = h2f(Xh[ro + tid]) + h2f(Xl[ro + tid]);
    float x1 = h2f(Xh[ro + tid + 256]) + h2f(Xl[ro + tid + 256]);
    r1[tid] = x0 + x1; r2[tid] = x0*x0 + x1*x1;
    __syncthreads();
    for (int s = 128; s > 0; s >>= 1) {
        if (tid < s) { r1[tid] += r1[tid+s]; r2[tid] += r2[tid+s]; }
        __syncthreads();
    }
    float mu = r1[0] * (1.f/512.f);
    float var = r2[0] * (1.f/512.f) - mu*mu;
    float rstd = rsqrtf(var + 1e-5f);
    float v0 = (x0 - mu) * rstd * w[tid]     + bias[tid];
    float v1 = (x1 - mu) * rstd * w[tid+256] + bias[tid+256];
    ushortb h0 = f2h(v0), h1 = f2h(v1);
    Yh[ro + tid] = h0;       Yl[ro + tid] = f2h(v0 - h2f(h0));
    Yh[ro + tid + 256] = h1; Yl[ro + tid + 256] = f2h(v1 - h2f(h1));
}

// column-mean partials from pair — COALESCED: consecutive threads walk
// consecutive d (128B/wave reads). PC layout unchanged: PC[b][d][c].
__launch_bounds__(256)
__global__ void colmean_p(const ushortb* __restrict__ Yh, const ushortb* __restrict__ Yl,
                          float* __restrict__ PC)
{
    int i = blockIdx.x * 256 + threadIdx.x;   // G*4096
    int b = i >> 12, r = i & 4095, d = r & 511, c = r >> 9;
    size_t o = ((size_t)b << 19) + ((size_t)(c << 7) << 9) + d;
    float s = 0.f;
    for (int t = 0; t < 128; ++t) { size_t oo = o + ((size_t)t << 9); s += h2f(Yh[oo]) + h2f(Yl[oo]); }
    PC[((size_t)b << 12) + (d << 3) + c] = s * (1.f/1024.f);
}

// Z = Y - colmean, pair -> pair
__launch_bounds__(256)
__global__ void submean_s(const ushortb* __restrict__ Yh, const ushortb* __restrict__ Yl,
                          const float* __restrict__ PC,
                          ushortb* __restrict__ Zh, ushortb* __restrict__ Zl)
{
    int idx = blockIdx.x * 256 + threadIdx.x;
    int d = idx & 511, b = idx >> 19;
    const float* pc = PC + ((size_t)b << 12) + (d << 3);
    float m = ((pc[0]+pc[1])+(pc[2]+pc[3]))+((pc[4]+pc[5])+(pc[6]+pc[7]));
    float v = h2f(Yh[idx]) + h2f(Yl[idx]) - m;
    ushortb h = f2h(v);
    Zh[idx] = h; Zl[idx] = f2h(v - h2f(h));
}

// embedding -> pair
__launch_bounds__(256)
__global__ void embed_es(const float* __restrict__ x, const float* __restrict__ mark,
                         const float* __restrict__ Wtok, const float* __restrict__ Wtem,
                         ushortb* __restrict__ Oh, ushortb* __restrict__ Ol)
{
    int idx = blockIdx.x * 256 + threadIdx.x;
    int d = idx & 511, bt = idx >> 9, t = bt & 1023, b = bt >> 10;
    float acc = 0.f;
    #pragma unroll
    for (int j = 0; j < 3; ++j) {
        int tt = (t + 1023 + j) & 1023;
        const float* xr = x + (size_t)(b*1024 + tt)*7;
        #pragma unroll
        for (int c = 0; c < 7; ++c)
            acc += xr[c] * Wtok[(j*7+c)*512 + d];
    }
    const float* mr = mark + (size_t)bt*4;
    #pragma unroll
    for (int m = 0; m < 4; ++m) acc += mr[m] * Wtem[m*512 + d];
    ushortb h = f2h(acc);
    Oh[idx] = h; Ol[idx] = f2h(acc - h2f(h));
}

__launch_bounds__(256)
__global__ void mean7(const float* __restrict__ x, float* __restrict__ M7)
{
    __shared__ float r[256];
    int bc = blockIdx.x, b = bc / 7, c = bc % 7, tid = threadIdx.x;
    float s = 0.f;
    for (int t = tid; t < 1024; t += 256) s += x[(size_t)(b*1024+t)*7 + c];
    r[tid] = s; __syncthreads();
    for (int st = 128; st > 0; st >>= 1) { if (tid < st) r[tid] += r[tid+st]; __syncthreads(); }
    if (tid == 0) M7[bc] = r[0] * (1.f/1024.f);
}

__launch_bounds__(256)
__global__ void decomp7(const float* __restrict__ x, const float* __restrict__ M7,
                        float* __restrict__ SEAS7, float* __restrict__ TREND7)
{
    int idx = blockIdx.x * 256 + threadIdx.x;  // TG*7
    int c = idx % 7, bt = idx / 7, t = bt & 1023, b = bt >> 10;
    if (t < 512) {
        int s0 = t + 512;
        float s = 0.f;
        #pragma unroll
        for (int w = -12; w <= 12; ++w) {
            int tt = s0 + w; tt = tt < 0 ? 0 : (tt > 1023 ? 1023 : tt);
            s += x[(size_t)(b*1024+tt)*7 + c];
        }
        float m = s * (1.f/25.f);
        SEAS7[idx] = x[(size_t)(b*1024+s0)*7 + c] - m;
        TREND7[idx] = m;
    } else {
        SEAS7[idx] = 0.f;
        TREND7[idx] = M7[b*7 + c];
    }
}

// fused: out = projb + TREND7 + X@projW + circ_conv3(TTs)@dec_trend_W  (rows t>=512)
__launch_bounds__(256)
__global__ void final_fused(const ushortb* __restrict__ Xh, const ushortb* __restrict__ Xl,
                            const float* __restrict__ PW, const float* __restrict__ PB,
                            const float* __restrict__ TW, const float* __restrict__ TTs,
                            const float* __restrict__ TREND7, float* __restrict__ out)
{
    __shared__ float WT[10752];   // 3*512*7
    __shared__ float WP[3584];    // 512*7
    for (int i = threadIdx.x; i < 10752; i += 256) WT[i] = TW[i];
    for (int i = threadIdx.x; i < 3584; i += 256) WP[i] = PW[i];
    __syncthreads();
    int idx = blockIdx.x * 256 + threadIdx.x;  // G*512*7
    int c = idx % 7, btt = idx / 7, tt = btt & 511, b = btt >> 9;
    int t = tt + 512;
    float acc = PB[c] + TREND7[(size_t)(b*1024 + t)*7 + c];
    size_t ro = ((size_t)(b*1024 + t) << 9);
    for (int d = 0; d < 512; ++d)
        acc += (h2f(Xh[ro + d]) + h2f(Xl[ro + d])) * WP[d*7 + c];
    for (int j = 0; j < 3; ++j) {
        int t2 = t - 1 + j;
        int slot = (t2 >= 1024) ? 513 : (t2 - 511);
        const float* r = TTs + (size_t)b * 263168 + ((size_t)slot << 9);
        const float* wj = WT + j*3584 + c;
        for (int d = 0; d < 512; ++d) acc += r[d] * wj[d*7];
    }
    out[idx] = acc;
}

// attn weight transpose+split pool (block a: 1572864 elems):
// QKh@0 (1024x512), QKl@524288, Vh@1048576, Oh@1310720
__launch_bounds__(256)
__global__ void wsplit_att(const float* __restrict__ W, ushortb* __restrict__ pool, int which)
{
    __shared__ float t[32][33];
    const int m = blockIdx.z;
    const int kb = blockIdx.y << 5, nb = blockIdx.x << 5;
    const int c = threadIdx.x & 31, rr = threadIdx.x >> 5;
    const float* Wm = W + (size_t)m * 262144;
    #pragma unroll
    for (int i = 0; i < 4; ++i)
        t[rr + i*8][c] = Wm[(size_t)(kb + rr + i*8) * 512 + nb + c];
    __syncthreads();
    const int a = (which == 0) ? (m >> 2) : (which + 1);
    const int j = (which == 0) ? (m & 3) : m;
    size_t hi, lo; bool haslo;
    if (j == 0)      { hi = 0;       lo = 524288; haslo = true; }
    else if (j == 1) { hi = 262144;  lo = 786432; haslo = true; }
    else if (j == 2) { hi = 1048576; lo = 0; haslo = false; }
    else             { hi = 1310720; lo = 0; haslo = false; }
    ushortb* pb = pool + (size_t)a * 1572864;
    #pragma unroll
    for (int i = 0; i < 4; ++i) {
        int n = nb + rr + i*8, k = kb + c;
        float v = t[c][rr + i*8];
        ushortb h = f2h(v);
        pb[hi + (size_t)n * 512 + k] = h;
        if (haslo) pb[lo + (size_t)n * 512 + k] = f2h(v - h2f(h));
    }
}

__launch_bounds__(256)
__global__ void wsplit_ff(const float* __restrict__ W, ushortb* __restrict__ dh,
                          int K, int N)
{
    __shared__ float t[32][33];
    const int m = blockIdx.z;
    const int kb = blockIdx.y << 5, nb = blockIdx.x << 5;
    const int c = threadIdx.x & 31, rr = threadIdx.x >> 5;
    const float* Wm = W + (size_t)m * K * N;
    #pragma unroll
    for (int i = 0; i < 4; ++i)
        t[rr + i*8][c] = Wm[(size_t)(kb + rr + i*8) * N + nb + c];
    __syncthreads();
    ushortb* Dh = dh + (size_t)m * 1048576;
    #pragma unroll
    for (int i = 0; i < 4; ++i) {
        int n = nb + rr + i*8, k = kb + c;
        Dh[(size_t)n * K + k] = f2h(t[c][rr + i*8]);
    }
}

__launch_bounds__(256)
__global__ void sentinel(float* __restrict__ out, int n)
{
    int i = blockIdx.x * 256 + threadIdx.x;
    if (i < n) out[i] = -54321.0f;
}

// ------------------------------------------------------------------
extern "C" void kernel_launch(void* const* d_in, const int* in_sizes, int n_in,
                              void* d_out, int out_size, void* d_ws, size_t ws_size,
                              hipStream_t stream)
{
    const float* x_enc      = (const float*)d_in[0];
    const float* x_mark_enc = (const float*)d_in[1];
    const float* x_mark_dec = (const float*)d_in[3];
    const float* W_enc_tok  = (const float*)d_in[4];
    const float* W_enc_tem  = (const float*)d_in[5];
    const float* W_dec_tok  = (const float*)d_in[6];
    const float* W_dec_tem  = (const float*)d_in[7];
    const float* enc_attn_W = (const float*)d_in[8];
    const float* enc_attn_b = (const float*)d_in[9];
    const float* enc_ff1    = (const float*)d_in[10];
    const float* enc_ff2    = (const float*)d_in[11];
    const float* enc_ln_w   = (const float*)d_in[12];
    const float* enc_ln_b   = (const float*)d_in[13];
    const float* dec_self_W = (const float*)d_in[14];
    const float* dec_self_b = (const float*)d_in[15];
    const float* dec_cross_W= (const float*)d_in[16];
    const float* dec_cross_b= (const float*)d_in[17];
    const float* dec_ff1    = (const float*)d_in[18];
    const float* dec_ff2    = (const float*)d_in[19];
    const float* dec_trend_W= (const float*)d_in[20];
    const float* dec_ln_w   = (const float*)d_in[21];
    const float* dec_ln_b   = (const float*)d_in[22];
    const float* proj_W     = (const float*)d_in[23];
    const float* proj_b     = (const float*)d_in[24];
    float* out = (float*)d_out;

    const size_t ATT_E = (size_t)4 * 1572864;
    const size_t FF_E  = (size_t)3 * 1048576;
    const size_t WBYTES = (ATT_E + 2 * FF_E) * 2 + 4096;

    auto need = [&](long g) -> size_t {
        size_t TGl = (size_t)g * 1024;
        size_t pairs = 3 * TGl * 2048;            // SA, TMP, SE pairs
        size_t qk    = TGl * 4096;                // QK pair / MID
        size_t vh    = TGl * 1024;
        size_t tts   = (size_t)g * 263168 * 4;
        size_t pbin  = (size_t)g * 262144;
        size_t misc  = (size_t)g * (16384 + 28 + 28672 + 28672 + 64) + 65536;
        return WBYTES + pairs + qk + vh + tts + pbin + misc + 16384;
    };
    int G = 0;
    for (int g = 32; g >= 1; g >>= 1) if (need(g) <= ws_size) { G = g; break; }
    if (G == 0) {
        sentinel<<<(out_size + 255) / 256, 256, 0, stream>>>(out, out_size);
        return;
    }
    const int TG = G * 1024;

    char* p = (char*)d_ws;
    auto carve = [&](size_t bytes) -> char* {
        char* r = p; p += (bytes + 255) & ~(size_t)255; return r;
    };
    ushortb* ATT = (ushortb*)carve(ATT_E * 2);
    ushortb* FF1 = (ushortb*)carve(FF_E * 2);
    ushortb* FF2 = (ushortb*)carve(FF_E * 2);

    const size_t SPLB = (size_t)TG * 512 * 2;
    ushortb* SAh = (ushortb*)carve(SPLB);
    ushortb* SAl = (ushortb*)carve(SPLB);
    ushortb* TMh = (ushortb*)carve(SPLB);
    ushortb* TMl = (ushortb*)carve(SPLB);
    ushortb* SEh = (ushortb*)carve(SPLB);
    ushortb* SEl = (ushortb*)carve(SPLB);
    char* R1 = carve((size_t)TG * 4096);             // QKTh+QKTl pair / MID
    ushortb* Vh = (ushortb*)carve((size_t)TG * 1024);
    float* TTs   = (float*)carve((size_t)G * 263168 * 4);
    float* PBIN  = (float*)carve((size_t)G * 262144);   // S-partials [b][32][2][1024] f32
    float* PC    = (float*)carve((size_t)G * 16384);
    float* M7    = (float*)carve((size_t)G * 28);
    float* SEAS7 = (float*)carve((size_t)G * 28672);
    float* TREND7= (float*)carve((size_t)G * 28672);
    float* WGT   = (float*)carve((size_t)G * 24);
    int*   DELAY = (int*)  carve((size_t)G * 24);

    ushortb* QKh = (ushortb*)R1;                       // transposed [b][d][t]
    ushortb* QKl = QKh + (size_t)TG * 1024;
    ushortb* MIDh = (ushortb*)R1;

    // ---- weight transforms ----
    wsplit_att<<<dim3(16,16,8),256,0,stream>>>(enc_attn_W, ATT, 0);
    wsplit_att<<<dim3(16,16,4),256,0,stream>>>(dec_self_W, ATT, 1);
    wsplit_att<<<dim3(16,16,4),256,0,stream>>>(dec_cross_W, ATT, 2);
    wsplit_ff<<<dim3(64,16,2),256,0,stream>>>(enc_ff1, FF1, 512, 2048);
    wsplit_ff<<<dim3(64,16,1),256,0,stream>>>(dec_ff1, FF1 + (size_t)2*1048576, 512, 2048);
    wsplit_ff<<<dim3(16,64,2),256,0,stream>>>(enc_ff2, FF2, 2048, 512);
    wsplit_ff<<<dim3(16,64,1),256,0,stream>>>(dec_ff2, FF2 + (size_t)2*1048576, 2048, 512);

    for (int g0 = 0; g0 < 32; g0 += G) {
        const float* xe  = x_enc      + (size_t)g0 * 1024 * 7;
        const float* me  = x_mark_enc + (size_t)g0 * 1024 * 4;
        const float* md  = x_mark_dec + (size_t)g0 * 1024 * 4;
        float*       outg= out        + (size_t)g0 * 512 * 7;
        const int GB = G * 8;    // TG/128
        const int GB2 = G * 16;  // TG/64 (M-tile-64 GEMMs)

        auto corr_gather_oproj = [&](const ushortb* base, const float* bv,
                                     const ushortb* rh, const ushortb* rl) {
            corr_fft<<<dim3(32,G),256,0,stream>>>(QKh, QKl, PBIN);
            topk6f_fft<<<G,256,0,stream>>>(PBIN, DELAY, WGT);
            gemm_og<<<dim3(4,GB2),256,0,stream>>>(Vh, DELAY, WGT,
                                                  base+1310720,512, bv+1536,
                                                  rh,rl, TMh,TMl, 512, 512);
        };
        auto attn_self = [&](const ushortb* xh, const ushortb* xl, int a, const float* bv) {
            const ushortb* base = ATT + (size_t)a * 1572864;
            gemm_h3<<<dim3(8,GB),256,0,stream>>>(xh,xl,512, base,base+524288,512, bv,
                                                 QKh,QKl, 512);
            gemm_h1<<<dim3(4,GB2),256,0,stream>>>(xh,512, base+1048576,512, bv+1024,
                                                  nullptr,nullptr, Vh,nullptr, 512, 512, 0);
            corr_gather_oproj(base, bv, xh, xl);
        };
        auto attn_cross = [&](const ushortb* qh, const ushortb* ql,
                              const ushortb* kvh, const ushortb* kvl,
                              int a, const float* bv) {
            const ushortb* base = ATT + (size_t)a * 1572864;
            gemm_h3<<<dim3(4,GB),256,0,stream>>>(qh,ql,512, base,base+524288,512, bv,
                                                 QKh,QKl, 512);
            gemm_h3<<<dim3(4,GB),256,0,stream>>>(kvh,kvl,512, base+262144,base+786432,512, bv+512,
                                                 QKh+524288,QKl+524288, 512);
            gemm_h1<<<dim3(4,GB2),256,0,stream>>>(kvh,512, base+1048576,512, bv+1024,
                                                  nullptr,nullptr, Vh,nullptr, 512, 512, 0);
            corr_gather_oproj(base, bv, qh, ql);
        };
        auto ffn = [&](const ushortb* xh, const ushortb* xl, int fi) {
            gemm_h1<<<dim3(16,GB2),256,0,stream>>>(xh,512, FF1 + (size_t)fi*1048576,512, nullptr,
                                                   nullptr,nullptr, MIDh,nullptr, 2048, 512, 1);
            gemm_h1<<<dim3(4,GB2),256,0,stream>>>(MIDh,2048, FF2 + (size_t)fi*1048576,2048, nullptr,
                                                  xh,xl, TMh,TMl, 512, 2048, 0);
        };

        // ---------------- encoder ----------------
        embed_es<<<TG*2,256,0,stream>>>(xe, me, W_enc_tok, W_enc_tem, SAh, SAl);
        for (int l = 0; l < 2; ++l) {
            attn_self(SAh, SAl, l, enc_attn_b + (size_t)l*4*512);
            decomp512v<<<TG/8,256,0,stream>>>(TMh, TMl, SAh, SAl, nullptr, 0);
            ffn(SAh, SAl, l);
            decomp512v<<<TG/8,256,0,stream>>>(TMh, TMl, SAh, SAl, nullptr, 0);
        }
        ln_rows<<<TG,256,0,stream>>>(SAh, SAl, enc_ln_w, enc_ln_b, TMh, TMl);
        colmean_p<<<G*16,256,0,stream>>>(TMh, TMl, PC);
        submean_s<<<TG*2,256,0,stream>>>(TMh, TMl, PC, SEh, SEl);

        // ---------------- decoder prep ----------------
        mean7<<<G*7,256,0,stream>>>(xe, M7);
        decomp7<<<G*28,256,0,stream>>>(xe, M7, SEAS7, TREND7);
        embed_es<<<TG*2,256,0,stream>>>(SEAS7, md, W_dec_tok, W_dec_tem, SAh, SAl);

        // ---------------- decoder layer ----------------
        attn_self(SAh, SAl, 2, dec_self_b);
        decomp512v<<<TG/8,256,0,stream>>>(TMh, TMl, SAh, SAl, TTs, 1);

        attn_cross(SAh, SAl, SEh, SEl, 3, dec_cross_b);
        decomp512v<<<TG/8,256,0,stream>>>(TMh, TMl, SAh, SAl, TTs, 2);

        ffn(SAh, SAl, 2);
        decomp512v<<<TG/8,256,0,stream>>>(TMh, TMl, SAh, SAl, TTs, 2);

        ln_rows<<<TG,256,0,stream>>>(SAh, SAl, dec_ln_w, dec_ln_b, TMh, TMl);
        colmean_p<<<G*16,256,0,stream>>>(TMh, TMl, PC);
        submean_s<<<TG*2,256,0,stream>>>(TMh, TMl, PC, SAh, SAl);

        final_fused<<<G*14,256,0,stream>>>(SAh, SAl, proj_W, proj_b, dec_trend_W,
                                           TTs, TREND7, outg);
    }
}